// Round 14
// baseline (1985.773 us; speedup 1.0000x reference)
//
#include <hip/hip_runtime.h>
#include <hip/hip_fp16.h>
#include <math.h>

#define BB 2
#define DD 256
#define HH 8
#define HDIM 32
#define FFD 1024
#define LL 6
#define NQQ 540
#define QPO_ 27
#define PS0 20
#define PS1 20
#define PS2 32
#define PP (PS0*PS1*PS2)   // 12800
#define MR (BB*NQQ)        // 1080
#define NSPL 4             // cross-attn row-partials per query

typedef _Float16 half8 __attribute__((ext_vector_type(8)));
typedef _Float16 half4v __attribute__((ext_vector_type(4)));
typedef _Float16 h2v  __attribute__((ext_vector_type(2)));
typedef float f32x4 __attribute__((ext_vector_type(4)));

static __device__ __forceinline__ float wred_sum(float x) {
#pragma unroll
  for (int off = 32; off; off >>= 1) x += __shfl_xor(x, off, 64);
  return x;
}
static __device__ __forceinline__ float4 h4_to_f4(uint2 u) {
  __half2 h0 = *reinterpret_cast<__half2*>(&u.x);
  __half2 h1 = *reinterpret_cast<__half2*>(&u.y);
  float2 f0 = __half22float2(h0);
  float2 f1 = __half22float2(h1);
  return make_float4(f0.x, f0.y, f1.x, f1.y);
}
static __device__ __forceinline__ float dot4h(uint2 kw, h2v q01, h2v q23) {
  h2v a = *reinterpret_cast<h2v*>(&kw.x);
  h2v b = *reinterpret_cast<h2v*>(&kw.y);
  float d = __builtin_amdgcn_fdot2(a, q01, 0.f, false);
  return __builtin_amdgcn_fdot2(b, q23, d, false);
}

// ---------------------------------------------------------------------------
// init: tgt[b,q,d] = qe[q, 256+d]; qpos[b,q,d] = qe[q, d]
__global__ __launch_bounds__(256) void init_kernel(
    const float* __restrict__ qe, float* __restrict__ tgt, float* __restrict__ qpos)
{
  int idx = blockIdx.x * 256 + threadIdx.x;   // < B*NQ*D == 276480
  int d = idx % DD;
  int q = (idx / DD) % NQQ;
  qpos[idx] = qe[q * 512 + d];
  tgt[idx]  = qe[q * 512 + 256 + d];
}

// ---------------------------------------------------------------------------
// One-time: transpose+convert src/pos to fp16 [b][p][d] layouts.
__global__ __launch_bounds__(256) void conv_kv_inputs(
    const float* __restrict__ src, const float* __restrict__ pos,
    __half* __restrict__ s16, __half* __restrict__ kv16)
{
  __shared__ float ls[64][65];
  __shared__ float lk[64][65];
  int b  = blockIdx.z;
  int p0 = blockIdx.x * 64;
  int d0 = blockIdx.y * 64;
  int t = threadIdx.x;
  int pr = (t & 15) * 4;
  int dr = t >> 4;
#pragma unroll
  for (int dd = 0; dd < 64; dd += 16) {
    int d = d0 + dd + dr;
    float4 sv = *(const float4*)&src[((size_t)b * DD + d) * PP + p0 + pr];
    float4 pv = *(const float4*)&pos[((size_t)b * DD + d) * PP + p0 + pr];
    ls[pr + 0][dd + dr] = sv.x; ls[pr + 1][dd + dr] = sv.y;
    ls[pr + 2][dd + dr] = sv.z; ls[pr + 3][dd + dr] = sv.w;
    lk[pr + 0][dd + dr] = sv.x + pv.x; lk[pr + 1][dd + dr] = sv.y + pv.y;
    lk[pr + 2][dd + dr] = sv.z + pv.z; lk[pr + 3][dd + dr] = sv.w + pv.w;
  }
  __syncthreads();
  int wp = t >> 2;
  int wd = (t & 3) * 16;
  size_t base = ((size_t)b * PP + p0 + wp) * 256 + d0 + wd;
#pragma unroll
  for (int i = 0; i < 16; i += 2) {
    *(__half2*)&s16[base + i]  = __floats2half2_rn(ls[wp][wd + i], ls[wp][wd + i + 1]);
    *(__half2*)&kv16[base + i] = __floats2half2_rn(lk[wp][wd + i], lk[wp][wd + i + 1]);
  }
}

// One-time: fp32 -> fp16 weight conversion (grid-stride).
__global__ __launch_bounds__(256) void conv_w(
    const float* __restrict__ w, __half* __restrict__ w16, int n)
{
  for (int i = blockIdx.x * 256 + threadIdx.x; i < n; i += gridDim.x * 256)
    w16[i] = __float2half_rn(w[i]);
}

// ---------------------------------------------------------------------------
// Merged MFMA K&V projection: z>>1 selects (A,W,out) pair, z&1 = batch b.
__global__ __launch_bounds__(256) void gemm_kv2_mfma(
    const __half* __restrict__ Ak, const __half* __restrict__ Av,
    const __half* __restrict__ Wk, const __half* __restrict__ Wv,
    __half* __restrict__ Ko, __half* __restrict__ Vo)
{
  int z = blockIdx.z;
  int b = z & 1;
  const __half* A = (z >> 1) ? Av : Ak;
  const __half* W = (z >> 1) ? Wv : Wk;
  __half* out     = (z >> 1) ? Vo : Ko;
  int wid = threadIdx.x >> 6;
  int lane = threadIdx.x & 63;
  int p0 = blockIdx.x * 128 + (wid >> 1) * 64;
  int n0 = blockIdx.y * 128 + (wid & 1) * 64;
  const __half* Ab = A + (size_t)b * PP * 256;
  int row = lane & 15;
  int kg  = lane >> 4;
  f32x4 acc[4][4] = {};
  for (int k0 = 0; k0 < 256; k0 += 32) {
    half8 af[4], bf[4];
#pragma unroll
    for (int i = 0; i < 4; ++i)
      af[i] = *(const half8*)&Ab[((size_t)(p0 + 16 * i + row)) * 256 + k0 + kg * 8];
#pragma unroll
    for (int j = 0; j < 4; ++j)
      bf[j] = *(const half8*)&W[((size_t)(n0 + 16 * j + row)) * 256 + k0 + kg * 8];
#pragma unroll
    for (int i = 0; i < 4; ++i)
#pragma unroll
      for (int j = 0; j < 4; ++j)
        acc[i][j] = __builtin_amdgcn_mfma_f32_16x16x32_f16(af[i], bf[j], acc[i][j], 0, 0, 0);
  }
#pragma unroll
  for (int i = 0; i < 4; ++i)
#pragma unroll
    for (int j = 0; j < 4; ++j) {
      int nc = n0 + 16 * j + row;
#pragma unroll
      for (int r = 0; r < 4; ++r) {
        int pr = p0 + 16 * i + kg * 4 + r;
        out[((size_t)b * PP + pr) * 256 + nc] = __float2half_rn(acc[i][j][r]);
      }
    }
}

// ---------------------------------------------------------------------------
// MFMA row GEMM: C[r,n] = (A1[r,:](+A2[r,:])) @ W16[n,:] (+bias)(+res)(relu).
__global__ __launch_bounds__(256) void gemm_rows_mfma(
    const float* __restrict__ A1, const float* __restrict__ A2,
    const __half* __restrict__ W, const float* __restrict__ bias,
    const float* __restrict__ res, float* __restrict__ C,
    int M, int N, int K, int relu)
{
  __shared__ __half a_s[64][40];   // row stride 80B (16B-mult): aligned half8 ops
  int bm = blockIdx.x * 64;
  int bn = blockIdx.y * 64;
  int wv = threadIdx.x >> 6;
  int lane = threadIdx.x & 63;
  int row = lane & 15;
  int kg  = lane >> 4;
  int nw  = bn + wv * 16;
  int t = threadIdx.x;
  int srow = t >> 2, skq = (t & 3) * 8;
  f32x4 acc[4] = {};

  for (int k0 = 0; k0 < K; k0 += 32) {
    { // stage A tile (64 rows x 32 k) as fp16; over-read rows land in ws
      size_t off = (size_t)(bm + srow) * K + k0 + skq;
      float4 a0 = *(const float4*)&A1[off];
      float4 a1 = *(const float4*)&A1[off + 4];
      if (A2) {
        float4 b0 = *(const float4*)&A2[off];
        float4 b1 = *(const float4*)&A2[off + 4];
        a0.x += b0.x; a0.y += b0.y; a0.z += b0.z; a0.w += b0.w;
        a1.x += b1.x; a1.y += b1.y; a1.z += b1.z; a1.w += b1.w;
      }
      half8 h;
      h[0] = (_Float16)a0.x; h[1] = (_Float16)a0.y;
      h[2] = (_Float16)a0.z; h[3] = (_Float16)a0.w;
      h[4] = (_Float16)a1.x; h[5] = (_Float16)a1.y;
      h[6] = (_Float16)a1.z; h[7] = (_Float16)a1.w;
      *(half8*)&a_s[srow][skq] = h;
    }
    __syncthreads();
    half8 bf = *(const half8*)&W[(size_t)(nw + row) * K + k0 + kg * 8];
#pragma unroll
    for (int i = 0; i < 4; ++i) {
      half8 af = *(const half8*)&a_s[16 * i + row][kg * 8];
      acc[i] = __builtin_amdgcn_mfma_f32_16x16x32_f16(af, bf, acc[i], 0, 0, 0);
    }
    __syncthreads();
  }

  int col = nw + row;
  float bval = bias ? bias[col] : 0.f;
#pragma unroll
  for (int i = 0; i < 4; ++i) {
#pragma unroll
    for (int r = 0; r < 4; ++r) {
      int rr = bm + 16 * i + kg * 4 + r;
      if (rr >= M) continue;
      float v = acc[i][r] + bval;
      if (relu) v = fmaxf(v, 0.f);
      if (res)  v += res[(size_t)rr * N + col];
      C[(size_t)rr * N + col] = v;
    }
  }
}

// ---------------------------------------------------------------------------
// Fused MFMA GEMM + bias + residual + LayerNorm. N fixed = 256.
// 512 thr (8 waves); tile 64M x 256N; wave wv owns cols [wv*32, wv*32+32).
// Outputs staged to LDS fp16; LN with 8 threads/row; fp32 store.
__global__ __launch_bounds__(512) void gemm_ln_mfma(
    const float* __restrict__ A1, const __half* __restrict__ W,
    const float* __restrict__ bias, const float* __restrict__ res,
    const float* __restrict__ g, const float* __restrict__ bta,
    float* __restrict__ out, int M, int K)
{
  __shared__ __half a_s[64][40];
  __shared__ __half o_s[64][264];
  int bm = blockIdx.x * 64;
  int wv = threadIdx.x >> 6;
  int lane = threadIdx.x & 63;
  int row = lane & 15;
  int kg  = lane >> 4;
  int t = threadIdx.x;
  int srow = t >> 3, skq = (t & 7) * 4;
  f32x4 acc[4][2] = {};

  for (int k0 = 0; k0 < K; k0 += 32) {
    { // stage A (64 x 32) as fp16; one float4 per thread
      float4 a0 = *(const float4*)&A1[(size_t)(bm + srow) * K + k0 + skq];
      half4v h;
      h[0] = (_Float16)a0.x; h[1] = (_Float16)a0.y;
      h[2] = (_Float16)a0.z; h[3] = (_Float16)a0.w;
      *(half4v*)&a_s[srow][skq] = h;
    }
    __syncthreads();
    half8 bf0 = *(const half8*)&W[(size_t)(wv * 32 + row) * K + k0 + kg * 8];
    half8 bf1 = *(const half8*)&W[(size_t)(wv * 32 + 16 + row) * K + k0 + kg * 8];
#pragma unroll
    for (int i = 0; i < 4; ++i) {
      half8 af = *(const half8*)&a_s[16 * i + row][kg * 8];
      acc[i][0] = __builtin_amdgcn_mfma_f32_16x16x32_f16(af, bf0, acc[i][0], 0, 0, 0);
      acc[i][1] = __builtin_amdgcn_mfma_f32_16x16x32_f16(af, bf1, acc[i][1], 0, 0, 0);
    }
    __syncthreads();
  }

  // epilogue: bias + residual -> LDS fp16
#pragma unroll
  for (int j = 0; j < 2; ++j) {
    int col = wv * 32 + 16 * j + row;
    float bval = bias[col];
#pragma unroll
    for (int i = 0; i < 4; ++i)
#pragma unroll
      for (int r = 0; r < 4; ++r) {
        int rr = 16 * i + kg * 4 + r;
        float v = acc[i][j][r] + bval + res[(size_t)(bm + rr) * 256 + col];
        o_s[rr][col] = __float2half_rn(v);
      }
  }
  __syncthreads();

  // LayerNorm: 8 threads per row, 32 cols each
  int r8 = t >> 3;
  int c8 = (t & 7) * 32;
  float vals[32];
  float sum = 0.f, sq = 0.f;
#pragma unroll
  for (int c = 0; c < 32; ++c) {
    float v = __half2float(o_s[r8][c8 + c]);
    vals[c] = v; sum += v; sq = fmaf(v, v, sq);
  }
#pragma unroll
  for (int off = 1; off < 8; off <<= 1) {
    sum += __shfl_xor(sum, off, 64);
    sq  += __shfl_xor(sq,  off, 64);
  }
  float mean = sum * (1.f / 256.f);
  float var  = fmaxf(sq * (1.f / 256.f) - mean * mean, 0.f);
  float inv  = rsqrtf(var + 1e-5f);
  int grow = bm + r8;
  if (grow < M) {
    float* orow = out + (size_t)grow * 256 + c8;
#pragma unroll
    for (int c = 0; c < 32; c += 4) {
      float4 o;
      o.x = (vals[c + 0] - mean) * inv * g[c8 + c + 0] + bta[c8 + c + 0];
      o.y = (vals[c + 1] - mean) * inv * g[c8 + c + 1] + bta[c8 + c + 1];
      o.z = (vals[c + 2] - mean) * inv * g[c8 + c + 2] + bta[c8 + c + 2];
      o.w = (vals[c + 3] - mean) * inv * g[c8 + c + 3] + bta[c8 + c + 3];
      *(float4*)&orow[c] = o;
    }
  }
}

// ---------------------------------------------------------------------------
// Self-attention, all-heads-batched. One block (8 waves) per (b,q). fp32 K/V.
__global__ __launch_bounds__(512) void sa_attn(
    const float* __restrict__ qkbuf, const float* __restrict__ vbuf,
    float* __restrict__ out)
{
  __shared__ float wmS[8][8];
  __shared__ float wsS[8][8];
  __shared__ float4 ooS[8][64];

  int bid = blockIdx.x;           // b*NQQ + q
  int b = bid / NQQ;
  int wv = threadIdx.x >> 6;
  int lane = threadIdx.x & 63;
  const float scale = 0.17677669529663687f;  // 32^-0.5

  float4 q4 = ((const float4*)(qkbuf + (size_t)bid * 512))[lane];
  q4.x *= scale; q4.y *= scale; q4.z *= scale; q4.w *= scale;

  const float* Kb = qkbuf + (size_t)b * NQQ * 512 + 256;  // k part of rows
  const float* Vb = vbuf + (size_t)b * NQQ * 256;

  float m = -INFINITY, s = 0.f;
  float4 o4 = make_float4(0.f, 0.f, 0.f, 0.f);

  for (int k0 = wv * 8; k0 < NQQ; k0 += 64) {
    const float4* kp = (const float4*)(Kb + (size_t)k0 * 512) + lane;
    const float4* vp = (const float4*)(Vb + (size_t)k0 * 256) + lane;
    float4 kk[8];
#pragma unroll
    for (int i = 0; i < 8; ++i) kk[i] = kp[i * 128];
    float lg[8];
#pragma unroll
    for (int i = 0; i < 8; ++i) {
      float d = q4.x * kk[i].x;
      d = fmaf(q4.y, kk[i].y, d);
      d = fmaf(q4.z, kk[i].z, d);
      d = fmaf(q4.w, kk[i].w, d);
      d += __shfl_xor(d, 1, 64);
      d += __shfl_xor(d, 2, 64);
      d += __shfl_xor(d, 4, 64);
      lg[i] = (k0 + i < NQQ) ? d : -INFINITY;
    }
    float4 vv[8];
#pragma unroll
    for (int i = 0; i < 8; ++i) vv[i] = vp[i * 64];

    float bm = fmaxf(fmaxf(fmaxf(lg[0], lg[1]), fmaxf(lg[2], lg[3])),
                     fmaxf(fmaxf(lg[4], lg[5]), fmaxf(lg[6], lg[7])));
    float mn = fmaxf(m, bm);
    float f = __expf(m - mn);        // first batch: m=-inf -> f=0
    s *= f; o4.x *= f; o4.y *= f; o4.z *= f; o4.w *= f;
    m = mn;
#pragma unroll
    for (int i = 0; i < 8; ++i) {
      float p = __expf(lg[i] - mn);  // tail lg=-inf -> 0
      s += p;
      o4.x = fmaf(p, vv[i].x, o4.x);
      o4.y = fmaf(p, vv[i].y, o4.y);
      o4.z = fmaf(p, vv[i].z, o4.z);
      o4.w = fmaf(p, vv[i].w, o4.w);
    }
  }

  // ---- merge 8 wave-states (per head) ----
  int hg = lane >> 3, sub = lane & 7;
  if (sub == 0) wmS[wv][hg] = m;
  __syncthreads();
  float M = wmS[0][hg];
#pragma unroll
  for (int w = 1; w < 8; ++w) M = fmaxf(M, wmS[w][hg]);
  float f = __expf(m - M);
  if (sub == 0) wsS[wv][hg] = s * f;
  ooS[wv][lane] = make_float4(o4.x * f, o4.y * f, o4.z * f, o4.w * f);
  __syncthreads();
  if (threadIdx.x < 64) {
    int l = threadIdx.x;
    int hg2 = l >> 3;
    float4 acc = make_float4(0.f, 0.f, 0.f, 0.f);
    float den = 0.f;
#pragma unroll
    for (int w = 0; w < 8; ++w) {
      float4 t = ooS[w][l];
      acc.x += t.x; acc.y += t.y; acc.z += t.z; acc.w += t.w;
      den += wsS[w][hg2];
    }
    float inv = 1.f / den;
    float4 res = make_float4(acc.x * inv, acc.y * inv, acc.z * inv, acc.w * inv);
    *(float4*)&out[(size_t)bid * 256 + l * 4] = res;
  }
}

// ---------------------------------------------------------------------------
// Cross-attention partial (R9 version — best measured): dim-layout lanes,
// fdot2 QK, split even/odd accumulator chains. fp16 K/V; NSPL blocks per
// (b,q); XCD-grouping swizzle.
__global__ __launch_bounds__(512) void ca_attn_part(
    const float* __restrict__ qbuf, const __half* __restrict__ Kbuf,
    const __half* __restrict__ Vbuf, const int* __restrict__ lohi,
    float* __restrict__ pm, float* __restrict__ ps, float* __restrict__ po)
{
  __shared__ float wmS[8][8];
  __shared__ float wsS[8][8];
  __shared__ float4 ooS[8][64];

  // --- swizzle: 4320 blocks = 8 cls x 5 gsub x 27 iq x 4 part ---
  int idx  = blockIdx.x;
  int cls  = idx & 7;
  int rest = idx >> 3;          // 0..539
  int gsub = rest / 108;        // 0..4
  int rem  = rest % 108;
  int iq   = rem >> 2;          // 0..26
  int part = rem & 3;           // NSPL == 4
  int g    = gsub * 8 + cls;    // organ-group 0..39
  int b    = g / 20;
  int q    = (g % 20) * QPO_ + iq;
  int bid  = b * NQQ + q;

  int wv = threadIdx.x >> 6;
  int lane = threadIdx.x & 63;
  const float scale = 0.17677669529663687f;

  const int* lh = lohi + (size_t)bid * 6;
  int lo0 = lh[0], lo1 = lh[1], lo2 = lh[2];
  int nx = lh[3] - lo0, ny = lh[4] - lo1, nz = lh[5] - lo2;
  int nxy = nx * ny;
  float inv_ny = 1.0f / (float)ny;

  float4 q4 = ((const float4*)(qbuf + (size_t)bid * 256))[lane];
  q4.x *= scale; q4.y *= scale; q4.z *= scale; q4.w *= scale;
  h2v q01, q23;
  q01[0] = (_Float16)q4.x; q01[1] = (_Float16)q4.y;
  q23[0] = (_Float16)q4.z; q23[1] = (_Float16)q4.w;

  const __half* Kb = Kbuf + (size_t)b * PP * 256;
  const __half* Vb = Vbuf + (size_t)b * PP * 256;

  float m = -INFINITY, sA = 0.f, sB = 0.f;
  float4 oA = make_float4(0.f, 0.f, 0.f, 0.f);
  float4 oB = make_float4(0.f, 0.f, 0.f, 0.f);

  for (int r = part + NSPL * wv; r < nxy; r += NSPL * 8) {
    int x = (int)((float)r * inv_ny);
    int y = r - x * ny;
    if (y < 0)        { x--; y += ny; }
    else if (y >= ny) { x++; y -= ny; }
    int base = (lo0 + x) * (PS1 * PS2) + (lo1 + y) * PS2 + lo2;

    for (int z0 = 0; z0 < nz; z0 += 8) {
      const uint2* kp = (const uint2*)(Kb + ((size_t)base + z0) * 256) + lane;
      const uint2* vp = (const uint2*)(Vb + ((size_t)base + z0) * 256) + lane;
      uint2 kw[8];
#pragma unroll
      for (int i = 0; i < 8; ++i) kw[i] = kp[i * 64];   // row stride 256 halfs
      uint2 vw[8];
#pragma unroll
      for (int i = 0; i < 8; ++i) vw[i] = vp[i * 64];

      float lg[8];
#pragma unroll
      for (int i = 0; i < 8; ++i) {
        float d = dot4h(kw[i], q01, q23);
        d += __shfl_xor(d, 1, 64);
        d += __shfl_xor(d, 2, 64);
        d += __shfl_xor(d, 4, 64);
        lg[i] = (z0 + i < nz) ? d : -INFINITY;
      }

      float bm = fmaxf(fmaxf(fmaxf(lg[0], lg[1]), fmaxf(lg[2], lg[3])),
                       fmaxf(fmaxf(lg[4], lg[5]), fmaxf(lg[6], lg[7])));
      float mn = fmaxf(m, bm);
      float f = __expf(m - mn);      // first batch: m=-inf -> f=0
      sA *= f; sB *= f;
      oA.x *= f; oA.y *= f; oA.z *= f; oA.w *= f;
      oB.x *= f; oB.y *= f; oB.z *= f; oB.w *= f;
      m = mn;
#pragma unroll
      for (int i = 0; i < 8; i += 2) {
        float pa = __expf(lg[i] - mn);      // masked -inf -> 0
        float pb = __expf(lg[i + 1] - mn);
        float4 va = h4_to_f4(vw[i]);
        float4 vb = h4_to_f4(vw[i + 1]);
        sA += pa; sB += pb;
        oA.x = fmaf(pa, va.x, oA.x); oB.x = fmaf(pb, vb.x, oB.x);
        oA.y = fmaf(pa, va.y, oA.y); oB.y = fmaf(pb, vb.y, oB.y);
        oA.z = fmaf(pa, va.z, oA.z); oB.z = fmaf(pb, vb.z, oB.z);
        oA.w = fmaf(pa, va.w, oA.w); oB.w = fmaf(pb, vb.w, oB.w);
      }
    }
  }

  float s = sA + sB;
  float4 o4 = make_float4(oA.x + oB.x, oA.y + oB.y, oA.z + oB.z, oA.w + oB.w);

  // ---- merge this block's 8 wave-states; write partial (M, S, O) ----
  int hg = lane >> 3, sub = lane & 7;
  if (sub == 0) wmS[wv][hg] = m;
  __syncthreads();
  float M = wmS[0][hg];
#pragma unroll
  for (int w = 1; w < 8; ++w) M = fmaxf(M, wmS[w][hg]);
  float f = (M == -INFINITY) ? 0.f : __expf(m - M);  // empty part -> zeros
  if (sub == 0) wsS[wv][hg] = s * f;
  ooS[wv][lane] = make_float4(o4.x * f, o4.y * f, o4.z * f, o4.w * f);
  __syncthreads();
  if (threadIdx.x < 64) {
    int l = threadIdx.x;
    int hg2 = l >> 3;
    float4 acc = make_float4(0.f, 0.f, 0.f, 0.f);
    float den = 0.f;
#pragma unroll
    for (int w = 0; w < 8; ++w) {
      float4 t = ooS[w][l];
      acc.x += t.x; acc.y += t.y; acc.z += t.z; acc.w += t.w;
      den += wsS[w][hg2];
    }
    float M2 = wmS[0][hg2];
#pragma unroll
    for (int w = 1; w < 8; ++w) M2 = fmaxf(M2, wmS[w][hg2]);
    size_t pb = (size_t)bid * NSPL + part;
    if ((l & 7) == 0) { pm[pb * 8 + hg2] = M2; ps[pb * 8 + hg2] = den; }
    *(float4*)&po[pb * 256 + l * 4] = acc;
  }
}

// ---------------------------------------------------------------------------
// Merge NSPL cross-attn partials per query. One wave per (b,q).
__global__ __launch_bounds__(256) void ca_merge(
    const float* __restrict__ pm, const float* __restrict__ ps,
    const float* __restrict__ po, float* __restrict__ out)
{
  int wv = threadIdx.x >> 6;
  int lane = threadIdx.x & 63;
  int bid = blockIdx.x * 4 + wv;
  int hg = lane >> 3;
  size_t pb = (size_t)bid * NSPL;

  float mp[NSPL], sp[NSPL];
#pragma unroll
  for (int p = 0; p < NSPL; ++p) {
    mp[p] = pm[(pb + p) * 8 + hg];
    sp[p] = ps[(pb + p) * 8 + hg];
  }
  float M = fmaxf(fmaxf(mp[0], mp[1]), fmaxf(mp[2], mp[3]));
  float den = 0.f;
  float4 acc = make_float4(0.f, 0.f, 0.f, 0.f);
#pragma unroll
  for (int p = 0; p < NSPL; ++p) {
    float f = __expf(mp[p] - M);     // empty part m=-inf -> 0
    den = fmaf(f, sp[p], den);
    float4 t = *(const float4*)&po[(pb + p) * 256 + lane * 4];
    acc.x = fmaf(f, t.x, acc.x);
    acc.y = fmaf(f, t.y, acc.y);
    acc.z = fmaf(f, t.z, acc.z);
    acc.w = fmaf(f, t.w, acc.w);
  }
  float inv = 1.f / den;
  float4 res = make_float4(acc.x * inv, acc.y * inv, acc.z * inv, acc.w * inv);
  *(float4*)&out[(size_t)bid * 256 + lane * 4] = res;
}

// ---------------------------------------------------------------------------
// Layer-0 mask boxes from attn_area.
__global__ __launch_bounds__(256) void mask0_kernel(
    const float* __restrict__ area, int* __restrict__ lohi,
    float px, float py, float pz)
{
  int row = blockIdx.x * 256 + threadIdx.x;
  if (row >= MR) return;
  int q = row % NQQ;
  int org = q / QPO_;
  const float* a = area + org * 6;
  int* o = lohi + (size_t)row * 6;
  o[0] = (int)fminf(fmaxf(floorf(a[0] * 20.f - px), 0.f), 20.f);
  o[1] = (int)fminf(fmaxf(floorf(a[1] * 20.f - py), 0.f), 20.f);
  o[2] = (int)fminf(fmaxf(floorf(a[2] * 32.f - pz), 0.f), 32.f);
  o[3] = (int)fminf(fmaxf(floorf(a[3] * 20.f + px), 0.f), 20.f);
  o[4] = (int)fminf(fmaxf(floorf(a[4] * 20.f + py), 0.f), 20.f);
  o[5] = (int)fminf(fmaxf(floorf(a[5] * 32.f + pz), 0.f), 32.f);
}

// ---------------------------------------------------------------------------
// Layers >=1: prop = h2 @ w3.T + b3 -> tanh*0.1 + anchors -> clip -> box ints.
__global__ __launch_bounds__(256) void mask_reg_kernel(
    const float* __restrict__ h2, const float* __restrict__ w3,
    const float* __restrict__ b3, const float* __restrict__ anchors,
    int* __restrict__ lohi, float px, float py, float pz)
{
  int wv = threadIdx.x >> 6;
  int lane = threadIdx.x & 63;
  int row = blockIdx.x * 4 + wv;
  int q = row % NQQ;
  const float* hr = h2 + (size_t)row * 256;
  float part[6] = {};
#pragma unroll
  for (int j = 0; j < 4; ++j) {
    float hv = hr[lane + 64 * j];
#pragma unroll
    for (int o = 0; o < 6; ++o)
      part[o] = fmaf(hv, w3[o * 256 + lane + 64 * j], part[o]);
  }
#pragma unroll
  for (int o = 0; o < 6; ++o) part[o] = wred_sum(part[o]);
  if (lane == 0) {
    float prop[6];
#pragma unroll
    for (int o = 0; o < 6; ++o) {
      float v = tanhf(part[o] + b3[o]) * 0.1f + anchors[q * 6 + o];
      prop[o] = fminf(fmaxf(v, 0.f), 1.f);
    }
    float vl0 = prop[0] - 0.5f * prop[3], vh0 = prop[0] + 0.5f * prop[3];
    float vl1 = prop[1] - 0.5f * prop[4], vh1 = prop[1] + 0.5f * prop[4];
    float vl2 = prop[2] - 0.5f * prop[5], vh2 = prop[2] + 0.5f * prop[5];
    int* o = lohi + (size_t)row * 6;
    o[0] = (int)fminf(fmaxf(floorf(vl0 * 20.f - px), 0.f), 20.f);
    o[1] = (int)fminf(fmaxf(floorf(vl1 * 20.f - py), 0.f), 20.f);
    o[2] = (int)fminf(fmaxf(floorf(vl2 * 32.f - pz), 0.f), 32.f);
    o[3] = (int)fminf(fmaxf(floorf(vh0 * 20.f + px), 0.f), 20.f);
    o[4] = (int)fminf(fmaxf(floorf(vh1 * 20.f + py), 0.f), 20.f);
    o[5] = (int)fminf(fmaxf(floorf(vh2 * 32.f + pz), 0.f), 32.f);
  }
}

// ---------------------------------------------------------------------------
extern "C" void kernel_launch(void* const* d_in, const int* in_sizes, int n_in,
                              void* d_out, int out_size, void* d_ws, size_t ws_size,
                              hipStream_t stream)
{
  const float* src       = (const float*)d_in[0];
  const float* pos       = (const float*)d_in[1];
  const float* qe        = (const float*)d_in[2];
  const float* sa_in_w   = (const float*)d_in[3];
  const float* sa_in_b   = (const float*)d_in[4];
  const float* sa_out_w  = (const float*)d_in[5];
  const float* sa_out_b  = (const float*)d_in[6];
  const float* ca_k_w    = (const float*)d_in[7];
  const float* ca_v_w    = (const float*)d_in[8];
  const float* ca_proj_w = (const float*)d_in[9];
  const float* ca_proj_b = (const float*)d_in[10];
  const float* ln1_g = (const float*)d_in[11];
  const float* ln1_b = (const float*)d_in[12];
  const float* ln2_g = (const float*)d_in[13];
  const float* ln2_b = (const float*)d_in[14];
  const float* ln3_g = (const float*)d_in[15];
  const float* ln3_b = (const float*)d_in[16];
  const float* ffn_w1 = (const float*)d_in[17];
  const float* ffn_b1 = (const float*)d_in[18];
  const float* ffn_w2 = (const float*)d_in[19];
  const float* ffn_b2 = (const float*)d_in[20];
  const float* reg_w1 = (const float*)d_in[21];
  const float* reg_b1 = (const float*)d_in[22];
  const float* reg_w2 = (const float*)d_in[23];
  const float* reg_b2 = (const float*)d_in[24];
  const float* reg_w3 = (const float*)d_in[25];
  const float* reg_b3 = (const float*)d_in[26];
  const float* anchors   = (const float*)d_in[27];
  const float* attn_area = (const float*)d_in[28];
  float* outp = (float*)d_out;

  float* ws = (float*)d_ws;
  size_t off = 0;
  auto alloc = [&](size_t n) { float* p = ws + off; off += n; return p; };
  __half* Kb = (__half*)alloc((size_t)BB * PP * 128);   // fp16 [b][p][256], 13.1 MB
  __half* Vb = (__half*)alloc((size_t)BB * PP * 128);   // fp16, 13.1 MB
  alloc(2048);                                          // over-read pad
  __half* s16  = (__half*)alloc((size_t)BB * PP * 128); // fp16(src) [b][p][d]
  __half* kv16 = (__half*)alloc((size_t)BB * PP * 128); // fp16(src+pos) [b][p][d]
  __half* kw16 = (__half*)alloc((size_t)LL * DD * DD / 2);
  __half* vw16 = (__half*)alloc((size_t)LL * DD * DD / 2);
  __half* saw16 = (__half*)alloc((size_t)LL * 768 * DD / 2);   // sa_in_w
  __half* sow16 = (__half*)alloc((size_t)LL * DD * DD / 2);    // sa_out_w
  __half* pw16  = (__half*)alloc((size_t)LL * DD * DD / 2);    // ca_proj_w
  __half* f1w16 = (__half*)alloc((size_t)LL * FFD * DD / 2);   // ffn_w1
  __half* f2w16 = (__half*)alloc((size_t)LL * DD * FFD / 2);   // ffn_w2
  __half* r1w16 = (__half*)alloc((size_t)DD * DD / 2);         // reg_w1
  __half* r2w16 = (__half*)alloc((size_t)DD * DD / 2);         // reg_w2
  float* tgt  = alloc((size_t)MR * DD);
  float* qpos = alloc((size_t)MR * DD);
  float* saqk = alloc((size_t)MR * 512);
  float* sav  = alloc((size_t)MR * DD);
  float* sao  = alloc((size_t)MR * DD);
  float* caq  = alloc((size_t)MR * DD);
  float* cao  = alloc((size_t)MR * DD);
  float* mh1  = alloc((size_t)MR * DD);
  float* mh2  = alloc((size_t)MR * DD);
  float* ffh  = alloc((size_t)MR * FFD);
  float* pmb  = alloc((size_t)MR * NSPL * 8);
  float* psb  = alloc((size_t)MR * NSPL * 8);
  float* pob  = alloc((size_t)MR * NSPL * 256);
  int*   lohi = (int*)alloc((size_t)MR * 6);
  alloc(4096);                                          // A over-read pad
  (void)in_sizes; (void)n_in; (void)out_size; (void)ws_size;

  const float FOCUS_H[6] = {0.1f, 0.075f, 0.05f, 0.05f, 0.025f, 0.025f};

  init_kernel<<<1080, 256, 0, stream>>>(qe, tgt, qpos);
  conv_kv_inputs<<<dim3(200, 4, 2), 256, 0, stream>>>(src, pos, s16, kv16);
  conv_w<<<768, 256, 0, stream>>>(ca_k_w, kw16, LL * DD * DD);
  conv_w<<<768, 256, 0, stream>>>(ca_v_w, vw16, LL * DD * DD);
  conv_w<<<768, 256, 0, stream>>>(sa_in_w, saw16, LL * 768 * DD);
  conv_w<<<768, 256, 0, stream>>>(sa_out_w, sow16, LL * DD * DD);
  conv_w<<<768, 256, 0, stream>>>(ca_proj_w, pw16, LL * DD * DD);
  conv_w<<<768, 256, 0, stream>>>(ffn_w1, f1w16, LL * FFD * DD);
  conv_w<<<768, 256, 0, stream>>>(ffn_w2, f2w16, LL * DD * FFD);
  conv_w<<<256, 256, 0, stream>>>(reg_w1, r1w16, DD * DD);
  conv_w<<<256, 256, 0, stream>>>(reg_w2, r2w16, DD * DD);

  for (int i = 0; i < LL; ++i) {
    const __half* wi16 = saw16 + (size_t)i * 768 * DD;
    const float*  bi   = sa_in_b + (size_t)i * 768;
    // SA: q,k from (tgt+qpos), v from tgt
    gemm_rows_mfma<<<dim3(17, 8), 256, 0, stream>>>(tgt, qpos, wi16, bi, nullptr, saqk, MR, 512, DD, 0);
    gemm_rows_mfma<<<dim3(17, 4), 256, 0, stream>>>(tgt, nullptr, wi16 + 512 * DD, bi + 512, nullptr, sav, MR, DD, DD, 0);
    sa_attn<<<MR, 512, 0, stream>>>(saqk, sav, sao);
    gemm_ln_mfma<<<17, 512, 0, stream>>>(sao, sow16 + (size_t)i * DD * DD,
                                         sa_out_b + (size_t)i * DD, tgt,
                                         ln2_g + i * DD, ln2_b + i * DD, tgt, MR, DD);

    // mask boxes
    if (i == 0) {
      mask0_kernel<<<5, 256, 0, stream>>>(attn_area, lohi,
          FOCUS_H[0] * PS0, FOCUS_H[0] * PS1, FOCUS_H[0] * PS2);
    } else {
      gemm_rows_mfma<<<dim3(17, 4), 256, 0, stream>>>(tgt, nullptr, r1w16, reg_b1, nullptr, mh1, MR, DD, DD, 1);
      gemm_rows_mfma<<<dim3(17, 4), 256, 0, stream>>>(mh1, nullptr, r2w16, reg_b2, nullptr, mh2, MR, DD, DD, 1);
      mask_reg_kernel<<<270, 256, 0, stream>>>(mh2, reg_w3, reg_b3, anchors, lohi,
          FOCUS_H[i] * PS0, FOCUS_H[i] * PS1, FOCUS_H[i] * PS2);
    }

    // CA: q from (tgt+qpos)@ca_k_w; K from (src+pos)@ca_k_w; V from src@ca_v_w
    gemm_rows_mfma<<<dim3(17, 4), 256, 0, stream>>>(tgt, qpos, kw16 + (size_t)i * DD * DD,
                                                    nullptr, nullptr, caq, MR, DD, DD, 0);
    gemm_kv2_mfma<<<dim3(100, 2, 4), 256, 0, stream>>>(kv16, s16,
                                                       kw16 + (size_t)i * DD * DD,
                                                       vw16 + (size_t)i * DD * DD, Kb, Vb);
    ca_attn_part<<<MR * NSPL, 512, 0, stream>>>(caq, Kb, Vb, lohi, pmb, psb, pob);
    ca_merge<<<270, 256, 0, stream>>>(pmb, psb, pob, cao);
    gemm_ln_mfma<<<17, 512, 0, stream>>>(cao, pw16 + (size_t)i * DD * DD,
                                         ca_proj_b + (size_t)i * DD, tgt,
                                         ln1_g + i * DD, ln1_b + i * DD, tgt, MR, DD);

    // FFN
    gemm_rows_mfma<<<dim3(17, 16), 256, 0, stream>>>(tgt, nullptr, f1w16 + (size_t)i * FFD * DD,
                                                     ffn_b1 + (size_t)i * FFD, nullptr, ffh, MR, FFD, DD, 1);
    float* lno = (i == LL - 1) ? outp : tgt;
    gemm_ln_mfma<<<17, 512, 0, stream>>>(ffh, f2w16 + (size_t)i * DD * FFD,
                                         ffn_b2 + (size_t)i * DD, tgt,
                                         ln3_g + i * DD, ln3_b + i * DD, lno, MR, FFD);
  }
}

// Round 15
// 1809.144 us; speedup vs baseline: 1.0976x; 1.0976x over previous
//
#include <hip/hip_runtime.h>
#include <hip/hip_fp16.h>
#include <math.h>

#define BB 2
#define DD 256
#define HH 8
#define HDIM 32
#define FFD 1024
#define LL 6
#define NQQ 540
#define QPO_ 27
#define PS0 20
#define PS1 20
#define PS2 32
#define PP (PS0*PS1*PS2)   // 12800
#define MR (BB*NQQ)        // 1080
#define NSPL 8             // cross-attn row-partials per query (4-wave blocks)

typedef _Float16 half8 __attribute__((ext_vector_type(8)));
typedef _Float16 h2v  __attribute__((ext_vector_type(2)));
typedef float f32x4 __attribute__((ext_vector_type(4)));

static __device__ __forceinline__ float wred_sum(float x) {
#pragma unroll
  for (int off = 32; off; off >>= 1) x += __shfl_xor(x, off, 64);
  return x;
}
static __device__ __forceinline__ float4 h4_to_f4(uint2 u) {
  __half2 h0 = *reinterpret_cast<__half2*>(&u.x);
  __half2 h1 = *reinterpret_cast<__half2*>(&u.y);
  float2 f0 = __half22float2(h0);
  float2 f1 = __half22float2(h1);
  return make_float4(f0.x, f0.y, f1.x, f1.y);
}
static __device__ __forceinline__ float dot4h(uint2 kw, h2v q01, h2v q23) {
  h2v a = *reinterpret_cast<h2v*>(&kw.x);
  h2v b = *reinterpret_cast<h2v*>(&kw.y);
  float d = __builtin_amdgcn_fdot2(a, q01, 0.f, false);
  return __builtin_amdgcn_fdot2(b, q23, d, false);
}

// ---------------------------------------------------------------------------
// init: tgt[b,q,d] = qe[q, 256+d]; qpos[b,q,d] = qe[q, d]
__global__ __launch_bounds__(256) void init_kernel(
    const float* __restrict__ qe, float* __restrict__ tgt, float* __restrict__ qpos)
{
  int idx = blockIdx.x * 256 + threadIdx.x;   // < B*NQ*D == 276480
  int d = idx % DD;
  int q = (idx / DD) % NQQ;
  qpos[idx] = qe[q * 512 + d];
  tgt[idx]  = qe[q * 512 + 256 + d];
}

// ---------------------------------------------------------------------------
// One-time: transpose+convert src/pos to fp16 [b][p][d] layouts.
__global__ __launch_bounds__(256) void conv_kv_inputs(
    const float* __restrict__ src, const float* __restrict__ pos,
    __half* __restrict__ s16, __half* __restrict__ kv16)
{
  __shared__ float ls[64][65];
  __shared__ float lk[64][65];
  int b  = blockIdx.z;
  int p0 = blockIdx.x * 64;
  int d0 = blockIdx.y * 64;
  int t = threadIdx.x;
  int pr = (t & 15) * 4;
  int dr = t >> 4;
#pragma unroll
  for (int dd = 0; dd < 64; dd += 16) {
    int d = d0 + dd + dr;
    float4 sv = *(const float4*)&src[((size_t)b * DD + d) * PP + p0 + pr];
    float4 pv = *(const float4*)&pos[((size_t)b * DD + d) * PP + p0 + pr];
    ls[pr + 0][dd + dr] = sv.x; ls[pr + 1][dd + dr] = sv.y;
    ls[pr + 2][dd + dr] = sv.z; ls[pr + 3][dd + dr] = sv.w;
    lk[pr + 0][dd + dr] = sv.x + pv.x; lk[pr + 1][dd + dr] = sv.y + pv.y;
    lk[pr + 2][dd + dr] = sv.z + pv.z; lk[pr + 3][dd + dr] = sv.w + pv.w;
  }
  __syncthreads();
  int wp = t >> 2;
  int wd = (t & 3) * 16;
  size_t base = ((size_t)b * PP + p0 + wp) * 256 + d0 + wd;
#pragma unroll
  for (int i = 0; i < 16; i += 2) {
    *(__half2*)&s16[base + i]  = __floats2half2_rn(ls[wp][wd + i], ls[wp][wd + i + 1]);
    *(__half2*)&kv16[base + i] = __floats2half2_rn(lk[wp][wd + i], lk[wp][wd + i + 1]);
  }
}

// One-time: fp32 -> fp16 weight conversion (grid-stride).
__global__ __launch_bounds__(256) void conv_w(
    const float* __restrict__ w, __half* __restrict__ w16, int n)
{
  for (int i = blockIdx.x * 256 + threadIdx.x; i < n; i += gridDim.x * 256)
    w16[i] = __float2half_rn(w[i]);
}

// ---------------------------------------------------------------------------
// Merged MFMA K&V projection: z>>1 selects (A,W,out) pair, z&1 = batch b.
__global__ __launch_bounds__(256) void gemm_kv2_mfma(
    const __half* __restrict__ Ak, const __half* __restrict__ Av,
    const __half* __restrict__ Wk, const __half* __restrict__ Wv,
    __half* __restrict__ Ko, __half* __restrict__ Vo)
{
  int z = blockIdx.z;
  int b = z & 1;
  const __half* A = (z >> 1) ? Av : Ak;
  const __half* W = (z >> 1) ? Wv : Wk;
  __half* out     = (z >> 1) ? Vo : Ko;
  int wid = threadIdx.x >> 6;
  int lane = threadIdx.x & 63;
  int p0 = blockIdx.x * 128 + (wid >> 1) * 64;
  int n0 = blockIdx.y * 128 + (wid & 1) * 64;
  const __half* Ab = A + (size_t)b * PP * 256;
  int row = lane & 15;
  int kg  = lane >> 4;
  f32x4 acc[4][4] = {};
  for (int k0 = 0; k0 < 256; k0 += 32) {
    half8 af[4], bf[4];
#pragma unroll
    for (int i = 0; i < 4; ++i)
      af[i] = *(const half8*)&Ab[((size_t)(p0 + 16 * i + row)) * 256 + k0 + kg * 8];
#pragma unroll
    for (int j = 0; j < 4; ++j)
      bf[j] = *(const half8*)&W[((size_t)(n0 + 16 * j + row)) * 256 + k0 + kg * 8];
#pragma unroll
    for (int i = 0; i < 4; ++i)
#pragma unroll
      for (int j = 0; j < 4; ++j)
        acc[i][j] = __builtin_amdgcn_mfma_f32_16x16x32_f16(af[i], bf[j], acc[i][j], 0, 0, 0);
  }
#pragma unroll
  for (int i = 0; i < 4; ++i)
#pragma unroll
    for (int j = 0; j < 4; ++j) {
      int nc = n0 + 16 * j + row;
#pragma unroll
      for (int r = 0; r < 4; ++r) {
        int pr = p0 + 16 * i + kg * 4 + r;
        out[((size_t)b * PP + pr) * 256 + nc] = __float2half_rn(acc[i][j][r]);
      }
    }
}

// ---------------------------------------------------------------------------
// MFMA row GEMM: C[r,n] = (A1[r,:](+A2[r,:])) @ W16[n,:] (+bias)(+res)(relu).
__global__ __launch_bounds__(256) void gemm_rows_mfma(
    const float* __restrict__ A1, const float* __restrict__ A2,
    const __half* __restrict__ W, const float* __restrict__ bias,
    const float* __restrict__ res, float* __restrict__ C,
    int M, int N, int K, int relu)
{
  __shared__ __half a_s[64][40];   // row stride 80B (16B-mult): aligned half8 ops
  int bm = blockIdx.x * 64;
  int bn = blockIdx.y * 64;
  int wv = threadIdx.x >> 6;
  int lane = threadIdx.x & 63;
  int row = lane & 15;
  int kg  = lane >> 4;
  int nw  = bn + wv * 16;
  int t = threadIdx.x;
  int srow = t >> 2, skq = (t & 3) * 8;
  f32x4 acc[4] = {};

  for (int k0 = 0; k0 < K; k0 += 32) {
    { // stage A tile (64 rows x 32 k) as fp16; over-read rows land in ws
      size_t off = (size_t)(bm + srow) * K + k0 + skq;
      float4 a0 = *(const float4*)&A1[off];
      float4 a1 = *(const float4*)&A1[off + 4];
      if (A2) {
        float4 b0 = *(const float4*)&A2[off];
        float4 b1 = *(const float4*)&A2[off + 4];
        a0.x += b0.x; a0.y += b0.y; a0.z += b0.z; a0.w += b0.w;
        a1.x += b1.x; a1.y += b1.y; a1.z += b1.z; a1.w += b1.w;
      }
      half8 h;
      h[0] = (_Float16)a0.x; h[1] = (_Float16)a0.y;
      h[2] = (_Float16)a0.z; h[3] = (_Float16)a0.w;
      h[4] = (_Float16)a1.x; h[5] = (_Float16)a1.y;
      h[6] = (_Float16)a1.z; h[7] = (_Float16)a1.w;
      *(half8*)&a_s[srow][skq] = h;
    }
    __syncthreads();
    half8 bf = *(const half8*)&W[(size_t)(nw + row) * K + k0 + kg * 8];
#pragma unroll
    for (int i = 0; i < 4; ++i) {
      half8 af = *(const half8*)&a_s[16 * i + row][kg * 8];
      acc[i] = __builtin_amdgcn_mfma_f32_16x16x32_f16(af, bf, acc[i], 0, 0, 0);
    }
    __syncthreads();
  }

  int col = nw + row;
  float bval = bias ? bias[col] : 0.f;
#pragma unroll
  for (int i = 0; i < 4; ++i) {
#pragma unroll
    for (int r = 0; r < 4; ++r) {
      int rr = bm + 16 * i + kg * 4 + r;
      if (rr >= M) continue;
      float v = acc[i][r] + bval;
      if (relu) v = fmaxf(v, 0.f);
      if (res)  v += res[(size_t)rr * N + col];
      C[(size_t)rr * N + col] = v;
    }
  }
}

// ---------------------------------------------------------------------------
// Self-attention, all-heads-batched. One block (8 waves) per (b,q). fp32 K/V.
__global__ __launch_bounds__(512) void sa_attn(
    const float* __restrict__ qkbuf, const float* __restrict__ vbuf,
    float* __restrict__ out)
{
  __shared__ float wmS[8][8];
  __shared__ float wsS[8][8];
  __shared__ float4 ooS[8][64];

  int bid = blockIdx.x;           // b*NQQ + q
  int b = bid / NQQ;
  int wv = threadIdx.x >> 6;
  int lane = threadIdx.x & 63;
  const float scale = 0.17677669529663687f;  // 32^-0.5

  float4 q4 = ((const float4*)(qkbuf + (size_t)bid * 512))[lane];
  q4.x *= scale; q4.y *= scale; q4.z *= scale; q4.w *= scale;

  const float* Kb = qkbuf + (size_t)b * NQQ * 512 + 256;  // k part of rows
  const float* Vb = vbuf + (size_t)b * NQQ * 256;

  float m = -INFINITY, s = 0.f;
  float4 o4 = make_float4(0.f, 0.f, 0.f, 0.f);

  for (int k0 = wv * 8; k0 < NQQ; k0 += 64) {
    const float4* kp = (const float4*)(Kb + (size_t)k0 * 512) + lane;
    const float4* vp = (const float4*)(Vb + (size_t)k0 * 256) + lane;
    float4 kk[8];
#pragma unroll
    for (int i = 0; i < 8; ++i) kk[i] = kp[i * 128];
    float lg[8];
#pragma unroll
    for (int i = 0; i < 8; ++i) {
      float d = q4.x * kk[i].x;
      d = fmaf(q4.y, kk[i].y, d);
      d = fmaf(q4.z, kk[i].z, d);
      d = fmaf(q4.w, kk[i].w, d);
      d += __shfl_xor(d, 1, 64);
      d += __shfl_xor(d, 2, 64);
      d += __shfl_xor(d, 4, 64);
      lg[i] = (k0 + i < NQQ) ? d : -INFINITY;
    }
    float4 vv[8];
#pragma unroll
    for (int i = 0; i < 8; ++i) vv[i] = vp[i * 64];

    float bm = fmaxf(fmaxf(fmaxf(lg[0], lg[1]), fmaxf(lg[2], lg[3])),
                     fmaxf(fmaxf(lg[4], lg[5]), fmaxf(lg[6], lg[7])));
    float mn = fmaxf(m, bm);
    float f = __expf(m - mn);        // first batch: m=-inf -> f=0
    s *= f; o4.x *= f; o4.y *= f; o4.z *= f; o4.w *= f;
    m = mn;
#pragma unroll
    for (int i = 0; i < 8; ++i) {
      float p = __expf(lg[i] - mn);  // tail lg=-inf -> 0
      s += p;
      o4.x = fmaf(p, vv[i].x, o4.x);
      o4.y = fmaf(p, vv[i].y, o4.y);
      o4.z = fmaf(p, vv[i].z, o4.z);
      o4.w = fmaf(p, vv[i].w, o4.w);
    }
  }

  // ---- merge 8 wave-states (per head) ----
  int hg = lane >> 3, sub = lane & 7;
  if (sub == 0) wmS[wv][hg] = m;
  __syncthreads();
  float M = wmS[0][hg];
#pragma unroll
  for (int w = 1; w < 8; ++w) M = fmaxf(M, wmS[w][hg]);
  float f = __expf(m - M);
  if (sub == 0) wsS[wv][hg] = s * f;
  ooS[wv][lane] = make_float4(o4.x * f, o4.y * f, o4.z * f, o4.w * f);
  __syncthreads();
  if (threadIdx.x < 64) {
    int l = threadIdx.x;
    int hg2 = l >> 3;
    float4 acc = make_float4(0.f, 0.f, 0.f, 0.f);
    float den = 0.f;
#pragma unroll
    for (int w = 0; w < 8; ++w) {
      float4 t = ooS[w][l];
      acc.x += t.x; acc.y += t.y; acc.z += t.z; acc.w += t.w;
      den += wsS[w][hg2];
    }
    float inv = 1.f / den;
    float4 res = make_float4(acc.x * inv, acc.y * inv, acc.z * inv, acc.w * inv);
    *(float4*)&out[(size_t)bid * 256 + l * 4] = res;
  }
}

// ---------------------------------------------------------------------------
// Cross-attention partial (R9 inner loop — best measured), repacked:
// 256-thr (4-wave) blocks, NSPL=8 parts per query -> grid 8640. Finer
// scheduling quanta + flatter tail; row partition r = part + 8*wv + 32*j.
__global__ __launch_bounds__(256) void ca_attn_part(
    const float* __restrict__ qbuf, const __half* __restrict__ Kbuf,
    const __half* __restrict__ Vbuf, const int* __restrict__ lohi,
    float* __restrict__ pm, float* __restrict__ ps, float* __restrict__ po)
{
  __shared__ float wmS[4][8];
  __shared__ float wsS[4][8];
  __shared__ float4 ooS[4][64];

  // --- swizzle: 8640 blocks = 8 cls x 5 gsub x 27 iq x 8 part ---
  int idx  = blockIdx.x;
  int cls  = idx & 7;
  int rest = idx >> 3;          // 0..1079
  int gsub = rest / 216;        // 0..4
  int rem  = rest % 216;
  int iq   = rem >> 3;          // 0..26
  int part = rem & 7;           // NSPL == 8
  int g    = gsub * 8 + cls;    // organ-group 0..39
  int b    = g / 20;
  int q    = (g % 20) * QPO_ + iq;
  int bid  = b * NQQ + q;

  int wv = threadIdx.x >> 6;    // 0..3
  int lane = threadIdx.x & 63;
  const float scale = 0.17677669529663687f;

  const int* lh = lohi + (size_t)bid * 6;
  int lo0 = lh[0], lo1 = lh[1], lo2 = lh[2];
  int nx = lh[3] - lo0, ny = lh[4] - lo1, nz = lh[5] - lo2;
  int nxy = nx * ny;
  float inv_ny = 1.0f / (float)ny;

  float4 q4 = ((const float4*)(qbuf + (size_t)bid * 256))[lane];
  q4.x *= scale; q4.y *= scale; q4.z *= scale; q4.w *= scale;
  h2v q01, q23;
  q01[0] = (_Float16)q4.x; q01[1] = (_Float16)q4.y;
  q23[0] = (_Float16)q4.z; q23[1] = (_Float16)q4.w;

  const __half* Kb = Kbuf + (size_t)b * PP * 256;
  const __half* Vb = Vbuf + (size_t)b * PP * 256;

  float m = -INFINITY, sA = 0.f, sB = 0.f;
  float4 oA = make_float4(0.f, 0.f, 0.f, 0.f);
  float4 oB = make_float4(0.f, 0.f, 0.f, 0.f);

  for (int r = part + 8 * wv; r < nxy; r += 32) {
    int x = (int)((float)r * inv_ny);
    int y = r - x * ny;
    if (y < 0)        { x--; y += ny; }
    else if (y >= ny) { x++; y -= ny; }
    int base = (lo0 + x) * (PS1 * PS2) + (lo1 + y) * PS2 + lo2;

    for (int z0 = 0; z0 < nz; z0 += 8) {
      const uint2* kp = (const uint2*)(Kb + ((size_t)base + z0) * 256) + lane;
      const uint2* vp = (const uint2*)(Vb + ((size_t)base + z0) * 256) + lane;
      uint2 kw[8];
#pragma unroll
      for (int i = 0; i < 8; ++i) kw[i] = kp[i * 64];   // row stride 256 halfs
      uint2 vw[8];
#pragma unroll
      for (int i = 0; i < 8; ++i) vw[i] = vp[i * 64];

      float lg[8];
#pragma unroll
      for (int i = 0; i < 8; ++i) {
        float d = dot4h(kw[i], q01, q23);
        d += __shfl_xor(d, 1, 64);
        d += __shfl_xor(d, 2, 64);
        d += __shfl_xor(d, 4, 64);
        lg[i] = (z0 + i < nz) ? d : -INFINITY;
      }

      float bm = fmaxf(fmaxf(fmaxf(lg[0], lg[1]), fmaxf(lg[2], lg[3])),
                       fmaxf(fmaxf(lg[4], lg[5]), fmaxf(lg[6], lg[7])));
      float mn = fmaxf(m, bm);
      float f = __expf(m - mn);      // first batch: m=-inf -> f=0
      sA *= f; sB *= f;
      oA.x *= f; oA.y *= f; oA.z *= f; oA.w *= f;
      oB.x *= f; oB.y *= f; oB.z *= f; oB.w *= f;
      m = mn;
#pragma unroll
      for (int i = 0; i < 8; i += 2) {
        float pa = __expf(lg[i] - mn);      // masked -inf -> 0
        float pb = __expf(lg[i + 1] - mn);
        float4 va = h4_to_f4(vw[i]);
        float4 vb = h4_to_f4(vw[i + 1]);
        sA += pa; sB += pb;
        oA.x = fmaf(pa, va.x, oA.x); oB.x = fmaf(pb, vb.x, oB.x);
        oA.y = fmaf(pa, va.y, oA.y); oB.y = fmaf(pb, vb.y, oB.y);
        oA.z = fmaf(pa, va.z, oA.z); oB.z = fmaf(pb, vb.z, oB.z);
        oA.w = fmaf(pa, va.w, oA.w); oB.w = fmaf(pb, vb.w, oB.w);
      }
    }
  }

  float s = sA + sB;
  float4 o4 = make_float4(oA.x + oB.x, oA.y + oB.y, oA.z + oB.z, oA.w + oB.w);

  // ---- merge this block's 4 wave-states; write partial (M, S, O) ----
  int hg = lane >> 3, sub = lane & 7;
  if (sub == 0) wmS[wv][hg] = m;
  __syncthreads();
  float M = wmS[0][hg];
#pragma unroll
  for (int w = 1; w < 4; ++w) M = fmaxf(M, wmS[w][hg]);
  float f = (M == -INFINITY) ? 0.f : __expf(m - M);  // empty part -> zeros
  if (sub == 0) wsS[wv][hg] = s * f;
  ooS[wv][lane] = make_float4(o4.x * f, o4.y * f, o4.z * f, o4.w * f);
  __syncthreads();
  if (threadIdx.x < 64) {
    int l = threadIdx.x;
    int hg2 = l >> 3;
    float4 acc = make_float4(0.f, 0.f, 0.f, 0.f);
    float den = 0.f;
#pragma unroll
    for (int w = 0; w < 4; ++w) {
      float4 t = ooS[w][l];
      acc.x += t.x; acc.y += t.y; acc.z += t.z; acc.w += t.w;
      den += wsS[w][hg2];
    }
    float M2 = wmS[0][hg2];
#pragma unroll
    for (int w = 1; w < 4; ++w) M2 = fmaxf(M2, wmS[w][hg2]);
    size_t pb = (size_t)bid * NSPL + part;
    if ((l & 7) == 0) { pm[pb * 8 + hg2] = M2; ps[pb * 8 + hg2] = den; }
    *(float4*)&po[pb * 256 + l * 4] = acc;
  }
}

// ---------------------------------------------------------------------------
// Merge NSPL cross-attn partials per query. One wave per (b,q).
__global__ __launch_bounds__(256) void ca_merge(
    const float* __restrict__ pm, const float* __restrict__ ps,
    const float* __restrict__ po, float* __restrict__ out)
{
  int wv = threadIdx.x >> 6;
  int lane = threadIdx.x & 63;
  int bid = blockIdx.x * 4 + wv;
  int hg = lane >> 3;
  size_t pb = (size_t)bid * NSPL;

  float mp[NSPL], sp[NSPL];
#pragma unroll
  for (int p = 0; p < NSPL; ++p) {
    mp[p] = pm[(pb + p) * 8 + hg];
    sp[p] = ps[(pb + p) * 8 + hg];
  }
  float M = mp[0];
#pragma unroll
  for (int p = 1; p < NSPL; ++p) M = fmaxf(M, mp[p]);
  float den = 0.f;
  float4 acc = make_float4(0.f, 0.f, 0.f, 0.f);
#pragma unroll
  for (int p = 0; p < NSPL; ++p) {
    float f = __expf(mp[p] - M);     // empty part m=-inf -> 0
    den = fmaf(f, sp[p], den);
    float4 t = *(const float4*)&po[(pb + p) * 256 + lane * 4];
    acc.x = fmaf(f, t.x, acc.x);
    acc.y = fmaf(f, t.y, acc.y);
    acc.z = fmaf(f, t.z, acc.z);
    acc.w = fmaf(f, t.w, acc.w);
  }
  float inv = 1.f / den;
  float4 res = make_float4(acc.x * inv, acc.y * inv, acc.z * inv, acc.w * inv);
  *(float4*)&out[(size_t)bid * 256 + lane * 4] = res;
}

// ---------------------------------------------------------------------------
// LayerNorm over D=256: one wave per row. x already contains residual sum.
__global__ __launch_bounds__(256) void ln_kernel(
    const float* __restrict__ x, const float* __restrict__ g,
    const float* __restrict__ bta, float* __restrict__ out)
{
  int wv = threadIdx.x >> 6;
  int lane = threadIdx.x & 63;
  int row = blockIdx.x * 4 + wv;
  const float* xr = x + (size_t)row * 256;
  float v[4];
#pragma unroll
  for (int j = 0; j < 4; ++j) v[j] = xr[lane + 64 * j];
  float s = v[0] + v[1] + v[2] + v[3];
  s = wred_sum(s);
  float mean = s * (1.f / 256.f);
  float vs = 0.f;
#pragma unroll
  for (int j = 0; j < 4; ++j) { float d = v[j] - mean; vs = fmaf(d, d, vs); }
  vs = wred_sum(vs);
  float inv = rsqrtf(vs * (1.f / 256.f) + 1e-5f);
  float* orow = out + (size_t)row * 256;
#pragma unroll
  for (int j = 0; j < 4; ++j) {
    int c = lane + 64 * j;
    orow[c] = (v[j] - mean) * inv * g[c] + bta[c];
  }
}

// ---------------------------------------------------------------------------
// Layer-0 mask boxes from attn_area.
__global__ __launch_bounds__(256) void mask0_kernel(
    const float* __restrict__ area, int* __restrict__ lohi,
    float px, float py, float pz)
{
  int row = blockIdx.x * 256 + threadIdx.x;
  if (row >= MR) return;
  int q = row % NQQ;
  int org = q / QPO_;
  const float* a = area + org * 6;
  int* o = lohi + (size_t)row * 6;
  o[0] = (int)fminf(fmaxf(floorf(a[0] * 20.f - px), 0.f), 20.f);
  o[1] = (int)fminf(fmaxf(floorf(a[1] * 20.f - py), 0.f), 20.f);
  o[2] = (int)fminf(fmaxf(floorf(a[2] * 32.f - pz), 0.f), 32.f);
  o[3] = (int)fminf(fmaxf(floorf(a[3] * 20.f + px), 0.f), 20.f);
  o[4] = (int)fminf(fmaxf(floorf(a[4] * 20.f + py), 0.f), 20.f);
  o[5] = (int)fminf(fmaxf(floorf(a[5] * 32.f + pz), 0.f), 32.f);
}

// ---------------------------------------------------------------------------
// Layers >=1: prop = h2 @ w3.T + b3 -> tanh*0.1 + anchors -> clip -> box ints.
__global__ __launch_bounds__(256) void mask_reg_kernel(
    const float* __restrict__ h2, const float* __restrict__ w3,
    const float* __restrict__ b3, const float* __restrict__ anchors,
    int* __restrict__ lohi, float px, float py, float pz)
{
  int wv = threadIdx.x >> 6;
  int lane = threadIdx.x & 63;
  int row = blockIdx.x * 4 + wv;
  int q = row % NQQ;
  const float* hr = h2 + (size_t)row * 256;
  float part[6] = {};
#pragma unroll
  for (int j = 0; j < 4; ++j) {
    float hv = hr[lane + 64 * j];
#pragma unroll
    for (int o = 0; o < 6; ++o)
      part[o] = fmaf(hv, w3[o * 256 + lane + 64 * j], part[o]);
  }
#pragma unroll
  for (int o = 0; o < 6; ++o) part[o] = wred_sum(part[o]);
  if (lane == 0) {
    float prop[6];
#pragma unroll
    for (int o = 0; o < 6; ++o) {
      float v = tanhf(part[o] + b3[o]) * 0.1f + anchors[q * 6 + o];
      prop[o] = fminf(fmaxf(v, 0.f), 1.f);
    }
    float vl0 = prop[0] - 0.5f * prop[3], vh0 = prop[0] + 0.5f * prop[3];
    float vl1 = prop[1] - 0.5f * prop[4], vh1 = prop[1] + 0.5f * prop[4];
    float vl2 = prop[2] - 0.5f * prop[5], vh2 = prop[2] + 0.5f * prop[5];
    int* o = lohi + (size_t)row * 6;
    o[0] = (int)fminf(fmaxf(floorf(vl0 * 20.f - px), 0.f), 20.f);
    o[1] = (int)fminf(fmaxf(floorf(vl1 * 20.f - py), 0.f), 20.f);
    o[2] = (int)fminf(fmaxf(floorf(vl2 * 32.f - pz), 0.f), 32.f);
    o[3] = (int)fminf(fmaxf(floorf(vh0 * 20.f + px), 0.f), 20.f);
    o[4] = (int)fminf(fmaxf(floorf(vh1 * 20.f + py), 0.f), 20.f);
    o[5] = (int)fminf(fmaxf(floorf(vh2 * 32.f + pz), 0.f), 32.f);
  }
}

// ---------------------------------------------------------------------------
extern "C" void kernel_launch(void* const* d_in, const int* in_sizes, int n_in,
                              void* d_out, int out_size, void* d_ws, size_t ws_size,
                              hipStream_t stream)
{
  const float* src       = (const float*)d_in[0];
  const float* pos       = (const float*)d_in[1];
  const float* qe        = (const float*)d_in[2];
  const float* sa_in_w   = (const float*)d_in[3];
  const float* sa_in_b   = (const float*)d_in[4];
  const float* sa_out_w  = (const float*)d_in[5];
  const float* sa_out_b  = (const float*)d_in[6];
  const float* ca_k_w    = (const float*)d_in[7];
  const float* ca_v_w    = (const float*)d_in[8];
  const float* ca_proj_w = (const float*)d_in[9];
  const float* ca_proj_b = (const float*)d_in[10];
  const float* ln1_g = (const float*)d_in[11];
  const float* ln1_b = (const float*)d_in[12];
  const float* ln2_g = (const float*)d_in[13];
  const float* ln2_b = (const float*)d_in[14];
  const float* ln3_g = (const float*)d_in[15];
  const float* ln3_b = (const float*)d_in[16];
  const float* ffn_w1 = (const float*)d_in[17];
  const float* ffn_b1 = (const float*)d_in[18];
  const float* ffn_w2 = (const float*)d_in[19];
  const float* ffn_b2 = (const float*)d_in[20];
  const float* reg_w1 = (const float*)d_in[21];
  const float* reg_b1 = (const float*)d_in[22];
  const float* reg_w2 = (const float*)d_in[23];
  const float* reg_b2 = (const float*)d_in[24];
  const float* reg_w3 = (const float*)d_in[25];
  const float* reg_b3 = (const float*)d_in[26];
  const float* anchors   = (const float*)d_in[27];
  const float* attn_area = (const float*)d_in[28];
  float* outp = (float*)d_out;

  float* ws = (float*)d_ws;
  size_t off = 0;
  auto alloc = [&](size_t n) { float* p = ws + off; off += n; return p; };
  __half* Kb = (__half*)alloc((size_t)BB * PP * 128);   // fp16 [b][p][256], 13.1 MB
  __half* Vb = (__half*)alloc((size_t)BB * PP * 128);   // fp16, 13.1 MB
  alloc(2048);                                          // over-read pad
  __half* s16  = (__half*)alloc((size_t)BB * PP * 128); // fp16(src) [b][p][d]
  __half* kv16 = (__half*)alloc((size_t)BB * PP * 128); // fp16(src+pos) [b][p][d]
  __half* kw16 = (__half*)alloc((size_t)LL * DD * DD / 2);
  __half* vw16 = (__half*)alloc((size_t)LL * DD * DD / 2);
  __half* saw16 = (__half*)alloc((size_t)LL * 768 * DD / 2);   // sa_in_w
  __half* sow16 = (__half*)alloc((size_t)LL * DD * DD / 2);    // sa_out_w
  __half* pw16  = (__half*)alloc((size_t)LL * DD * DD / 2);    // ca_proj_w
  __half* f1w16 = (__half*)alloc((size_t)LL * FFD * DD / 2);   // ffn_w1
  __half* f2w16 = (__half*)alloc((size_t)LL * DD * FFD / 2);   // ffn_w2
  __half* r1w16 = (__half*)alloc((size_t)DD * DD / 2);         // reg_w1
  __half* r2w16 = (__half*)alloc((size_t)DD * DD / 2);         // reg_w2
  float* tgt  = alloc((size_t)MR * DD);
  float* qpos = alloc((size_t)MR * DD);
  float* tmp  = alloc((size_t)MR * DD);
  float* saqk = alloc((size_t)MR * 512);
  float* sav  = alloc((size_t)MR * DD);
  float* sao  = alloc((size_t)MR * DD);
  float* caq  = alloc((size_t)MR * DD);
  float* cao  = alloc((size_t)MR * DD);
  float* mh1  = alloc((size_t)MR * DD);
  float* mh2  = alloc((size_t)MR * DD);
  float* ffh  = alloc((size_t)MR * FFD);
  float* pmb  = alloc((size_t)MR * NSPL * 8);
  float* psb  = alloc((size_t)MR * NSPL * 8);
  float* pob  = alloc((size_t)MR * NSPL * 256);
  int*   lohi = (int*)alloc((size_t)MR * 6);
  alloc(4096);                                          // A over-read pad
  (void)in_sizes; (void)n_in; (void)out_size; (void)ws_size;

  const float FOCUS_H[6] = {0.1f, 0.075f, 0.05f, 0.05f, 0.025f, 0.025f};

  init_kernel<<<1080, 256, 0, stream>>>(qe, tgt, qpos);
  conv_kv_inputs<<<dim3(200, 4, 2), 256, 0, stream>>>(src, pos, s16, kv16);
  conv_w<<<768, 256, 0, stream>>>(ca_k_w, kw16, LL * DD * DD);
  conv_w<<<768, 256, 0, stream>>>(ca_v_w, vw16, LL * DD * DD);
  conv_w<<<768, 256, 0, stream>>>(sa_in_w, saw16, LL * 768 * DD);
  conv_w<<<768, 256, 0, stream>>>(sa_out_w, sow16, LL * DD * DD);
  conv_w<<<768, 256, 0, stream>>>(ca_proj_w, pw16, LL * DD * DD);
  conv_w<<<768, 256, 0, stream>>>(ffn_w1, f1w16, LL * FFD * DD);
  conv_w<<<768, 256, 0, stream>>>(ffn_w2, f2w16, LL * DD * FFD);
  conv_w<<<256, 256, 0, stream>>>(reg_w1, r1w16, DD * DD);
  conv_w<<<256, 256, 0, stream>>>(reg_w2, r2w16, DD * DD);

  for (int i = 0; i < LL; ++i) {
    const __half* wi16 = saw16 + (size_t)i * 768 * DD;
    const float*  bi   = sa_in_b + (size_t)i * 768;
    // SA: q,k from (tgt+qpos), v from tgt
    gemm_rows_mfma<<<dim3(17, 8), 256, 0, stream>>>(tgt, qpos, wi16, bi, nullptr, saqk, MR, 512, DD, 0);
    gemm_rows_mfma<<<dim3(17, 4), 256, 0, stream>>>(tgt, nullptr, wi16 + 512 * DD, bi + 512, nullptr, sav, MR, DD, DD, 0);
    sa_attn<<<MR, 512, 0, stream>>>(saqk, sav, sao);
    gemm_rows_mfma<<<dim3(17, 4), 256, 0, stream>>>(sao, nullptr, sow16 + (size_t)i * DD * DD,
                                                    sa_out_b + (size_t)i * DD, tgt, tmp, MR, DD, DD, 0);
    ln_kernel<<<270, 256, 0, stream>>>(tmp, ln2_g + i * DD, ln2_b + i * DD, tgt);

    // mask boxes
    if (i == 0) {
      mask0_kernel<<<5, 256, 0, stream>>>(attn_area, lohi,
          FOCUS_H[0] * PS0, FOCUS_H[0] * PS1, FOCUS_H[0] * PS2);
    } else {
      gemm_rows_mfma<<<dim3(17, 4), 256, 0, stream>>>(tgt, nullptr, r1w16, reg_b1, nullptr, mh1, MR, DD, DD, 1);
      gemm_rows_mfma<<<dim3(17, 4), 256, 0, stream>>>(mh1, nullptr, r2w16, reg_b2, nullptr, mh2, MR, DD, DD, 1);
      mask_reg_kernel<<<270, 256, 0, stream>>>(mh2, reg_w3, reg_b3, anchors, lohi,
          FOCUS_H[i] * PS0, FOCUS_H[i] * PS1, FOCUS_H[i] * PS2);
    }

    // CA: q from (tgt+qpos)@ca_k_w; K from (src+pos)@ca_k_w; V from src@ca_v_w
    gemm_rows_mfma<<<dim3(17, 4), 256, 0, stream>>>(tgt, qpos, kw16 + (size_t)i * DD * DD,
                                                    nullptr, nullptr, caq, MR, DD, DD, 0);
    gemm_kv2_mfma<<<dim3(100, 2, 4), 256, 0, stream>>>(kv16, s16,
                                                       kw16 + (size_t)i * DD * DD,
                                                       vw16 + (size_t)i * DD * DD, Kb, Vb);
    ca_attn_part<<<MR * NSPL, 256, 0, stream>>>(caq, Kb, Vb, lohi, pmb, psb, pob);
    ca_merge<<<270, 256, 0, stream>>>(pmb, psb, pob, cao);
    gemm_rows_mfma<<<dim3(17, 4), 256, 0, stream>>>(cao, nullptr, pw16 + (size_t)i * DD * DD,
                                                    ca_proj_b + (size_t)i * DD, tgt, tmp, MR, DD, DD, 0);
    ln_kernel<<<270, 256, 0, stream>>>(tmp, ln1_g + i * DD, ln1_b + i * DD, tgt);

    // FFN
    gemm_rows_mfma<<<dim3(17, 16), 256, 0, stream>>>(tgt, nullptr, f1w16 + (size_t)i * FFD * DD,
                                                     ffn_b1 + (size_t)i * FFD, nullptr, ffh, MR, FFD, DD, 1);
    gemm_rows_mfma<<<dim3(17, 4), 256, 0, stream>>>(ffh, nullptr, f2w16 + (size_t)i * DD * FFD,
                                                    ffn_b2 + (size_t)i * DD, tgt, tmp, MR, DD, FFD, 0);
    float* lno = (i == LL - 1) ? outp : tgt;
    ln_kernel<<<270, 256, 0, stream>>>(tmp, ln3_g + i * DD, ln3_b + i * DD, lno);
  }
}

// Round 16
// 1733.315 us; speedup vs baseline: 1.1457x; 1.0437x over previous
//
#include <hip/hip_runtime.h>
#include <hip/hip_fp16.h>
#include <math.h>

#define BB 2
#define DD 256
#define HH 8
#define HDIM 32
#define FFD 1024
#define LL 6
#define NQQ 540
#define QPO_ 27
#define PS0 20
#define PS1 20
#define PS2 32
#define PP (PS0*PS1*PS2)   // 12800
#define MR (BB*NQQ)        // 1080
#define NSPL 8             // cross-attn row-partials per query (4-wave blocks)

typedef _Float16 half8 __attribute__((ext_vector_type(8)));
typedef _Float16 h2v  __attribute__((ext_vector_type(2)));
typedef float f32x4 __attribute__((ext_vector_type(4)));

static __device__ __forceinline__ float wred_sum(float x) {
#pragma unroll
  for (int off = 32; off; off >>= 1) x += __shfl_xor(x, off, 64);
  return x;
}
static __device__ __forceinline__ float4 h4_to_f4(uint2 u) {
  __half2 h0 = *reinterpret_cast<__half2*>(&u.x);
  __half2 h1 = *reinterpret_cast<__half2*>(&u.y);
  float2 f0 = __half22float2(h0);
  float2 f1 = __half22float2(h1);
  return make_float4(f0.x, f0.y, f1.x, f1.y);
}
static __device__ __forceinline__ float dot4h(uint2 kw, h2v q01, h2v q23) {
  h2v a = *reinterpret_cast<h2v*>(&kw.x);
  h2v b = *reinterpret_cast<h2v*>(&kw.y);
  float d = __builtin_amdgcn_fdot2(a, q01, 0.f, false);
  return __builtin_amdgcn_fdot2(b, q23, d, false);
}

// ---------------------------------------------------------------------------
// init: tgt[b,q,d] = qe[q, 256+d]; qpos[b,q,d] = qe[q, d]
__global__ __launch_bounds__(256) void init_kernel(
    const float* __restrict__ qe, float* __restrict__ tgt, float* __restrict__ qpos)
{
  int idx = blockIdx.x * 256 + threadIdx.x;   // < B*NQ*D == 276480
  int d = idx % DD;
  int q = (idx / DD) % NQQ;
  qpos[idx] = qe[q * 512 + d];
  tgt[idx]  = qe[q * 512 + 256 + d];
}

// ---------------------------------------------------------------------------
// One-time: transpose+convert src/pos to fp16 [b][p][d] layouts.
__global__ __launch_bounds__(256) void conv_kv_inputs(
    const float* __restrict__ src, const float* __restrict__ pos,
    __half* __restrict__ s16, __half* __restrict__ kv16)
{
  __shared__ float ls[64][65];
  __shared__ float lk[64][65];
  int b  = blockIdx.z;
  int p0 = blockIdx.x * 64;
  int d0 = blockIdx.y * 64;
  int t = threadIdx.x;
  int pr = (t & 15) * 4;
  int dr = t >> 4;
#pragma unroll
  for (int dd = 0; dd < 64; dd += 16) {
    int d = d0 + dd + dr;
    float4 sv = *(const float4*)&src[((size_t)b * DD + d) * PP + p0 + pr];
    float4 pv = *(const float4*)&pos[((size_t)b * DD + d) * PP + p0 + pr];
    ls[pr + 0][dd + dr] = sv.x; ls[pr + 1][dd + dr] = sv.y;
    ls[pr + 2][dd + dr] = sv.z; ls[pr + 3][dd + dr] = sv.w;
    lk[pr + 0][dd + dr] = sv.x + pv.x; lk[pr + 1][dd + dr] = sv.y + pv.y;
    lk[pr + 2][dd + dr] = sv.z + pv.z; lk[pr + 3][dd + dr] = sv.w + pv.w;
  }
  __syncthreads();
  int wp = t >> 2;
  int wd = (t & 3) * 16;
  size_t base = ((size_t)b * PP + p0 + wp) * 256 + d0 + wd;
#pragma unroll
  for (int i = 0; i < 16; i += 2) {
    *(__half2*)&s16[base + i]  = __floats2half2_rn(ls[wp][wd + i], ls[wp][wd + i + 1]);
    *(__half2*)&kv16[base + i] = __floats2half2_rn(lk[wp][wd + i], lk[wp][wd + i + 1]);
  }
}

// One-time: fp32 -> fp16 weight conversion (grid-stride).
__global__ __launch_bounds__(256) void conv_w(
    const float* __restrict__ w, __half* __restrict__ w16, int n)
{
  for (int i = blockIdx.x * 256 + threadIdx.x; i < n; i += gridDim.x * 256)
    w16[i] = __float2half_rn(w[i]);
}

// ---------------------------------------------------------------------------
// Merged MFMA K&V projection: z>>1 selects (A,W,out) pair, z&1 = batch b.
__global__ __launch_bounds__(256) void gemm_kv2_mfma(
    const __half* __restrict__ Ak, const __half* __restrict__ Av,
    const __half* __restrict__ Wk, const __half* __restrict__ Wv,
    __half* __restrict__ Ko, __half* __restrict__ Vo)
{
  int z = blockIdx.z;
  int b = z & 1;
  const __half* A = (z >> 1) ? Av : Ak;
  const __half* W = (z >> 1) ? Wv : Wk;
  __half* out     = (z >> 1) ? Vo : Ko;
  int wid = threadIdx.x >> 6;
  int lane = threadIdx.x & 63;
  int p0 = blockIdx.x * 128 + (wid >> 1) * 64;
  int n0 = blockIdx.y * 128 + (wid & 1) * 64;
  const __half* Ab = A + (size_t)b * PP * 256;
  int row = lane & 15;
  int kg  = lane >> 4;
  f32x4 acc[4][4] = {};
  for (int k0 = 0; k0 < 256; k0 += 32) {
    half8 af[4], bf[4];
#pragma unroll
    for (int i = 0; i < 4; ++i)
      af[i] = *(const half8*)&Ab[((size_t)(p0 + 16 * i + row)) * 256 + k0 + kg * 8];
#pragma unroll
    for (int j = 0; j < 4; ++j)
      bf[j] = *(const half8*)&W[((size_t)(n0 + 16 * j + row)) * 256 + k0 + kg * 8];
#pragma unroll
    for (int i = 0; i < 4; ++i)
#pragma unroll
      for (int j = 0; j < 4; ++j)
        acc[i][j] = __builtin_amdgcn_mfma_f32_16x16x32_f16(af[i], bf[j], acc[i][j], 0, 0, 0);
  }
#pragma unroll
  for (int i = 0; i < 4; ++i)
#pragma unroll
    for (int j = 0; j < 4; ++j) {
      int nc = n0 + 16 * j + row;
#pragma unroll
      for (int r = 0; r < 4; ++r) {
        int pr = p0 + 16 * i + kg * 4 + r;
        out[((size_t)b * PP + pr) * 256 + nc] = __float2half_rn(acc[i][j][r]);
      }
    }
}

// ---------------------------------------------------------------------------
// MFMA row GEMM: C[r,n] = (A1[r,:](+A2[r,:])) @ W16[n,:] (+bias)(+res)(relu).
__global__ __launch_bounds__(256) void gemm_rows_mfma(
    const float* __restrict__ A1, const float* __restrict__ A2,
    const __half* __restrict__ W, const float* __restrict__ bias,
    const float* __restrict__ res, float* __restrict__ C,
    int M, int N, int K, int relu)
{
  __shared__ __half a_s[64][40];
  int bm = blockIdx.x * 64;
  int bn = blockIdx.y * 64;
  int wv = threadIdx.x >> 6;
  int lane = threadIdx.x & 63;
  int row = lane & 15;
  int kg  = lane >> 4;
  int nw  = bn + wv * 16;
  int t = threadIdx.x;
  int srow = t >> 2, skq = (t & 3) * 8;
  f32x4 acc[4] = {};

  for (int k0 = 0; k0 < K; k0 += 32) {
    {
      size_t off = (size_t)(bm + srow) * K + k0 + skq;
      float4 a0 = *(const float4*)&A1[off];
      float4 a1 = *(const float4*)&A1[off + 4];
      if (A2) {
        float4 b0 = *(const float4*)&A2[off];
        float4 b1 = *(const float4*)&A2[off + 4];
        a0.x += b0.x; a0.y += b0.y; a0.z += b0.z; a0.w += b0.w;
        a1.x += b1.x; a1.y += b1.y; a1.z += b1.z; a1.w += b1.w;
      }
      half8 h;
      h[0] = (_Float16)a0.x; h[1] = (_Float16)a0.y;
      h[2] = (_Float16)a0.z; h[3] = (_Float16)a0.w;
      h[4] = (_Float16)a1.x; h[5] = (_Float16)a1.y;
      h[6] = (_Float16)a1.z; h[7] = (_Float16)a1.w;
      *(half8*)&a_s[srow][skq] = h;
    }
    __syncthreads();
    half8 bf = *(const half8*)&W[(size_t)(nw + row) * K + k0 + kg * 8];
#pragma unroll
    for (int i = 0; i < 4; ++i) {
      half8 af = *(const half8*)&a_s[16 * i + row][kg * 8];
      acc[i] = __builtin_amdgcn_mfma_f32_16x16x32_f16(af, bf, acc[i], 0, 0, 0);
    }
    __syncthreads();
  }

  int col = nw + row;
  float bval = bias ? bias[col] : 0.f;
#pragma unroll
  for (int i = 0; i < 4; ++i) {
#pragma unroll
    for (int r = 0; r < 4; ++r) {
      int rr = bm + 16 * i + kg * 4 + r;
      if (rr >= M) continue;
      float v = acc[i][r] + bval;
      if (relu) v = fmaxf(v, 0.f);
      if (res)  v += res[(size_t)rr * N + col];
      C[(size_t)rr * N + col] = v;
    }
  }
}

// ---------------------------------------------------------------------------
// MFMA row GEMM with fp16 output (for SA q/k/v buffers): C16 = A1(+A2) @ W16 + bias.
__global__ __launch_bounds__(256) void gemm_rows_mfma_h(
    const float* __restrict__ A1, const float* __restrict__ A2,
    const __half* __restrict__ W, const float* __restrict__ bias,
    __half* __restrict__ C, int M, int N, int K)
{
  __shared__ __half a_s[64][40];
  int bm = blockIdx.x * 64;
  int bn = blockIdx.y * 64;
  int wv = threadIdx.x >> 6;
  int lane = threadIdx.x & 63;
  int row = lane & 15;
  int kg  = lane >> 4;
  int nw  = bn + wv * 16;
  int t = threadIdx.x;
  int srow = t >> 2, skq = (t & 3) * 8;
  f32x4 acc[4] = {};

  for (int k0 = 0; k0 < K; k0 += 32) {
    {
      size_t off = (size_t)(bm + srow) * K + k0 + skq;
      float4 a0 = *(const float4*)&A1[off];
      float4 a1 = *(const float4*)&A1[off + 4];
      if (A2) {
        float4 b0 = *(const float4*)&A2[off];
        float4 b1 = *(const float4*)&A2[off + 4];
        a0.x += b0.x; a0.y += b0.y; a0.z += b0.z; a0.w += b0.w;
        a1.x += b1.x; a1.y += b1.y; a1.z += b1.z; a1.w += b1.w;
      }
      half8 h;
      h[0] = (_Float16)a0.x; h[1] = (_Float16)a0.y;
      h[2] = (_Float16)a0.z; h[3] = (_Float16)a0.w;
      h[4] = (_Float16)a1.x; h[5] = (_Float16)a1.y;
      h[6] = (_Float16)a1.z; h[7] = (_Float16)a1.w;
      *(half8*)&a_s[srow][skq] = h;
    }
    __syncthreads();
    half8 bf = *(const half8*)&W[(size_t)(nw + row) * K + k0 + kg * 8];
#pragma unroll
    for (int i = 0; i < 4; ++i) {
      half8 af = *(const half8*)&a_s[16 * i + row][kg * 8];
      acc[i] = __builtin_amdgcn_mfma_f32_16x16x32_f16(af, bf, acc[i], 0, 0, 0);
    }
    __syncthreads();
  }

  int col = nw + row;
  float bval = bias ? bias[col] : 0.f;
#pragma unroll
  for (int i = 0; i < 4; ++i) {
#pragma unroll
    for (int r = 0; r < 4; ++r) {
      int rr = bm + 16 * i + kg * 4 + r;
      if (rr >= M) continue;
      C[(size_t)rr * N + col] = __float2half_rn(acc[i][r] + bval);
    }
  }
}

// ---------------------------------------------------------------------------
// Self-attention, fp16 K/V, all-heads-batched, defer-max. One block (8 waves)
// per (b,q). qk16: (MR,512) q cols 0..255, k cols 256..511. v16: (MR,256).
__global__ __launch_bounds__(512) void sa_attn(
    const __half* __restrict__ qk16, const __half* __restrict__ v16,
    float* __restrict__ out)
{
  __shared__ float wmS[8][8];
  __shared__ float wsS[8][8];
  __shared__ float4 ooS[8][64];

  int bid = blockIdx.x;           // b*NQQ + q
  int b = bid / NQQ;
  int wv = threadIdx.x >> 6;
  int lane = threadIdx.x & 63;
  const float scale = 0.17677669529663687f;  // 32^-0.5

  uint2 qw = ((const uint2*)(qk16 + (size_t)bid * 512))[lane];
  float4 q4 = h4_to_f4(qw);
  q4.x *= scale; q4.y *= scale; q4.z *= scale; q4.w *= scale;
  h2v q01, q23;
  q01[0] = (_Float16)q4.x; q01[1] = (_Float16)q4.y;
  q23[0] = (_Float16)q4.z; q23[1] = (_Float16)q4.w;

  const __half* Kb = qk16 + (size_t)b * NQQ * 512 + 256;  // k part of rows
  const __half* Vb = v16 + (size_t)b * NQQ * 256;

  float m = -INFINITY, sA = 0.f, sB = 0.f;
  float4 oA = make_float4(0.f, 0.f, 0.f, 0.f);
  float4 oB = make_float4(0.f, 0.f, 0.f, 0.f);

  for (int k0 = wv * 8; k0 < NQQ; k0 += 64) {
    const uint2* kp = (const uint2*)(Kb + (size_t)k0 * 512) + lane;
    const uint2* vp = (const uint2*)(Vb + (size_t)k0 * 256) + lane;
    uint2 kw[8];
#pragma unroll
    for (int i = 0; i < 8; ++i) kw[i] = kp[i * 128];   // row stride 512 halfs
    uint2 vw[8];
#pragma unroll
    for (int i = 0; i < 8; ++i) vw[i] = vp[i * 64];

    float lg[8];
#pragma unroll
    for (int i = 0; i < 8; ++i) {
      float d = dot4h(kw[i], q01, q23);
      d += __shfl_xor(d, 1, 64);
      d += __shfl_xor(d, 2, 64);
      d += __shfl_xor(d, 4, 64);
      lg[i] = (k0 + i < NQQ) ? d : -INFINITY;
    }

    float bm = fmaxf(fmaxf(fmaxf(lg[0], lg[1]), fmaxf(lg[2], lg[3])),
                     fmaxf(fmaxf(lg[4], lg[5]), fmaxf(lg[6], lg[7])));
    if (bm > m + 8.f) {              // defer-max: rare after warm-up
      float f = __expf(m - bm);      // m=-inf first -> 0
      sA *= f; sB *= f;
      oA.x *= f; oA.y *= f; oA.z *= f; oA.w *= f;
      oB.x *= f; oB.y *= f; oB.z *= f; oB.w *= f;
      m = bm;
    }
#pragma unroll
    for (int i = 0; i < 8; i += 2) {
      float pa = __expf(lg[i] - m);
      float pb = __expf(lg[i + 1] - m);
      float4 va = h4_to_f4(vw[i]);
      float4 vb = h4_to_f4(vw[i + 1]);
      sA += pa; sB += pb;
      oA.x = fmaf(pa, va.x, oA.x); oB.x = fmaf(pb, vb.x, oB.x);
      oA.y = fmaf(pa, va.y, oA.y); oB.y = fmaf(pb, vb.y, oB.y);
      oA.z = fmaf(pa, va.z, oA.z); oB.z = fmaf(pb, vb.z, oB.z);
      oA.w = fmaf(pa, va.w, oA.w); oB.w = fmaf(pb, vb.w, oB.w);
    }
  }

  float s = sA + sB;
  float4 o4 = make_float4(oA.x + oB.x, oA.y + oB.y, oA.z + oB.z, oA.w + oB.w);

  // ---- merge 8 wave-states (per head) ----
  int hg = lane >> 3, sub = lane & 7;
  if (sub == 0) wmS[wv][hg] = m;
  __syncthreads();
  float M = wmS[0][hg];
#pragma unroll
  for (int w = 1; w < 8; ++w) M = fmaxf(M, wmS[w][hg]);
  float f = __expf(m - M);
  if (sub == 0) wsS[wv][hg] = s * f;
  ooS[wv][lane] = make_float4(o4.x * f, o4.y * f, o4.z * f, o4.w * f);
  __syncthreads();
  if (threadIdx.x < 64) {
    int l = threadIdx.x;
    int hg2 = l >> 3;
    float4 acc = make_float4(0.f, 0.f, 0.f, 0.f);
    float den = 0.f;
#pragma unroll
    for (int w = 0; w < 8; ++w) {
      float4 t = ooS[w][l];
      acc.x += t.x; acc.y += t.y; acc.z += t.z; acc.w += t.w;
      den += wsS[w][hg2];
    }
    float inv = 1.f / den;
    float4 res = make_float4(acc.x * inv, acc.y * inv, acc.z * inv, acc.w * inv);
    *(float4*)&out[(size_t)bid * 256 + l * 4] = res;
  }
}

// ---------------------------------------------------------------------------
// Cross-attention partial (R14 structure + defer-max): 256-thr (4-wave)
// blocks, NSPL=8, XCD swizzle, fdot2 QK, split even/odd accumulators.
__global__ __launch_bounds__(256) void ca_attn_part(
    const float* __restrict__ qbuf, const __half* __restrict__ Kbuf,
    const __half* __restrict__ Vbuf, const int* __restrict__ lohi,
    float* __restrict__ pm, float* __restrict__ ps, float* __restrict__ po)
{
  __shared__ float wmS[4][8];
  __shared__ float wsS[4][8];
  __shared__ float4 ooS[4][64];

  // --- swizzle: 8640 blocks = 8 cls x 5 gsub x 27 iq x 8 part ---
  int idx  = blockIdx.x;
  int cls  = idx & 7;
  int rest = idx >> 3;          // 0..1079
  int gsub = rest / 216;        // 0..4
  int rem  = rest % 216;
  int iq   = rem >> 3;          // 0..26
  int part = rem & 7;           // NSPL == 8
  int g    = gsub * 8 + cls;    // organ-group 0..39
  int b    = g / 20;
  int q    = (g % 20) * QPO_ + iq;
  int bid  = b * NQQ + q;

  int wv = threadIdx.x >> 6;    // 0..3
  int lane = threadIdx.x & 63;
  const float scale = 0.17677669529663687f;

  const int* lh = lohi + (size_t)bid * 6;
  int lo0 = lh[0], lo1 = lh[1], lo2 = lh[2];
  int nx = lh[3] - lo0, ny = lh[4] - lo1, nz = lh[5] - lo2;
  int nxy = nx * ny;
  float inv_ny = 1.0f / (float)ny;

  float4 q4 = ((const float4*)(qbuf + (size_t)bid * 256))[lane];
  q4.x *= scale; q4.y *= scale; q4.z *= scale; q4.w *= scale;
  h2v q01, q23;
  q01[0] = (_Float16)q4.x; q01[1] = (_Float16)q4.y;
  q23[0] = (_Float16)q4.z; q23[1] = (_Float16)q4.w;

  const __half* Kb = Kbuf + (size_t)b * PP * 256;
  const __half* Vb = Vbuf + (size_t)b * PP * 256;

  float m = -INFINITY, sA = 0.f, sB = 0.f;
  float4 oA = make_float4(0.f, 0.f, 0.f, 0.f);
  float4 oB = make_float4(0.f, 0.f, 0.f, 0.f);

  for (int r = part + 8 * wv; r < nxy; r += 32) {
    int x = (int)((float)r * inv_ny);
    int y = r - x * ny;
    if (y < 0)        { x--; y += ny; }
    else if (y >= ny) { x++; y -= ny; }
    int base = (lo0 + x) * (PS1 * PS2) + (lo1 + y) * PS2 + lo2;

    for (int z0 = 0; z0 < nz; z0 += 8) {
      const uint2* kp = (const uint2*)(Kb + ((size_t)base + z0) * 256) + lane;
      const uint2* vp = (const uint2*)(Vb + ((size_t)base + z0) * 256) + lane;
      uint2 kw[8];
#pragma unroll
      for (int i = 0; i < 8; ++i) kw[i] = kp[i * 64];   // row stride 256 halfs
      uint2 vw[8];
#pragma unroll
      for (int i = 0; i < 8; ++i) vw[i] = vp[i * 64];

      float lg[8];
#pragma unroll
      for (int i = 0; i < 8; ++i) {
        float d = dot4h(kw[i], q01, q23);
        d += __shfl_xor(d, 1, 64);
        d += __shfl_xor(d, 2, 64);
        d += __shfl_xor(d, 4, 64);
        lg[i] = (z0 + i < nz) ? d : -INFINITY;
      }

      float bm = fmaxf(fmaxf(fmaxf(lg[0], lg[1]), fmaxf(lg[2], lg[3])),
                       fmaxf(fmaxf(lg[4], lg[5]), fmaxf(lg[6], lg[7])));
      if (bm > m + 8.f) {            // defer-max: rare after warm-up
        float f = __expf(m - bm);    // m=-inf first -> 0
        sA *= f; sB *= f;
        oA.x *= f; oA.y *= f; oA.z *= f; oA.w *= f;
        oB.x *= f; oB.y *= f; oB.z *= f; oB.w *= f;
        m = bm;
      }
#pragma unroll
      for (int i = 0; i < 8; i += 2) {
        float pa = __expf(lg[i] - m);       // masked -inf -> 0
        float pb = __expf(lg[i + 1] - m);
        float4 va = h4_to_f4(vw[i]);
        float4 vb = h4_to_f4(vw[i + 1]);
        sA += pa; sB += pb;
        oA.x = fmaf(pa, va.x, oA.x); oB.x = fmaf(pb, vb.x, oB.x);
        oA.y = fmaf(pa, va.y, oA.y); oB.y = fmaf(pb, vb.y, oB.y);
        oA.z = fmaf(pa, va.z, oA.z); oB.z = fmaf(pb, vb.z, oB.z);
        oA.w = fmaf(pa, va.w, oA.w); oB.w = fmaf(pb, vb.w, oB.w);
      }
    }
  }

  float s = sA + sB;
  float4 o4 = make_float4(oA.x + oB.x, oA.y + oB.y, oA.z + oB.z, oA.w + oB.w);

  // ---- merge this block's 4 wave-states; write partial (M, S, O) ----
  int hg = lane >> 3, sub = lane & 7;
  if (sub == 0) wmS[wv][hg] = m;
  __syncthreads();
  float M = wmS[0][hg];
#pragma unroll
  for (int w = 1; w < 4; ++w) M = fmaxf(M, wmS[w][hg]);
  float f = (M == -INFINITY) ? 0.f : __expf(m - M);  // empty part -> zeros
  if (sub == 0) wsS[wv][hg] = s * f;
  ooS[wv][lane] = make_float4(o4.x * f, o4.y * f, o4.z * f, o4.w * f);
  __syncthreads();
  if (threadIdx.x < 64) {
    int l = threadIdx.x;
    int hg2 = l >> 3;
    float4 acc = make_float4(0.f, 0.f, 0.f, 0.f);
    float den = 0.f;
#pragma unroll
    for (int w = 0; w < 4; ++w) {
      float4 t = ooS[w][l];
      acc.x += t.x; acc.y += t.y; acc.z += t.z; acc.w += t.w;
      den += wsS[w][hg2];
    }
    float M2 = wmS[0][hg2];
#pragma unroll
    for (int w = 1; w < 4; ++w) M2 = fmaxf(M2, wmS[w][hg2]);
    size_t pb = (size_t)bid * NSPL + part;
    if ((l & 7) == 0) { pm[pb * 8 + hg2] = M2; ps[pb * 8 + hg2] = den; }
    *(float4*)&po[pb * 256 + l * 4] = acc;
  }
}

// ---------------------------------------------------------------------------
// Merge NSPL cross-attn partials per query. One wave per (b,q).
__global__ __launch_bounds__(256) void ca_merge(
    const float* __restrict__ pm, const float* __restrict__ ps,
    const float* __restrict__ po, float* __restrict__ out)
{
  int wv = threadIdx.x >> 6;
  int lane = threadIdx.x & 63;
  int bid = blockIdx.x * 4 + wv;
  int hg = lane >> 3;
  size_t pb = (size_t)bid * NSPL;

  float mp[NSPL], sp[NSPL];
#pragma unroll
  for (int p = 0; p < NSPL; ++p) {
    mp[p] = pm[(pb + p) * 8 + hg];
    sp[p] = ps[(pb + p) * 8 + hg];
  }
  float M = mp[0];
#pragma unroll
  for (int p = 1; p < NSPL; ++p) M = fmaxf(M, mp[p]);
  float den = 0.f;
  float4 acc = make_float4(0.f, 0.f, 0.f, 0.f);
#pragma unroll
  for (int p = 0; p < NSPL; ++p) {
    float f = __expf(mp[p] - M);     // empty part m=-inf -> 0
    den = fmaf(f, sp[p], den);
    float4 t = *(const float4*)&po[(pb + p) * 256 + lane * 4];
    acc.x = fmaf(f, t.x, acc.x);
    acc.y = fmaf(f, t.y, acc.y);
    acc.z = fmaf(f, t.z, acc.z);
    acc.w = fmaf(f, t.w, acc.w);
  }
  float inv = 1.f / den;
  float4 res = make_float4(acc.x * inv, acc.y * inv, acc.z * inv, acc.w * inv);
  *(float4*)&out[(size_t)bid * 256 + lane * 4] = res;
}

// ---------------------------------------------------------------------------
// LayerNorm over D=256: one wave per row. x already contains residual sum.
__global__ __launch_bounds__(256) void ln_kernel(
    const float* __restrict__ x, const float* __restrict__ g,
    const float* __restrict__ bta, float* __restrict__ out)
{
  int wv = threadIdx.x >> 6;
  int lane = threadIdx.x & 63;
  int row = blockIdx.x * 4 + wv;
  const float* xr = x + (size_t)row * 256;
  float v[4];
#pragma unroll
  for (int j = 0; j < 4; ++j) v[j] = xr[lane + 64 * j];
  float s = v[0] + v[1] + v[2] + v[3];
  s = wred_sum(s);
  float mean = s * (1.f / 256.f);
  float vs = 0.f;
#pragma unroll
  for (int j = 0; j < 4; ++j) { float d = v[j] - mean; vs = fmaf(d, d, vs); }
  vs = wred_sum(vs);
  float inv = rsqrtf(vs * (1.f / 256.f) + 1e-5f);
  float* orow = out + (size_t)row * 256;
#pragma unroll
  for (int j = 0; j < 4; ++j) {
    int c = lane + 64 * j;
    orow[c] = (v[j] - mean) * inv * g[c] + bta[c];
  }
}

// ---------------------------------------------------------------------------
// Layer-0 mask boxes from attn_area.
__global__ __launch_bounds__(256) void mask0_kernel(
    const float* __restrict__ area, int* __restrict__ lohi,
    float px, float py, float pz)
{
  int row = blockIdx.x * 256 + threadIdx.x;
  if (row >= MR) return;
  int q = row % NQQ;
  int org = q / QPO_;
  const float* a = area + org * 6;
  int* o = lohi + (size_t)row * 6;
  o[0] = (int)fminf(fmaxf(floorf(a[0] * 20.f - px), 0.f), 20.f);
  o[1] = (int)fminf(fmaxf(floorf(a[1] * 20.f - py), 0.f), 20.f);
  o[2] = (int)fminf(fmaxf(floorf(a[2] * 32.f - pz), 0.f), 32.f);
  o[3] = (int)fminf(fmaxf(floorf(a[3] * 20.f + px), 0.f), 20.f);
  o[4] = (int)fminf(fmaxf(floorf(a[4] * 20.f + py), 0.f), 20.f);
  o[5] = (int)fminf(fmaxf(floorf(a[5] * 32.f + pz), 0.f), 32.f);
}

// ---------------------------------------------------------------------------
// Layers >=1: prop = h2 @ w3.T + b3 -> tanh*0.1 + anchors -> clip -> box ints.
__global__ __launch_bounds__(256) void mask_reg_kernel(
    const float* __restrict__ h2, const float* __restrict__ w3,
    const float* __restrict__ b3, const float* __restrict__ anchors,
    int* __restrict__ lohi, float px, float py, float pz)
{
  int wv = threadIdx.x >> 6;
  int lane = threadIdx.x & 63;
  int row = blockIdx.x * 4 + wv;
  int q = row % NQQ;
  const float* hr = h2 + (size_t)row * 256;
  float part[6] = {};
#pragma unroll
  for (int j = 0; j < 4; ++j) {
    float hv = hr[lane + 64 * j];
#pragma unroll
    for (int o = 0; o < 6; ++o)
      part[o] = fmaf(hv, w3[o * 256 + lane + 64 * j], part[o]);
  }
#pragma unroll
  for (int o = 0; o < 6; ++o) part[o] = wred_sum(part[o]);
  if (lane == 0) {
    float prop[6];
#pragma unroll
    for (int o = 0; o < 6; ++o) {
      float v = tanhf(part[o] + b3[o]) * 0.1f + anchors[q * 6 + o];
      prop[o] = fminf(fmaxf(v, 0.f), 1.f);
    }
    float vl0 = prop[0] - 0.5f * prop[3], vh0 = prop[0] + 0.5f * prop[3];
    float vl1 = prop[1] - 0.5f * prop[4], vh1 = prop[1] + 0.5f * prop[4];
    float vl2 = prop[2] - 0.5f * prop[5], vh2 = prop[2] + 0.5f * prop[5];
    int* o = lohi + (size_t)row * 6;
    o[0] = (int)fminf(fmaxf(floorf(vl0 * 20.f - px), 0.f), 20.f);
    o[1] = (int)fminf(fmaxf(floorf(vl1 * 20.f - py), 0.f), 20.f);
    o[2] = (int)fminf(fmaxf(floorf(vl2 * 32.f - pz), 0.f), 32.f);
    o[3] = (int)fminf(fmaxf(floorf(vh0 * 20.f + px), 0.f), 20.f);
    o[4] = (int)fminf(fmaxf(floorf(vh1 * 20.f + py), 0.f), 20.f);
    o[5] = (int)fminf(fmaxf(floorf(vh2 * 32.f + pz), 0.f), 32.f);
  }
}

// ---------------------------------------------------------------------------
extern "C" void kernel_launch(void* const* d_in, const int* in_sizes, int n_in,
                              void* d_out, int out_size, void* d_ws, size_t ws_size,
                              hipStream_t stream)
{
  const float* src       = (const float*)d_in[0];
  const float* pos       = (const float*)d_in[1];
  const float* qe        = (const float*)d_in[2];
  const float* sa_in_w   = (const float*)d_in[3];
  const float* sa_in_b   = (const float*)d_in[4];
  const float* sa_out_w  = (const float*)d_in[5];
  const float* sa_out_b  = (const float*)d_in[6];
  const float* ca_k_w    = (const float*)d_in[7];
  const float* ca_v_w    = (const float*)d_in[8];
  const float* ca_proj_w = (const float*)d_in[9];
  const float* ca_proj_b = (const float*)d_in[10];
  const float* ln1_g = (const float*)d_in[11];
  const float* ln1_b = (const float*)d_in[12];
  const float* ln2_g = (const float*)d_in[13];
  const float* ln2_b = (const float*)d_in[14];
  const float* ln3_g = (const float*)d_in[15];
  const float* ln3_b = (const float*)d_in[16];
  const float* ffn_w1 = (const float*)d_in[17];
  const float* ffn_b1 = (const float*)d_in[18];
  const float* ffn_w2 = (const float*)d_in[19];
  const float* ffn_b2 = (const float*)d_in[20];
  const float* reg_w1 = (const float*)d_in[21];
  const float* reg_b1 = (const float*)d_in[22];
  const float* reg_w2 = (const float*)d_in[23];
  const float* reg_b2 = (const float*)d_in[24];
  const float* reg_w3 = (const float*)d_in[25];
  const float* reg_b3 = (const float*)d_in[26];
  const float* anchors   = (const float*)d_in[27];
  const float* attn_area = (const float*)d_in[28];
  float* outp = (float*)d_out;

  float* ws = (float*)d_ws;
  size_t off = 0;
  auto alloc = [&](size_t n) { float* p = ws + off; off += n; return p; };
  __half* Kb = (__half*)alloc((size_t)BB * PP * 128);   // fp16 [b][p][256], 13.1 MB
  __half* Vb = (__half*)alloc((size_t)BB * PP * 128);   // fp16, 13.1 MB
  alloc(2048);                                          // over-read pad
  __half* s16  = (__half*)alloc((size_t)BB * PP * 128); // fp16(src) [b][p][d]
  __half* kv16 = (__half*)alloc((size_t)BB * PP * 128); // fp16(src+pos) [b][p][d]
  __half* kw16 = (__half*)alloc((size_t)LL * DD * DD / 2);
  __half* vw16 = (__half*)alloc((size_t)LL * DD * DD / 2);
  __half* saw16 = (__half*)alloc((size_t)LL * 768 * DD / 2);   // sa_in_w
  __half* sow16 = (__half*)alloc((size_t)LL * DD * DD / 2);    // sa_out_w
  __half* pw16  = (__half*)alloc((size_t)LL * DD * DD / 2);    // ca_proj_w
  __half* f1w16 = (__half*)alloc((size_t)LL * FFD * DD / 2);   // ffn_w1
  __half* f2w16 = (__half*)alloc((size_t)LL * DD * FFD / 2);   // ffn_w2
  __half* r1w16 = (__half*)alloc((size_t)DD * DD / 2);         // reg_w1
  __half* r2w16 = (__half*)alloc((size_t)DD * DD / 2);         // reg_w2
  __half* saqk16 = (__half*)alloc((size_t)MR * 512 / 2);       // SA q|k fp16
  __half* sav16  = (__half*)alloc((size_t)MR * 256 / 2);       // SA v fp16
  alloc(2048);                                          // SA over-read pad
  float* tgt  = alloc((size_t)MR * DD);
  float* qpos = alloc((size_t)MR * DD);
  float* tmp  = alloc((size_t)MR * DD);
  float* sao  = alloc((size_t)MR * DD);
  float* caq  = alloc((size_t)MR * DD);
  float* cao  = alloc((size_t)MR * DD);
  float* mh1  = alloc((size_t)MR * DD);
  float* mh2  = alloc((size_t)MR * DD);
  float* ffh  = alloc((size_t)MR * FFD);
  float* pmb  = alloc((size_t)MR * NSPL * 8);
  float* psb  = alloc((size_t)MR * NSPL * 8);
  float* pob  = alloc((size_t)MR * NSPL * 256);
  int*   lohi = (int*)alloc((size_t)MR * 6);
  alloc(4096);                                          // A over-read pad
  (void)in_sizes; (void)n_in; (void)out_size; (void)ws_size;

  const float FOCUS_H[6] = {0.1f, 0.075f, 0.05f, 0.05f, 0.025f, 0.025f};

  init_kernel<<<1080, 256, 0, stream>>>(qe, tgt, qpos);
  conv_kv_inputs<<<dim3(200, 4, 2), 256, 0, stream>>>(src, pos, s16, kv16);
  conv_w<<<768, 256, 0, stream>>>(ca_k_w, kw16, LL * DD * DD);
  conv_w<<<768, 256, 0, stream>>>(ca_v_w, vw16, LL * DD * DD);
  conv_w<<<768, 256, 0, stream>>>(sa_in_w, saw16, LL * 768 * DD);
  conv_w<<<768, 256, 0, stream>>>(sa_out_w, sow16, LL * DD * DD);
  conv_w<<<768, 256, 0, stream>>>(ca_proj_w, pw16, LL * DD * DD);
  conv_w<<<768, 256, 0, stream>>>(ffn_w1, f1w16, LL * FFD * DD);
  conv_w<<<768, 256, 0, stream>>>(ffn_w2, f2w16, LL * DD * FFD);
  conv_w<<<256, 256, 0, stream>>>(reg_w1, r1w16, DD * DD);
  conv_w<<<256, 256, 0, stream>>>(reg_w2, r2w16, DD * DD);

  for (int i = 0; i < LL; ++i) {
    const __half* wi16 = saw16 + (size_t)i * 768 * DD;
    const float*  bi   = sa_in_b + (size_t)i * 768;
    // SA: q,k from (tgt+qpos), v from tgt -> fp16 buffers
    gemm_rows_mfma_h<<<dim3(17, 8), 256, 0, stream>>>(tgt, qpos, wi16, bi, saqk16, MR, 512, DD);
    gemm_rows_mfma_h<<<dim3(17, 4), 256, 0, stream>>>(tgt, nullptr, wi16 + 512 * DD, bi + 512, sav16, MR, DD, DD);
    sa_attn<<<MR, 512, 0, stream>>>(saqk16, sav16, sao);
    gemm_rows_mfma<<<dim3(17, 4), 256, 0, stream>>>(sao, nullptr, sow16 + (size_t)i * DD * DD,
                                                    sa_out_b + (size_t)i * DD, tgt, tmp, MR, DD, DD, 0);
    ln_kernel<<<270, 256, 0, stream>>>(tmp, ln2_g + i * DD, ln2_b + i * DD, tgt);

    // mask boxes
    if (i == 0) {
      mask0_kernel<<<5, 256, 0, stream>>>(attn_area, lohi,
          FOCUS_H[0] * PS0, FOCUS_H[0] * PS1, FOCUS_H[0] * PS2);
    } else {
      gemm_rows_mfma<<<dim3(17, 4), 256, 0, stream>>>(tgt, nullptr, r1w16, reg_b1, nullptr, mh1, MR, DD, DD, 1);
      gemm_rows_mfma<<<dim3(17, 4), 256, 0, stream>>>(mh1, nullptr, r2w16, reg_b2, nullptr, mh2, MR, DD, DD, 1);
      mask_reg_kernel<<<270, 256, 0, stream>>>(mh2, reg_w3, reg_b3, anchors, lohi,
          FOCUS_H[i] * PS0, FOCUS_H[i] * PS1, FOCUS_H[i] * PS2);
    }

    // CA: q from (tgt+qpos)@ca_k_w; K from (src+pos)@ca_k_w; V from src@ca_v_w
    gemm_rows_mfma<<<dim3(17, 4), 256, 0, stream>>>(tgt, qpos, kw16 + (size_t)i * DD * DD,
                                                    nullptr, nullptr, caq, MR, DD, DD, 0);
    gemm_kv2_mfma<<<dim3(100, 2, 4), 256, 0, stream>>>(kv16, s16,
                                                       kw16 + (size_t)i * DD * DD,
                                                       vw16 + (size_t)i * DD * DD, Kb, Vb);
    ca_attn_part<<<MR * NSPL, 256, 0, stream>>>(caq, Kb, Vb, lohi, pmb, psb, pob);
    ca_merge<<<270, 256, 0, stream>>>(pmb, psb, pob, cao);
    gemm_rows_mfma<<<dim3(17, 4), 256, 0, stream>>>(cao, nullptr, pw16 + (size_t)i * DD * DD,
                                                    ca_proj_b + (size_t)i * DD, tgt, tmp, MR, DD, DD, 0);
    ln_kernel<<<270, 256, 0, stream>>>(tmp, ln1_g + i * DD, ln1_b + i * DD, tgt);

    // FFN
    gemm_rows_mfma<<<dim3(17, 16), 256, 0, stream>>>(tgt, nullptr, f1w16 + (size_t)i * FFD * DD,
                                                     ffn_b1 + (size_t)i * FFD, nullptr, ffh, MR, FFD, DD, 1);
    gemm_rows_mfma<<<dim3(17, 4), 256, 0, stream>>>(ffh, nullptr, f2w16 + (size_t)i * DD * FFD,
                                                    ffn_b2 + (size_t)i * DD, tgt, tmp, MR, DD, FFD, 0);
    float* lno = (i == LL - 1) ? outp : tgt;
    ln_kernel<<<270, 256, 0, stream>>>(tmp, ln3_g + i * DD, ln3_b + i * DD, lno);
  }
}

// Round 17
// 1642.531 us; speedup vs baseline: 1.2090x; 1.0553x over previous
//
#include <hip/hip_runtime.h>
#include <hip/hip_fp16.h>
#include <math.h>

#define BB 2
#define DD 256
#define HH 8
#define HDIM 32
#define FFD 1024
#define LL 6
#define NQQ 540
#define QPO_ 27
#define PS0 20
#define PS1 20
#define PS2 32
#define PP (PS0*PS1*PS2)   // 12800
#define MR (BB*NQQ)        // 1080
#define NSPL 8             // cross-attn row-partials per query (4-wave blocks)

typedef _Float16 half8 __attribute__((ext_vector_type(8)));
typedef _Float16 h2v  __attribute__((ext_vector_type(2)));
typedef float f32x4 __attribute__((ext_vector_type(4)));

static __device__ __forceinline__ float wred_sum(float x) {
#pragma unroll
  for (int off = 32; off; off >>= 1) x += __shfl_xor(x, off, 64);
  return x;
}
static __device__ __forceinline__ float4 h4_to_f4(uint2 u) {
  __half2 h0 = *reinterpret_cast<__half2*>(&u.x);
  __half2 h1 = *reinterpret_cast<__half2*>(&u.y);
  float2 f0 = __half22float2(h0);
  float2 f1 = __half22float2(h1);
  return make_float4(f0.x, f0.y, f1.x, f1.y);
}
static __device__ __forceinline__ float dot4h(uint2 kw, h2v q01, h2v q23) {
  h2v a = *reinterpret_cast<h2v*>(&kw.x);
  h2v b = *reinterpret_cast<h2v*>(&kw.y);
  float d = __builtin_amdgcn_fdot2(a, q01, 0.f, false);
  return __builtin_amdgcn_fdot2(b, q23, d, false);
}

// ---------------------------------------------------------------------------
// init: tgt[b,q,d] = qe[q, 256+d]; qpos[b,q,d] = qe[q, d]
__global__ __launch_bounds__(256) void init_kernel(
    const float* __restrict__ qe, float* __restrict__ tgt, float* __restrict__ qpos)
{
  int idx = blockIdx.x * 256 + threadIdx.x;   // < B*NQ*D == 276480
  int d = idx % DD;
  int q = (idx / DD) % NQQ;
  qpos[idx] = qe[q * 512 + d];
  tgt[idx]  = qe[q * 512 + 256 + d];
}

// ---------------------------------------------------------------------------
// One-time: transpose+convert src/pos to fp16 [b][p][d] layouts.
__global__ __launch_bounds__(256) void conv_kv_inputs(
    const float* __restrict__ src, const float* __restrict__ pos,
    __half* __restrict__ s16, __half* __restrict__ kv16)
{
  __shared__ float ls[64][65];
  __shared__ float lk[64][65];
  int b  = blockIdx.z;
  int p0 = blockIdx.x * 64;
  int d0 = blockIdx.y * 64;
  int t = threadIdx.x;
  int pr = (t & 15) * 4;
  int dr = t >> 4;
#pragma unroll
  for (int dd = 0; dd < 64; dd += 16) {
    int d = d0 + dd + dr;
    float4 sv = *(const float4*)&src[((size_t)b * DD + d) * PP + p0 + pr];
    float4 pv = *(const float4*)&pos[((size_t)b * DD + d) * PP + p0 + pr];
    ls[pr + 0][dd + dr] = sv.x; ls[pr + 1][dd + dr] = sv.y;
    ls[pr + 2][dd + dr] = sv.z; ls[pr + 3][dd + dr] = sv.w;
    lk[pr + 0][dd + dr] = sv.x + pv.x; lk[pr + 1][dd + dr] = sv.y + pv.y;
    lk[pr + 2][dd + dr] = sv.z + pv.z; lk[pr + 3][dd + dr] = sv.w + pv.w;
  }
  __syncthreads();
  int wp = t >> 2;
  int wd = (t & 3) * 16;
  size_t base = ((size_t)b * PP + p0 + wp) * 256 + d0 + wd;
#pragma unroll
  for (int i = 0; i < 16; i += 2) {
    *(__half2*)&s16[base + i]  = __floats2half2_rn(ls[wp][wd + i], ls[wp][wd + i + 1]);
    *(__half2*)&kv16[base + i] = __floats2half2_rn(lk[wp][wd + i], lk[wp][wd + i + 1]);
  }
}

// One-time: fp32 -> fp16 weight conversion (grid-stride).
__global__ __launch_bounds__(256) void conv_w(
    const float* __restrict__ w, __half* __restrict__ w16, int n)
{
  for (int i = blockIdx.x * 256 + threadIdx.x; i < n; i += gridDim.x * 256)
    w16[i] = __float2half_rn(w[i]);
}

// ---------------------------------------------------------------------------
// Merged MFMA K&V projection: z>>1 selects (A,W,out) pair, z&1 = batch b.
__global__ __launch_bounds__(256) void gemm_kv2_mfma(
    const __half* __restrict__ Ak, const __half* __restrict__ Av,
    const __half* __restrict__ Wk, const __half* __restrict__ Wv,
    __half* __restrict__ Ko, __half* __restrict__ Vo)
{
  int z = blockIdx.z;
  int b = z & 1;
  const __half* A = (z >> 1) ? Av : Ak;
  const __half* W = (z >> 1) ? Wv : Wk;
  __half* out     = (z >> 1) ? Vo : Ko;
  int wid = threadIdx.x >> 6;
  int lane = threadIdx.x & 63;
  int p0 = blockIdx.x * 128 + (wid >> 1) * 64;
  int n0 = blockIdx.y * 128 + (wid & 1) * 64;
  const __half* Ab = A + (size_t)b * PP * 256;
  int row = lane & 15;
  int kg  = lane >> 4;
  f32x4 acc[4][4] = {};
  for (int k0 = 0; k0 < 256; k0 += 32) {
    half8 af[4], bf[4];
#pragma unroll
    for (int i = 0; i < 4; ++i)
      af[i] = *(const half8*)&Ab[((size_t)(p0 + 16 * i + row)) * 256 + k0 + kg * 8];
#pragma unroll
    for (int j = 0; j < 4; ++j)
      bf[j] = *(const half8*)&W[((size_t)(n0 + 16 * j + row)) * 256 + k0 + kg * 8];
#pragma unroll
    for (int i = 0; i < 4; ++i)
#pragma unroll
      for (int j = 0; j < 4; ++j)
        acc[i][j] = __builtin_amdgcn_mfma_f32_16x16x32_f16(af[i], bf[j], acc[i][j], 0, 0, 0);
  }
#pragma unroll
  for (int i = 0; i < 4; ++i)
#pragma unroll
    for (int j = 0; j < 4; ++j) {
      int nc = n0 + 16 * j + row;
#pragma unroll
      for (int r = 0; r < 4; ++r) {
        int pr = p0 + 16 * i + kg * 4 + r;
        out[((size_t)b * PP + pr) * 256 + nc] = __float2half_rn(acc[i][j][r]);
      }
    }
}

// ---------------------------------------------------------------------------
// MFMA row GEMM: C[r,n] = (A1[r,:](+A2[r,:])) @ W16[n,:] (+bias)(+res)(relu).
__global__ __launch_bounds__(256) void gemm_rows_mfma(
    const float* __restrict__ A1, const float* __restrict__ A2,
    const __half* __restrict__ W, const float* __restrict__ bias,
    const float* __restrict__ res, float* __restrict__ C,
    int M, int N, int K, int relu)
{
  __shared__ __half a_s[64][40];
  int bm = blockIdx.x * 64;
  int bn = blockIdx.y * 64;
  int wv = threadIdx.x >> 6;
  int lane = threadIdx.x & 63;
  int row = lane & 15;
  int kg  = lane >> 4;
  int nw  = bn + wv * 16;
  int t = threadIdx.x;
  int srow = t >> 2, skq = (t & 3) * 8;
  f32x4 acc[4] = {};

  for (int k0 = 0; k0 < K; k0 += 32) {
    {
      size_t off = (size_t)(bm + srow) * K + k0 + skq;
      float4 a0 = *(const float4*)&A1[off];
      float4 a1 = *(const float4*)&A1[off + 4];
      if (A2) {
        float4 b0 = *(const float4*)&A2[off];
        float4 b1 = *(const float4*)&A2[off + 4];
        a0.x += b0.x; a0.y += b0.y; a0.z += b0.z; a0.w += b0.w;
        a1.x += b1.x; a1.y += b1.y; a1.z += b1.z; a1.w += b1.w;
      }
      half8 h;
      h[0] = (_Float16)a0.x; h[1] = (_Float16)a0.y;
      h[2] = (_Float16)a0.z; h[3] = (_Float16)a0.w;
      h[4] = (_Float16)a1.x; h[5] = (_Float16)a1.y;
      h[6] = (_Float16)a1.z; h[7] = (_Float16)a1.w;
      *(half8*)&a_s[srow][skq] = h;
    }
    __syncthreads();
    half8 bf = *(const half8*)&W[(size_t)(nw + row) * K + k0 + kg * 8];
#pragma unroll
    for (int i = 0; i < 4; ++i) {
      half8 af = *(const half8*)&a_s[16 * i + row][kg * 8];
      acc[i] = __builtin_amdgcn_mfma_f32_16x16x32_f16(af, bf, acc[i], 0, 0, 0);
    }
    __syncthreads();
  }

  int col = nw + row;
  float bval = bias ? bias[col] : 0.f;
#pragma unroll
  for (int i = 0; i < 4; ++i) {
#pragma unroll
    for (int r = 0; r < 4; ++r) {
      int rr = bm + 16 * i + kg * 4 + r;
      if (rr >= M) continue;
      float v = acc[i][r] + bval;
      if (relu) v = fmaxf(v, 0.f);
      if (res)  v += res[(size_t)rr * N + col];
      C[(size_t)rr * N + col] = v;
    }
  }
}

// ---------------------------------------------------------------------------
// MFMA row GEMM with fp16 output (for SA q/k/v buffers): C16 = A1(+A2) @ W16 + bias.
__global__ __launch_bounds__(256) void gemm_rows_mfma_h(
    const float* __restrict__ A1, const float* __restrict__ A2,
    const __half* __restrict__ W, const float* __restrict__ bias,
    __half* __restrict__ C, int M, int N, int K)
{
  __shared__ __half a_s[64][40];
  int bm = blockIdx.x * 64;
  int bn = blockIdx.y * 64;
  int wv = threadIdx.x >> 6;
  int lane = threadIdx.x & 63;
  int row = lane & 15;
  int kg  = lane >> 4;
  int nw  = bn + wv * 16;
  int t = threadIdx.x;
  int srow = t >> 2, skq = (t & 3) * 8;
  f32x4 acc[4] = {};

  for (int k0 = 0; k0 < K; k0 += 32) {
    {
      size_t off = (size_t)(bm + srow) * K + k0 + skq;
      float4 a0 = *(const float4*)&A1[off];
      float4 a1 = *(const float4*)&A1[off + 4];
      if (A2) {
        float4 b0 = *(const float4*)&A2[off];
        float4 b1 = *(const float4*)&A2[off + 4];
        a0.x += b0.x; a0.y += b0.y; a0.z += b0.z; a0.w += b0.w;
        a1.x += b1.x; a1.y += b1.y; a1.z += b1.z; a1.w += b1.w;
      }
      half8 h;
      h[0] = (_Float16)a0.x; h[1] = (_Float16)a0.y;
      h[2] = (_Float16)a0.z; h[3] = (_Float16)a0.w;
      h[4] = (_Float16)a1.x; h[5] = (_Float16)a1.y;
      h[6] = (_Float16)a1.z; h[7] = (_Float16)a1.w;
      *(half8*)&a_s[srow][skq] = h;
    }
    __syncthreads();
    half8 bf = *(const half8*)&W[(size_t)(nw + row) * K + k0 + kg * 8];
#pragma unroll
    for (int i = 0; i < 4; ++i) {
      half8 af = *(const half8*)&a_s[16 * i + row][kg * 8];
      acc[i] = __builtin_amdgcn_mfma_f32_16x16x32_f16(af, bf, acc[i], 0, 0, 0);
    }
    __syncthreads();
  }

  int col = nw + row;
  float bval = bias ? bias[col] : 0.f;
#pragma unroll
  for (int i = 0; i < 4; ++i) {
#pragma unroll
    for (int r = 0; r < 4; ++r) {
      int rr = bm + 16 * i + kg * 4 + r;
      if (rr >= M) continue;
      C[(size_t)rr * N + col] = __float2half_rn(acc[i][r] + bval);
    }
  }
}

// ---------------------------------------------------------------------------
// Self-attention, fp16 K/V, all-heads-batched, defer-max. One block (8 waves)
// per (b,q). qk16: (MR,512) q cols 0..255, k cols 256..511. v16: (MR,256).
__global__ __launch_bounds__(512) void sa_attn(
    const __half* __restrict__ qk16, const __half* __restrict__ v16,
    float* __restrict__ out)
{
  __shared__ float wmS[8][8];
  __shared__ float wsS[8][8];
  __shared__ float4 ooS[8][64];

  int bid = blockIdx.x;           // b*NQQ + q
  int b = bid / NQQ;
  int wv = threadIdx.x >> 6;
  int lane = threadIdx.x & 63;
  const float scale = 0.17677669529663687f;  // 32^-0.5

  uint2 qw = ((const uint2*)(qk16 + (size_t)bid * 512))[lane];
  float4 q4 = h4_to_f4(qw);
  q4.x *= scale; q4.y *= scale; q4.z *= scale; q4.w *= scale;
  h2v q01, q23;
  q01[0] = (_Float16)q4.x; q01[1] = (_Float16)q4.y;
  q23[0] = (_Float16)q4.z; q23[1] = (_Float16)q4.w;

  const __half* Kb = qk16 + (size_t)b * NQQ * 512 + 256;  // k part of rows
  const __half* Vb = v16 + (size_t)b * NQQ * 256;

  float m = -INFINITY, sA = 0.f, sB = 0.f;
  float4 oA = make_float4(0.f, 0.f, 0.f, 0.f);
  float4 oB = make_float4(0.f, 0.f, 0.f, 0.f);

  for (int k0 = wv * 8; k0 < NQQ; k0 += 64) {
    const uint2* kp = (const uint2*)(Kb + (size_t)k0 * 512) + lane;
    const uint2* vp = (const uint2*)(Vb + (size_t)k0 * 256) + lane;
    uint2 kw[8];
#pragma unroll
    for (int i = 0; i < 8; ++i) kw[i] = kp[i * 128];   // row stride 512 halfs
    uint2 vw[8];
#pragma unroll
    for (int i = 0; i < 8; ++i) vw[i] = vp[i * 64];

    float lg[8];
#pragma unroll
    for (int i = 0; i < 8; ++i) {
      float d = dot4h(kw[i], q01, q23);
      d += __shfl_xor(d, 1, 64);
      d += __shfl_xor(d, 2, 64);
      d += __shfl_xor(d, 4, 64);
      lg[i] = (k0 + i < NQQ) ? d : -INFINITY;
    }

    float bm = fmaxf(fmaxf(fmaxf(lg[0], lg[1]), fmaxf(lg[2], lg[3])),
                     fmaxf(fmaxf(lg[4], lg[5]), fmaxf(lg[6], lg[7])));
    if (bm > m + 8.f) {              // defer-max: rare after warm-up
      float f = __expf(m - bm);      // m=-inf first -> 0
      sA *= f; sB *= f;
      oA.x *= f; oA.y *= f; oA.z *= f; oA.w *= f;
      oB.x *= f; oB.y *= f; oB.z *= f; oB.w *= f;
      m = bm;
    }
#pragma unroll
    for (int i = 0; i < 8; i += 2) {
      float pa = __expf(lg[i] - m);
      float pb = __expf(lg[i + 1] - m);
      float4 va = h4_to_f4(vw[i]);
      float4 vb = h4_to_f4(vw[i + 1]);
      sA += pa; sB += pb;
      oA.x = fmaf(pa, va.x, oA.x); oB.x = fmaf(pb, vb.x, oB.x);
      oA.y = fmaf(pa, va.y, oA.y); oB.y = fmaf(pb, vb.y, oB.y);
      oA.z = fmaf(pa, va.z, oA.z); oB.z = fmaf(pb, vb.z, oB.z);
      oA.w = fmaf(pa, va.w, oA.w); oB.w = fmaf(pb, vb.w, oB.w);
    }
  }

  float s = sA + sB;
  float4 o4 = make_float4(oA.x + oB.x, oA.y + oB.y, oA.z + oB.z, oA.w + oB.w);

  // ---- merge 8 wave-states (per head) ----
  int hg = lane >> 3, sub = lane & 7;
  if (sub == 0) wmS[wv][hg] = m;
  __syncthreads();
  float M = wmS[0][hg];
#pragma unroll
  for (int w = 1; w < 8; ++w) M = fmaxf(M, wmS[w][hg]);
  float f = __expf(m - M);
  if (sub == 0) wsS[wv][hg] = s * f;
  ooS[wv][lane] = make_float4(o4.x * f, o4.y * f, o4.z * f, o4.w * f);
  __syncthreads();
  if (threadIdx.x < 64) {
    int l = threadIdx.x;
    int hg2 = l >> 3;
    float4 acc = make_float4(0.f, 0.f, 0.f, 0.f);
    float den = 0.f;
#pragma unroll
    for (int w = 0; w < 8; ++w) {
      float4 t = ooS[w][l];
      acc.x += t.x; acc.y += t.y; acc.z += t.z; acc.w += t.w;
      den += wsS[w][hg2];
    }
    float inv = 1.f / den;
    float4 res = make_float4(acc.x * inv, acc.y * inv, acc.z * inv, acc.w * inv);
    *(float4*)&out[(size_t)bid * 256 + l * 4] = res;
  }
}

// ---------------------------------------------------------------------------
// Cross-attention partial, 2-keys-per-pass layout: lane owns 8 dims
// (8*(lane&31)) of key 2j+(lane>>5); 4 passes per 8-key z-batch.
// 16B K/V loads; dot reduce over 4 lanes (2 shfl/key); 4 exp/batch/lane.
// 256-thr (4-wave) blocks, NSPL=8, XCD swizzle, defer-max.
__global__ __launch_bounds__(256) void ca_attn_part(
    const float* __restrict__ qbuf, const __half* __restrict__ Kbuf,
    const __half* __restrict__ Vbuf, const int* __restrict__ lohi,
    float* __restrict__ pm, float* __restrict__ ps, float* __restrict__ po)
{
  __shared__ float wmS[4][8];
  __shared__ float wsS[4][8];
  __shared__ float4 ooS[4][64];

  // --- swizzle: 8640 blocks = 8 cls x 5 gsub x 27 iq x 8 part ---
  int idx  = blockIdx.x;
  int cls  = idx & 7;
  int rest = idx >> 3;          // 0..1079
  int gsub = rest / 216;        // 0..4
  int rem  = rest % 216;
  int iq   = rem >> 3;          // 0..26
  int part = rem & 7;           // NSPL == 8
  int g    = gsub * 8 + cls;    // organ-group 0..39
  int b    = g / 20;
  int q    = (g % 20) * QPO_ + iq;
  int bid  = b * NQQ + q;

  int wv = threadIdx.x >> 6;    // 0..3
  int lane = threadIdx.x & 63;
  int li   = lane & 31;         // dim-slot: dims 8*li .. 8*li+7
  int half = lane >> 5;         // even/odd key of each pass
  const float scale = 0.17677669529663687f;

  const int* lh = lohi + (size_t)bid * 6;
  int lo0 = lh[0], lo1 = lh[1], lo2 = lh[2];
  int nx = lh[3] - lo0, ny = lh[4] - lo1, nz = lh[5] - lo2;
  int nxy = nx * ny;
  float inv_ny = 1.0f / (float)ny;

  // q: 8 dims per lane, pre-scaled, as 4 h2v
  const float4* qp = (const float4*)(qbuf + (size_t)bid * 256 + 8 * li);
  float4 qa = qp[0], qb = qp[1];
  h2v qh0, qh1, qh2, qh3;
  qh0[0] = (_Float16)(qa.x * scale); qh0[1] = (_Float16)(qa.y * scale);
  qh1[0] = (_Float16)(qa.z * scale); qh1[1] = (_Float16)(qa.w * scale);
  qh2[0] = (_Float16)(qb.x * scale); qh2[1] = (_Float16)(qb.y * scale);
  qh3[0] = (_Float16)(qb.z * scale); qh3[1] = (_Float16)(qb.w * scale);

  const __half* Kb = Kbuf + (size_t)b * PP * 256;
  const __half* Vb = Vbuf + (size_t)b * PP * 256;

  float m = -INFINITY, sA = 0.f, sB = 0.f;
  float4 oA0 = make_float4(0.f, 0.f, 0.f, 0.f), oA1 = oA0;
  float4 oB0 = oA0, oB1 = oA0;

  for (int r = part + 8 * wv; r < nxy; r += 32) {
    int x = (int)((float)r * inv_ny);
    int y = r - x * ny;
    if (y < 0)        { x--; y += ny; }
    else if (y >= ny) { x++; y -= ny; }
    int base = (lo0 + x) * (PS1 * PS2) + (lo1 + y) * PS2 + lo2;

    for (int z0 = 0; z0 < nz; z0 += 8) {
      // lane's key for pass j: base + z0 + 2j + half; dims 8*li (16B)
      const uint4* kp = (const uint4*)(Kb + ((size_t)(base + z0 + half)) * 256 + 8 * li);
      const uint4* vp = (const uint4*)(Vb + ((size_t)(base + z0 + half)) * 256 + 8 * li);
      uint4 kw0 = kp[0],  kw1 = kp[64], kw2 = kp[128], kw3 = kp[192]; // 2-row step
      uint4 vw0 = vp[0],  vw1 = vp[64], vw2 = vp[128], vw3 = vp[192];

      float lg[4];
#pragma unroll
      for (int j = 0; j < 4; ++j) {
        uint4 kwj = (j == 0) ? kw0 : (j == 1) ? kw1 : (j == 2) ? kw2 : kw3;
        h2v a0 = *reinterpret_cast<h2v*>(&kwj.x);
        h2v a1 = *reinterpret_cast<h2v*>(&kwj.y);
        h2v a2 = *reinterpret_cast<h2v*>(&kwj.z);
        h2v a3 = *reinterpret_cast<h2v*>(&kwj.w);
        float d = __builtin_amdgcn_fdot2(a0, qh0, 0.f, false);
        d = __builtin_amdgcn_fdot2(a1, qh1, d, false);
        d = __builtin_amdgcn_fdot2(a2, qh2, d, false);
        d = __builtin_amdgcn_fdot2(a3, qh3, d, false);
        d += __shfl_xor(d, 1, 64);          // reduce over the 4 lanes of head
        d += __shfl_xor(d, 2, 64);
        lg[j] = (z0 + 2 * j + half < nz) ? d : -INFINITY;
      }

      float bm = fmaxf(fmaxf(lg[0], lg[1]), fmaxf(lg[2], lg[3]));
      bm = fmaxf(bm, __shfl_xor(bm, 32, 64));   // even|odd keys -> head max
      if (bm > m + 8.f) {                       // defer-max; first batch fires
        float f = __expf(m - bm);               // m=-inf -> 0
        sA *= f; sB *= f;
        oA0.x *= f; oA0.y *= f; oA0.z *= f; oA0.w *= f;
        oA1.x *= f; oA1.y *= f; oA1.z *= f; oA1.w *= f;
        oB0.x *= f; oB0.y *= f; oB0.z *= f; oB0.w *= f;
        oB1.x *= f; oB1.y *= f; oB1.z *= f; oB1.w *= f;
        m = bm;
      }
      {
        float pa = __expf(lg[0] - m);
        float pb = __expf(lg[1] - m);
        float4 alo = h4_to_f4(make_uint2(vw0.x, vw0.y));
        float4 ahi = h4_to_f4(make_uint2(vw0.z, vw0.w));
        float4 blo = h4_to_f4(make_uint2(vw1.x, vw1.y));
        float4 bhi = h4_to_f4(make_uint2(vw1.z, vw1.w));
        sA += pa; sB += pb;
        oA0.x = fmaf(pa, alo.x, oA0.x); oB0.x = fmaf(pb, blo.x, oB0.x);
        oA0.y = fmaf(pa, alo.y, oA0.y); oB0.y = fmaf(pb, blo.y, oB0.y);
        oA0.z = fmaf(pa, alo.z, oA0.z); oB0.z = fmaf(pb, blo.z, oB0.z);
        oA0.w = fmaf(pa, alo.w, oA0.w); oB0.w = fmaf(pb, blo.w, oB0.w);
        oA1.x = fmaf(pa, ahi.x, oA1.x); oB1.x = fmaf(pb, bhi.x, oB1.x);
        oA1.y = fmaf(pa, ahi.y, oA1.y); oB1.y = fmaf(pb, bhi.y, oB1.y);
        oA1.z = fmaf(pa, ahi.z, oA1.z); oB1.z = fmaf(pb, bhi.z, oB1.z);
        oA1.w = fmaf(pa, ahi.w, oA1.w); oB1.w = fmaf(pb, bhi.w, oB1.w);
      }
      {
        float pa = __expf(lg[2] - m);
        float pb = __expf(lg[3] - m);
        float4 alo = h4_to_f4(make_uint2(vw2.x, vw2.y));
        float4 ahi = h4_to_f4(make_uint2(vw2.z, vw2.w));
        float4 blo = h4_to_f4(make_uint2(vw3.x, vw3.y));
        float4 bhi = h4_to_f4(make_uint2(vw3.z, vw3.w));
        sA += pa; sB += pb;
        oA0.x = fmaf(pa, alo.x, oA0.x); oB0.x = fmaf(pb, blo.x, oB0.x);
        oA0.y = fmaf(pa, alo.y, oA0.y); oB0.y = fmaf(pb, blo.y, oB0.y);
        oA0.z = fmaf(pa, alo.z, oA0.z); oB0.z = fmaf(pb, blo.z, oB0.z);
        oA0.w = fmaf(pa, alo.w, oA0.w); oB0.w = fmaf(pb, blo.w, oB0.w);
        oA1.x = fmaf(pa, ahi.x, oA1.x); oB1.x = fmaf(pb, bhi.x, oB1.x);
        oA1.y = fmaf(pa, ahi.y, oA1.y); oB1.y = fmaf(pb, bhi.y, oB1.y);
        oA1.z = fmaf(pa, ahi.z, oA1.z); oB1.z = fmaf(pb, bhi.z, oB1.z);
        oA1.w = fmaf(pa, ahi.w, oA1.w); oB1.w = fmaf(pb, bhi.w, oB1.w);
      }
    }
  }

  // ---- merge even|odd key halves across lane^32 ----
  float s = sA + sB;
  s += __shfl_xor(s, 32, 64);
  float4 oL = make_float4(oA0.x + oB0.x, oA0.y + oB0.y, oA0.z + oB0.z, oA0.w + oB0.w);
  float4 oH = make_float4(oA1.x + oB1.x, oA1.y + oB1.y, oA1.z + oB1.z, oA1.w + oB1.w);
  oL.x += __shfl_xor(oL.x, 32, 64); oL.y += __shfl_xor(oL.y, 32, 64);
  oL.z += __shfl_xor(oL.z, 32, 64); oL.w += __shfl_xor(oL.w, 32, 64);
  oH.x += __shfl_xor(oH.x, 32, 64); oH.y += __shfl_xor(oH.y, 32, 64);
  oH.z += __shfl_xor(oH.z, 32, 64); oH.w += __shfl_xor(oH.w, 32, 64);

  // ---- merge this block's 4 wave-states; write partial (M, S, O) ----
  int hh = li >> 2;               // head of this lane's dims
  if (lane < 32 && (li & 3) == 0) wmS[wv][hh] = m;
  __syncthreads();
  float M = wmS[0][hh];
#pragma unroll
  for (int w = 1; w < 4; ++w) M = fmaxf(M, wmS[w][hh]);
  float f = (M == -INFINITY) ? 0.f : __expf(m - M);  // empty part -> zeros
  if (lane < 32 && (li & 3) == 0) wsS[wv][hh] = s * f;
  if (lane < 32) {
    ooS[wv][2 * li]     = make_float4(oL.x * f, oL.y * f, oL.z * f, oL.w * f);
    ooS[wv][2 * li + 1] = make_float4(oH.x * f, oH.y * f, oH.z * f, oH.w * f);
  }
  __syncthreads();
  if (threadIdx.x < 64) {
    int l = threadIdx.x;
    int hg2 = l >> 3;
    float4 acc = make_float4(0.f, 0.f, 0.f, 0.f);
    float den = 0.f;
#pragma unroll
    for (int w = 0; w < 4; ++w) {
      float4 t = ooS[w][l];
      acc.x += t.x; acc.y += t.y; acc.z += t.z; acc.w += t.w;
      den += wsS[w][hg2];
    }
    float M2 = wmS[0][hg2];
#pragma unroll
    for (int w = 1; w < 4; ++w) M2 = fmaxf(M2, wmS[w][hg2]);
    size_t pb = (size_t)bid * NSPL + part;
    if ((l & 7) == 0) { pm[pb * 8 + hg2] = M2; ps[pb * 8 + hg2] = den; }
    *(float4*)&po[pb * 256 + l * 4] = acc;
  }
}

// ---------------------------------------------------------------------------
// Merge NSPL cross-attn partials per query. One wave per (b,q).
__global__ __launch_bounds__(256) void ca_merge(
    const float* __restrict__ pm, const float* __restrict__ ps,
    const float* __restrict__ po, float* __restrict__ out)
{
  int wv = threadIdx.x >> 6;
  int lane = threadIdx.x & 63;
  int bid = blockIdx.x * 4 + wv;
  int hg = lane >> 3;
  size_t pb = (size_t)bid * NSPL;

  float mp[NSPL], sp[NSPL];
#pragma unroll
  for (int p = 0; p < NSPL; ++p) {
    mp[p] = pm[(pb + p) * 8 + hg];
    sp[p] = ps[(pb + p) * 8 + hg];
  }
  float M = mp[0];
#pragma unroll
  for (int p = 1; p < NSPL; ++p) M = fmaxf(M, mp[p]);
  float den = 0.f;
  float4 acc = make_float4(0.f, 0.f, 0.f, 0.f);
#pragma unroll
  for (int p = 0; p < NSPL; ++p) {
    float f = __expf(mp[p] - M);     // empty part m=-inf -> 0
    den = fmaf(f, sp[p], den);
    float4 t = *(const float4*)&po[(pb + p) * 256 + lane * 4];
    acc.x = fmaf(f, t.x, acc.x);
    acc.y = fmaf(f, t.y, acc.y);
    acc.z = fmaf(f, t.z, acc.z);
    acc.w = fmaf(f, t.w, acc.w);
  }
  float inv = 1.f / den;
  float4 res = make_float4(acc.x * inv, acc.y * inv, acc.z * inv, acc.w * inv);
  *(float4*)&out[(size_t)bid * 256 + lane * 4] = res;
}

// ---------------------------------------------------------------------------
// LayerNorm over D=256: one wave per row. x already contains residual sum.
__global__ __launch_bounds__(256) void ln_kernel(
    const float* __restrict__ x, const float* __restrict__ g,
    const float* __restrict__ bta, float* __restrict__ out)
{
  int wv = threadIdx.x >> 6;
  int lane = threadIdx.x & 63;
  int row = blockIdx.x * 4 + wv;
  const float* xr = x + (size_t)row * 256;
  float v[4];
#pragma unroll
  for (int j = 0; j < 4; ++j) v[j] = xr[lane + 64 * j];
  float s = v[0] + v[1] + v[2] + v[3];
  s = wred_sum(s);
  float mean = s * (1.f / 256.f);
  float vs = 0.f;
#pragma unroll
  for (int j = 0; j < 4; ++j) { float d = v[j] - mean; vs = fmaf(d, d, vs); }
  vs = wred_sum(vs);
  float inv = rsqrtf(vs * (1.f / 256.f) + 1e-5f);
  float* orow = out + (size_t)row * 256;
#pragma unroll
  for (int j = 0; j < 4; ++j) {
    int c = lane + 64 * j;
    orow[c] = (v[j] - mean) * inv * g[c] + bta[c];
  }
}

// ---------------------------------------------------------------------------
// Layer-0 mask boxes from attn_area.
__global__ __launch_bounds__(256) void mask0_kernel(
    const float* __restrict__ area, int* __restrict__ lohi,
    float px, float py, float pz)
{
  int row = blockIdx.x * 256 + threadIdx.x;
  if (row >= MR) return;
  int q = row % NQQ;
  int org = q / QPO_;
  const float* a = area + org * 6;
  int* o = lohi + (size_t)row * 6;
  o[0] = (int)fminf(fmaxf(floorf(a[0] * 20.f - px), 0.f), 20.f);
  o[1] = (int)fminf(fmaxf(floorf(a[1] * 20.f - py), 0.f), 20.f);
  o[2] = (int)fminf(fmaxf(floorf(a[2] * 32.f - pz), 0.f), 32.f);
  o[3] = (int)fminf(fmaxf(floorf(a[3] * 20.f + px), 0.f), 20.f);
  o[4] = (int)fminf(fmaxf(floorf(a[4] * 20.f + py), 0.f), 20.f);
  o[5] = (int)fminf(fmaxf(floorf(a[5] * 32.f + pz), 0.f), 32.f);
}

// ---------------------------------------------------------------------------
// Layers >=1: prop = h2 @ w3.T + b3 -> tanh*0.1 + anchors -> clip -> box ints.
__global__ __launch_bounds__(256) void mask_reg_kernel(
    const float* __restrict__ h2, const float* __restrict__ w3,
    const float* __restrict__ b3, const float* __restrict__ anchors,
    int* __restrict__ lohi, float px, float py, float pz)
{
  int wv = threadIdx.x >> 6;
  int lane = threadIdx.x & 63;
  int row = blockIdx.x * 4 + wv;
  int q = row % NQQ;
  const float* hr = h2 + (size_t)row * 256;
  float part[6] = {};
#pragma unroll
  for (int j = 0; j < 4; ++j) {
    float hv = hr[lane + 64 * j];
#pragma unroll
    for (int o = 0; o < 6; ++o)
      part[o] = fmaf(hv, w3[o * 256 + lane + 64 * j], part[o]);
  }
#pragma unroll
  for (int o = 0; o < 6; ++o) part[o] = wred_sum(part[o]);
  if (lane == 0) {
    float prop[6];
#pragma unroll
    for (int o = 0; o < 6; ++o) {
      float v = tanhf(part[o] + b3[o]) * 0.1f + anchors[q * 6 + o];
      prop[o] = fminf(fmaxf(v, 0.f), 1.f);
    }
    float vl0 = prop[0] - 0.5f * prop[3], vh0 = prop[0] + 0.5f * prop[3];
    float vl1 = prop[1] - 0.5f * prop[4], vh1 = prop[1] + 0.5f * prop[4];
    float vl2 = prop[2] - 0.5f * prop[5], vh2 = prop[2] + 0.5f * prop[5];
    int* o = lohi + (size_t)row * 6;
    o[0] = (int)fminf(fmaxf(floorf(vl0 * 20.f - px), 0.f), 20.f);
    o[1] = (int)fminf(fmaxf(floorf(vl1 * 20.f - py), 0.f), 20.f);
    o[2] = (int)fminf(fmaxf(floorf(vl2 * 32.f - pz), 0.f), 32.f);
    o[3] = (int)fminf(fmaxf(floorf(vh0 * 20.f + px), 0.f), 20.f);
    o[4] = (int)fminf(fmaxf(floorf(vh1 * 20.f + py), 0.f), 20.f);
    o[5] = (int)fminf(fmaxf(floorf(vh2 * 32.f + pz), 0.f), 32.f);
  }
}

// ---------------------------------------------------------------------------
extern "C" void kernel_launch(void* const* d_in, const int* in_sizes, int n_in,
                              void* d_out, int out_size, void* d_ws, size_t ws_size,
                              hipStream_t stream)
{
  const float* src       = (const float*)d_in[0];
  const float* pos       = (const float*)d_in[1];
  const float* qe        = (const float*)d_in[2];
  const float* sa_in_w   = (const float*)d_in[3];
  const float* sa_in_b   = (const float*)d_in[4];
  const float* sa_out_w  = (const float*)d_in[5];
  const float* sa_out_b  = (const float*)d_in[6];
  const float* ca_k_w    = (const float*)d_in[7];
  const float* ca_v_w    = (const float*)d_in[8];
  const float* ca_proj_w = (const float*)d_in[9];
  const float* ca_proj_b = (const float*)d_in[10];
  const float* ln1_g = (const float*)d_in[11];
  const float* ln1_b = (const float*)d_in[12];
  const float* ln2_g = (const float*)d_in[13];
  const float* ln2_b = (const float*)d_in[14];
  const float* ln3_g = (const float*)d_in[15];
  const float* ln3_b = (const float*)d_in[16];
  const float* ffn_w1 = (const float*)d_in[17];
  const float* ffn_b1 = (const float*)d_in[18];
  const float* ffn_w2 = (const float*)d_in[19];
  const float* ffn_b2 = (const float*)d_in[20];
  const float* reg_w1 = (const float*)d_in[21];
  const float* reg_b1 = (const float*)d_in[22];
  const float* reg_w2 = (const float*)d_in[23];
  const float* reg_b2 = (const float*)d_in[24];
  const float* reg_w3 = (const float*)d_in[25];
  const float* reg_b3 = (const float*)d_in[26];
  const float* anchors   = (const float*)d_in[27];
  const float* attn_area = (const float*)d_in[28];
  float* outp = (float*)d_out;

  float* ws = (float*)d_ws;
  size_t off = 0;
  auto alloc = [&](size_t n) { float* p = ws + off; off += n; return p; };
  __half* Kb = (__half*)alloc((size_t)BB * PP * 128);   // fp16 [b][p][256], 13.1 MB
  __half* Vb = (__half*)alloc((size_t)BB * PP * 128);   // fp16, 13.1 MB
  alloc(4096);                                          // over-read pad
  __half* s16  = (__half*)alloc((size_t)BB * PP * 128); // fp16(src) [b][p][d]
  __half* kv16 = (__half*)alloc((size_t)BB * PP * 128); // fp16(src+pos) [b][p][d]
  __half* kw16 = (__half*)alloc((size_t)LL * DD * DD / 2);
  __half* vw16 = (__half*)alloc((size_t)LL * DD * DD / 2);
  __half* saw16 = (__half*)alloc((size_t)LL * 768 * DD / 2);   // sa_in_w
  __half* sow16 = (__half*)alloc((size_t)LL * DD * DD / 2);    // sa_out_w
  __half* pw16  = (__half*)alloc((size_t)LL * DD * DD / 2);    // ca_proj_w
  __half* f1w16 = (__half*)alloc((size_t)LL * FFD * DD / 2);   // ffn_w1
  __half* f2w16 = (__half*)alloc((size_t)LL * DD * FFD / 2);   // ffn_w2
  __half* r1w16 = (__half*)alloc((size_t)DD * DD / 2);         // reg_w1
  __half* r2w16 = (__half*)alloc((size_t)DD * DD / 2);         // reg_w2
  __half* saqk16 = (__half*)alloc((size_t)MR * 512 / 2);       // SA q|k fp16
  __half* sav16  = (__half*)alloc((size_t)MR * 256 / 2);       // SA v fp16
  alloc(2048);                                          // SA over-read pad
  float* tgt  = alloc((size_t)MR * DD);
  float* qpos = alloc((size_t)MR * DD);
  float* tmp  = alloc((size_t)MR * DD);
  float* sao  = alloc((size_t)MR * DD);
  float* caq  = alloc((size_t)MR * DD);
  float* cao  = alloc((size_t)MR * DD);
  float* mh1  = alloc((size_t)MR * DD);
  float* mh2  = alloc((size_t)MR * DD);
  float* ffh  = alloc((size_t)MR * FFD);
  float* pmb  = alloc((size_t)MR * NSPL * 8);
  float* psb  = alloc((size_t)MR * NSPL * 8);
  float* pob  = alloc((size_t)MR * NSPL * 256);
  int*   lohi = (int*)alloc((size_t)MR * 6);
  alloc(4096);                                          // A over-read pad
  (void)in_sizes; (void)n_in; (void)out_size; (void)ws_size;

  const float FOCUS_H[6] = {0.1f, 0.075f, 0.05f, 0.05f, 0.025f, 0.025f};

  init_kernel<<<1080, 256, 0, stream>>>(qe, tgt, qpos);
  conv_kv_inputs<<<dim3(200, 4, 2), 256, 0, stream>>>(src, pos, s16, kv16);
  conv_w<<<768, 256, 0, stream>>>(ca_k_w, kw16, LL * DD * DD);
  conv_w<<<768, 256, 0, stream>>>(ca_v_w, vw16, LL * DD * DD);
  conv_w<<<768, 256, 0, stream>>>(sa_in_w, saw16, LL * 768 * DD);
  conv_w<<<768, 256, 0, stream>>>(sa_out_w, sow16, LL * DD * DD);
  conv_w<<<768, 256, 0, stream>>>(ca_proj_w, pw16, LL * DD * DD);
  conv_w<<<768, 256, 0, stream>>>(ffn_w1, f1w16, LL * FFD * DD);
  conv_w<<<768, 256, 0, stream>>>(ffn_w2, f2w16, LL * DD * FFD);
  conv_w<<<256, 256, 0, stream>>>(reg_w1, r1w16, DD * DD);
  conv_w<<<256, 256, 0, stream>>>(reg_w2, r2w16, DD * DD);

  for (int i = 0; i < LL; ++i) {
    const __half* wi16 = saw16 + (size_t)i * 768 * DD;
    const float*  bi   = sa_in_b + (size_t)i * 768;
    // SA: q,k from (tgt+qpos), v from tgt -> fp16 buffers
    gemm_rows_mfma_h<<<dim3(17, 8), 256, 0, stream>>>(tgt, qpos, wi16, bi, saqk16, MR, 512, DD);
    gemm_rows_mfma_h<<<dim3(17, 4), 256, 0, stream>>>(tgt, nullptr, wi16 + 512 * DD, bi + 512, sav16, MR, DD, DD);
    sa_attn<<<MR, 512, 0, stream>>>(saqk16, sav16, sao);
    gemm_rows_mfma<<<dim3(17, 4), 256, 0, stream>>>(sao, nullptr, sow16 + (size_t)i * DD * DD,
                                                    sa_out_b + (size_t)i * DD, tgt, tmp, MR, DD, DD, 0);
    ln_kernel<<<270, 256, 0, stream>>>(tmp, ln2_g + i * DD, ln2_b + i * DD, tgt);

    // mask boxes
    if (i == 0) {
      mask0_kernel<<<5, 256, 0, stream>>>(attn_area, lohi,
          FOCUS_H[0] * PS0, FOCUS_H[0] * PS1, FOCUS_H[0] * PS2);
    } else {
      gemm_rows_mfma<<<dim3(17, 4), 256, 0, stream>>>(tgt, nullptr, r1w16, reg_b1, nullptr, mh1, MR, DD, DD, 1);
      gemm_rows_mfma<<<dim3(17, 4), 256, 0, stream>>>(mh1, nullptr, r2w16, reg_b2, nullptr, mh2, MR, DD, DD, 1);
      mask_reg_kernel<<<270, 256, 0, stream>>>(mh2, reg_w3, reg_b3, anchors, lohi,
          FOCUS_H[i] * PS0, FOCUS_H[i] * PS1, FOCUS_H[i] * PS2);
    }

    // CA: q from (tgt+qpos)@ca_k_w; K from (src+pos)@ca_k_w; V from src@ca_v_w
    gemm_rows_mfma<<<dim3(17, 4), 256, 0, stream>>>(tgt, qpos, kw16 + (size_t)i * DD * DD,
                                                    nullptr, nullptr, caq, MR, DD, DD, 0);
    gemm_kv2_mfma<<<dim3(100, 2, 4), 256, 0, stream>>>(kv16, s16,
                                                       kw16 + (size_t)i * DD * DD,
                                                       vw16 + (size_t)i * DD * DD, Kb, Vb);
    ca_attn_part<<<MR * NSPL, 256, 0, stream>>>(caq, Kb, Vb, lohi, pmb, psb, pob);
    ca_merge<<<270, 256, 0, stream>>>(pmb, psb, pob, cao);
    gemm_rows_mfma<<<dim3(17, 4), 256, 0, stream>>>(cao, nullptr, pw16 + (size_t)i * DD * DD,
                                                    ca_proj_b + (size_t)i * DD, tgt, tmp, MR, DD, DD, 0);
    ln_kernel<<<270, 256, 0, stream>>>(tmp, ln1_g + i * DD, ln1_b + i * DD, tgt);

    // FFN
    gemm_rows_mfma<<<dim3(17, 16), 256, 0, stream>>>(tgt, nullptr, f1w16 + (size_t)i * FFD * DD,
                                                     ffn_b1 + (size_t)i * FFD, nullptr, ffh, MR, FFD, DD, 1);
    gemm_rows_mfma<<<dim3(17, 4), 256, 0, stream>>>(ffh, nullptr, f2w16 + (size_t)i * DD * FFD,
                                                    ffn_b2 + (size_t)i * DD, tgt, tmp, MR, DD, FFD, 0);
    float* lno = (i == LL - 1) ? outp : tgt;
    ln_kernel<<<270, 256, 0, stream>>>(tmp, ln3_g + i * DD, ln3_b + i * DD, lno);
  }
}

// Round 18
// 1557.143 us; speedup vs baseline: 1.2753x; 1.0548x over previous
//
#include <hip/hip_runtime.h>
#include <hip/hip_fp16.h>
#include <math.h>

#define BB 2
#define DD 256
#define HH 8
#define HDIM 32
#define FFD 1024
#define LL 6
#define NQQ 540
#define QPO_ 27
#define PS0 20
#define PS1 20
#define PS2 32
#define PP (PS0*PS1*PS2)   // 12800
#define MR (BB*NQQ)        // 1080
#define NSPL 8             // cross-attn row-partials per query (4-wave blocks)

typedef _Float16 half8 __attribute__((ext_vector_type(8)));
typedef _Float16 h2v  __attribute__((ext_vector_type(2)));
typedef float f32x4 __attribute__((ext_vector_type(4)));

static __device__ __forceinline__ float wred_sum(float x) {
#pragma unroll
  for (int off = 32; off; off >>= 1) x += __shfl_xor(x, off, 64);
  return x;
}
static __device__ __forceinline__ float4 h4_to_f4(uint2 u) {
  __half2 h0 = *reinterpret_cast<__half2*>(&u.x);
  __half2 h1 = *reinterpret_cast<__half2*>(&u.y);
  float2 f0 = __half22float2(h0);
  float2 f1 = __half22float2(h1);
  return make_float4(f0.x, f0.y, f1.x, f1.y);
}
static __device__ __forceinline__ float dot4h(uint2 kw, h2v q01, h2v q23) {
  h2v a = *reinterpret_cast<h2v*>(&kw.x);
  h2v b = *reinterpret_cast<h2v*>(&kw.y);
  float d = __builtin_amdgcn_fdot2(a, q01, 0.f, false);
  return __builtin_amdgcn_fdot2(b, q23, d, false);
}

// ---------------------------------------------------------------------------
// init: tgt[b,q,d] = qe[q, 256+d]; qpos[b,q,d] = qe[q, d]
__global__ __launch_bounds__(256) void init_kernel(
    const float* __restrict__ qe, float* __restrict__ tgt, float* __restrict__ qpos)
{
  int idx = blockIdx.x * 256 + threadIdx.x;   // < B*NQ*D == 276480
  int d = idx % DD;
  int q = (idx / DD) % NQQ;
  qpos[idx] = qe[q * 512 + d];
  tgt[idx]  = qe[q * 512 + 256 + d];
}

// ---------------------------------------------------------------------------
// One-time: transpose+convert src/pos to fp16 [b][p][d] layouts.
__global__ __launch_bounds__(256) void conv_kv_inputs(
    const float* __restrict__ src, const float* __restrict__ pos,
    __half* __restrict__ s16, __half* __restrict__ kv16)
{
  __shared__ float ls[64][65];
  __shared__ float lk[64][65];
  int b  = blockIdx.z;
  int p0 = blockIdx.x * 64;
  int d0 = blockIdx.y * 64;
  int t = threadIdx.x;
  int pr = (t & 15) * 4;
  int dr = t >> 4;
#pragma unroll
  for (int dd = 0; dd < 64; dd += 16) {
    int d = d0 + dd + dr;
    float4 sv = *(const float4*)&src[((size_t)b * DD + d) * PP + p0 + pr];
    float4 pv = *(const float4*)&pos[((size_t)b * DD + d) * PP + p0 + pr];
    ls[pr + 0][dd + dr] = sv.x; ls[pr + 1][dd + dr] = sv.y;
    ls[pr + 2][dd + dr] = sv.z; ls[pr + 3][dd + dr] = sv.w;
    lk[pr + 0][dd + dr] = sv.x + pv.x; lk[pr + 1][dd + dr] = sv.y + pv.y;
    lk[pr + 2][dd + dr] = sv.z + pv.z; lk[pr + 3][dd + dr] = sv.w + pv.w;
  }
  __syncthreads();
  int wp = t >> 2;
  int wd = (t & 3) * 16;
  size_t base = ((size_t)b * PP + p0 + wp) * 256 + d0 + wd;
#pragma unroll
  for (int i = 0; i < 16; i += 2) {
    *(__half2*)&s16[base + i]  = __floats2half2_rn(ls[wp][wd + i], ls[wp][wd + i + 1]);
    *(__half2*)&kv16[base + i] = __floats2half2_rn(lk[wp][wd + i], lk[wp][wd + i + 1]);
  }
}

// One-time: fp32 -> fp16 weight conversion (grid-stride).
__global__ __launch_bounds__(256) void conv_w(
    const float* __restrict__ w, __half* __restrict__ w16, int n)
{
  for (int i = blockIdx.x * 256 + threadIdx.x; i < n; i += gridDim.x * 256)
    w16[i] = __float2half_rn(w[i]);
}

// ---------------------------------------------------------------------------
// Merged MFMA K&V projection: z>>1 selects (A,W,out) pair, z&1 = batch b.
__global__ __launch_bounds__(256) void gemm_kv2_mfma(
    const __half* __restrict__ Ak, const __half* __restrict__ Av,
    const __half* __restrict__ Wk, const __half* __restrict__ Wv,
    __half* __restrict__ Ko, __half* __restrict__ Vo)
{
  int z = blockIdx.z;
  int b = z & 1;
  const __half* A = (z >> 1) ? Av : Ak;
  const __half* W = (z >> 1) ? Wv : Wk;
  __half* out     = (z >> 1) ? Vo : Ko;
  int wid = threadIdx.x >> 6;
  int lane = threadIdx.x & 63;
  int p0 = blockIdx.x * 128 + (wid >> 1) * 64;
  int n0 = blockIdx.y * 128 + (wid & 1) * 64;
  const __half* Ab = A + (size_t)b * PP * 256;
  int row = lane & 15;
  int kg  = lane >> 4;
  f32x4 acc[4][4] = {};
  for (int k0 = 0; k0 < 256; k0 += 32) {
    half8 af[4], bf[4];
#pragma unroll
    for (int i = 0; i < 4; ++i)
      af[i] = *(const half8*)&Ab[((size_t)(p0 + 16 * i + row)) * 256 + k0 + kg * 8];
#pragma unroll
    for (int j = 0; j < 4; ++j)
      bf[j] = *(const half8*)&W[((size_t)(n0 + 16 * j + row)) * 256 + k0 + kg * 8];
#pragma unroll
    for (int i = 0; i < 4; ++i)
#pragma unroll
      for (int j = 0; j < 4; ++j)
        acc[i][j] = __builtin_amdgcn_mfma_f32_16x16x32_f16(af[i], bf[j], acc[i][j], 0, 0, 0);
  }
#pragma unroll
  for (int i = 0; i < 4; ++i)
#pragma unroll
    for (int j = 0; j < 4; ++j) {
      int nc = n0 + 16 * j + row;
#pragma unroll
      for (int r = 0; r < 4; ++r) {
        int pr = p0 + 16 * i + kg * 4 + r;
        out[((size_t)b * PP + pr) * 256 + nc] = __float2half_rn(acc[i][j][r]);
      }
    }
}

// ---------------------------------------------------------------------------
// MFMA row GEMM: C[r,n] = (A1[r,:](+A2[r,:])) @ W16[n,:] (+bias)(+res)(relu).
__global__ __launch_bounds__(256) void gemm_rows_mfma(
    const float* __restrict__ A1, const float* __restrict__ A2,
    const __half* __restrict__ W, const float* __restrict__ bias,
    const float* __restrict__ res, float* __restrict__ C,
    int M, int N, int K, int relu)
{
  __shared__ __half a_s[64][40];
  int bm = blockIdx.x * 64;
  int bn = blockIdx.y * 64;
  int wv = threadIdx.x >> 6;
  int lane = threadIdx.x & 63;
  int row = lane & 15;
  int kg  = lane >> 4;
  int nw  = bn + wv * 16;
  int t = threadIdx.x;
  int srow = t >> 2, skq = (t & 3) * 8;
  f32x4 acc[4] = {};

  for (int k0 = 0; k0 < K; k0 += 32) {
    {
      size_t off = (size_t)(bm + srow) * K + k0 + skq;
      float4 a0 = *(const float4*)&A1[off];
      float4 a1 = *(const float4*)&A1[off + 4];
      if (A2) {
        float4 b0 = *(const float4*)&A2[off];
        float4 b1 = *(const float4*)&A2[off + 4];
        a0.x += b0.x; a0.y += b0.y; a0.z += b0.z; a0.w += b0.w;
        a1.x += b1.x; a1.y += b1.y; a1.z += b1.z; a1.w += b1.w;
      }
      half8 h;
      h[0] = (_Float16)a0.x; h[1] = (_Float16)a0.y;
      h[2] = (_Float16)a0.z; h[3] = (_Float16)a0.w;
      h[4] = (_Float16)a1.x; h[5] = (_Float16)a1.y;
      h[6] = (_Float16)a1.z; h[7] = (_Float16)a1.w;
      *(half8*)&a_s[srow][skq] = h;
    }
    __syncthreads();
    half8 bf = *(const half8*)&W[(size_t)(nw + row) * K + k0 + kg * 8];
#pragma unroll
    for (int i = 0; i < 4; ++i) {
      half8 af = *(const half8*)&a_s[16 * i + row][kg * 8];
      acc[i] = __builtin_amdgcn_mfma_f32_16x16x32_f16(af, bf, acc[i], 0, 0, 0);
    }
    __syncthreads();
  }

  int col = nw + row;
  float bval = bias ? bias[col] : 0.f;
#pragma unroll
  for (int i = 0; i < 4; ++i) {
#pragma unroll
    for (int r = 0; r < 4; ++r) {
      int rr = bm + 16 * i + kg * 4 + r;
      if (rr >= M) continue;
      float v = acc[i][r] + bval;
      if (relu) v = fmaxf(v, 0.f);
      if (res)  v += res[(size_t)rr * N + col];
      C[(size_t)rr * N + col] = v;
    }
  }
}

// ---------------------------------------------------------------------------
// MFMA row GEMM with fp16 output (for SA q/k/v buffers): C16 = A1(+A2) @ W16 + bias.
__global__ __launch_bounds__(256) void gemm_rows_mfma_h(
    const float* __restrict__ A1, const float* __restrict__ A2,
    const __half* __restrict__ W, const float* __restrict__ bias,
    __half* __restrict__ C, int M, int N, int K)
{
  __shared__ __half a_s[64][40];
  int bm = blockIdx.x * 64;
  int bn = blockIdx.y * 64;
  int wv = threadIdx.x >> 6;
  int lane = threadIdx.x & 63;
  int row = lane & 15;
  int kg  = lane >> 4;
  int nw  = bn + wv * 16;
  int t = threadIdx.x;
  int srow = t >> 2, skq = (t & 3) * 8;
  f32x4 acc[4] = {};

  for (int k0 = 0; k0 < K; k0 += 32) {
    {
      size_t off = (size_t)(bm + srow) * K + k0 + skq;
      float4 a0 = *(const float4*)&A1[off];
      float4 a1 = *(const float4*)&A1[off + 4];
      if (A2) {
        float4 b0 = *(const float4*)&A2[off];
        float4 b1 = *(const float4*)&A2[off + 4];
        a0.x += b0.x; a0.y += b0.y; a0.z += b0.z; a0.w += b0.w;
        a1.x += b1.x; a1.y += b1.y; a1.z += b1.z; a1.w += b1.w;
      }
      half8 h;
      h[0] = (_Float16)a0.x; h[1] = (_Float16)a0.y;
      h[2] = (_Float16)a0.z; h[3] = (_Float16)a0.w;
      h[4] = (_Float16)a1.x; h[5] = (_Float16)a1.y;
      h[6] = (_Float16)a1.z; h[7] = (_Float16)a1.w;
      *(half8*)&a_s[srow][skq] = h;
    }
    __syncthreads();
    half8 bf = *(const half8*)&W[(size_t)(nw + row) * K + k0 + kg * 8];
#pragma unroll
    for (int i = 0; i < 4; ++i) {
      half8 af = *(const half8*)&a_s[16 * i + row][kg * 8];
      acc[i] = __builtin_amdgcn_mfma_f32_16x16x32_f16(af, bf, acc[i], 0, 0, 0);
    }
    __syncthreads();
  }

  int col = nw + row;
  float bval = bias ? bias[col] : 0.f;
#pragma unroll
  for (int i = 0; i < 4; ++i) {
#pragma unroll
    for (int r = 0; r < 4; ++r) {
      int rr = bm + 16 * i + kg * 4 + r;
      if (rr >= M) continue;
      C[(size_t)rr * N + col] = __float2half_rn(acc[i][r] + bval);
    }
  }
}

// ---------------------------------------------------------------------------
// Self-attention, fp16 K/V, 2-keys-per-pass layout (R16-proven): lane owns
// 8 dims (8*(lane&31)) of key k0+2j+(lane>>5); 4 passes per 8-key batch.
// 16B K/V loads; 2 shfl/key dot reduce; defer-max. One block (8 waves)/(b,q).
__global__ __launch_bounds__(512) void sa_attn(
    const __half* __restrict__ qk16, const __half* __restrict__ v16,
    float* __restrict__ out)
{
  __shared__ float wmS[8][8];
  __shared__ float wsS[8][8];
  __shared__ float4 ooS[8][64];

  int bid = blockIdx.x;           // b*NQQ + q
  int b = bid / NQQ;
  int wv = threadIdx.x >> 6;
  int lane = threadIdx.x & 63;
  int li   = lane & 31;           // dim-slot: dims 8*li .. 8*li+7
  int half = lane >> 5;           // even/odd key of each pass
  const float scale = 0.17677669529663687f;  // 32^-0.5

  // q: 8 dims per lane (fp16 source), pre-scaled, as 4 h2v
  uint4 qraw = *(const uint4*)(qk16 + (size_t)bid * 512 + 8 * li);
  float4 qa = h4_to_f4(make_uint2(qraw.x, qraw.y));
  float4 qb = h4_to_f4(make_uint2(qraw.z, qraw.w));
  h2v qh0, qh1, qh2, qh3;
  qh0[0] = (_Float16)(qa.x * scale); qh0[1] = (_Float16)(qa.y * scale);
  qh1[0] = (_Float16)(qa.z * scale); qh1[1] = (_Float16)(qa.w * scale);
  qh2[0] = (_Float16)(qb.x * scale); qh2[1] = (_Float16)(qb.y * scale);
  qh3[0] = (_Float16)(qb.z * scale); qh3[1] = (_Float16)(qb.w * scale);

  const __half* Kb = qk16 + (size_t)b * NQQ * 512 + 256;  // k part of rows
  const __half* Vb = v16 + (size_t)b * NQQ * 256;

  float m = -INFINITY, sA = 0.f, sB = 0.f;
  float4 oA0 = make_float4(0.f, 0.f, 0.f, 0.f), oA1 = oA0;
  float4 oB0 = oA0, oB1 = oA0;

  for (int k0 = wv * 8; k0 < NQQ; k0 += 64) {
    // lane's key for pass j: k0 + 2j + half; dims 8*li (16B)
    const uint4* kp = (const uint4*)(Kb + (size_t)(k0 + half) * 512 + 8 * li);
    const uint4* vp = (const uint4*)(Vb + (size_t)(k0 + half) * 256 + 8 * li);
    uint4 kw0 = kp[0], kw1 = kp[128], kw2 = kp[256], kw3 = kp[384]; // 2-row step (512 halfs/row)
    uint4 vw0 = vp[0], vw1 = vp[64],  vw2 = vp[128], vw3 = vp[192]; // (256 halfs/row)

    float lg[4];
#pragma unroll
    for (int j = 0; j < 4; ++j) {
      uint4 kwj = (j == 0) ? kw0 : (j == 1) ? kw1 : (j == 2) ? kw2 : kw3;
      h2v a0 = *reinterpret_cast<h2v*>(&kwj.x);
      h2v a1 = *reinterpret_cast<h2v*>(&kwj.y);
      h2v a2 = *reinterpret_cast<h2v*>(&kwj.z);
      h2v a3 = *reinterpret_cast<h2v*>(&kwj.w);
      float d = __builtin_amdgcn_fdot2(a0, qh0, 0.f, false);
      d = __builtin_amdgcn_fdot2(a1, qh1, d, false);
      d = __builtin_amdgcn_fdot2(a2, qh2, d, false);
      d = __builtin_amdgcn_fdot2(a3, qh3, d, false);
      d += __shfl_xor(d, 1, 64);          // reduce over the 4 lanes of head
      d += __shfl_xor(d, 2, 64);
      lg[j] = (k0 + 2 * j + half < NQQ) ? d : -INFINITY;
    }

    float bm = fmaxf(fmaxf(lg[0], lg[1]), fmaxf(lg[2], lg[3]));
    bm = fmaxf(bm, __shfl_xor(bm, 32, 64));   // even|odd keys -> head max
    if (bm > m + 8.f) {                       // defer-max; first batch fires
      float f = __expf(m - bm);               // m=-inf -> 0
      sA *= f; sB *= f;
      oA0.x *= f; oA0.y *= f; oA0.z *= f; oA0.w *= f;
      oA1.x *= f; oA1.y *= f; oA1.z *= f; oA1.w *= f;
      oB0.x *= f; oB0.y *= f; oB0.z *= f; oB0.w *= f;
      oB1.x *= f; oB1.y *= f; oB1.z *= f; oB1.w *= f;
      m = bm;
    }
    {
      float pa = __expf(lg[0] - m);
      float pb = __expf(lg[1] - m);
      float4 alo = h4_to_f4(make_uint2(vw0.x, vw0.y));
      float4 ahi = h4_to_f4(make_uint2(vw0.z, vw0.w));
      float4 blo = h4_to_f4(make_uint2(vw1.x, vw1.y));
      float4 bhi = h4_to_f4(make_uint2(vw1.z, vw1.w));
      sA += pa; sB += pb;
      oA0.x = fmaf(pa, alo.x, oA0.x); oB0.x = fmaf(pb, blo.x, oB0.x);
      oA0.y = fmaf(pa, alo.y, oA0.y); oB0.y = fmaf(pb, blo.y, oB0.y);
      oA0.z = fmaf(pa, alo.z, oA0.z); oB0.z = fmaf(pb, blo.z, oB0.z);
      oA0.w = fmaf(pa, alo.w, oA0.w); oB0.w = fmaf(pb, blo.w, oB0.w);
      oA1.x = fmaf(pa, ahi.x, oA1.x); oB1.x = fmaf(pb, bhi.x, oB1.x);
      oA1.y = fmaf(pa, ahi.y, oA1.y); oB1.y = fmaf(pb, bhi.y, oB1.y);
      oA1.z = fmaf(pa, ahi.z, oA1.z); oB1.z = fmaf(pb, bhi.z, oB1.z);
      oA1.w = fmaf(pa, ahi.w, oA1.w); oB1.w = fmaf(pb, bhi.w, oB1.w);
    }
    {
      float pa = __expf(lg[2] - m);
      float pb = __expf(lg[3] - m);
      float4 alo = h4_to_f4(make_uint2(vw2.x, vw2.y));
      float4 ahi = h4_to_f4(make_uint2(vw2.z, vw2.w));
      float4 blo = h4_to_f4(make_uint2(vw3.x, vw3.y));
      float4 bhi = h4_to_f4(make_uint2(vw3.z, vw3.w));
      sA += pa; sB += pb;
      oA0.x = fmaf(pa, alo.x, oA0.x); oB0.x = fmaf(pb, blo.x, oB0.x);
      oA0.y = fmaf(pa, alo.y, oA0.y); oB0.y = fmaf(pb, blo.y, oB0.y);
      oA0.z = fmaf(pa, alo.z, oA0.z); oB0.z = fmaf(pb, blo.z, oB0.z);
      oA0.w = fmaf(pa, alo.w, oA0.w); oB0.w = fmaf(pb, blo.w, oB0.w);
      oA1.x = fmaf(pa, ahi.x, oA1.x); oB1.x = fmaf(pb, bhi.x, oB1.x);
      oA1.y = fmaf(pa, ahi.y, oA1.y); oB1.y = fmaf(pb, bhi.y, oB1.y);
      oA1.z = fmaf(pa, ahi.z, oA1.z); oB1.z = fmaf(pb, bhi.z, oB1.z);
      oA1.w = fmaf(pa, ahi.w, oA1.w); oB1.w = fmaf(pb, bhi.w, oB1.w);
    }
  }

  // ---- merge even|odd key halves across lane^32 ----
  float s = sA + sB;
  s += __shfl_xor(s, 32, 64);
  float4 oL = make_float4(oA0.x + oB0.x, oA0.y + oB0.y, oA0.z + oB0.z, oA0.w + oB0.w);
  float4 oH = make_float4(oA1.x + oB1.x, oA1.y + oB1.y, oA1.z + oB1.z, oA1.w + oB1.w);
  oL.x += __shfl_xor(oL.x, 32, 64); oL.y += __shfl_xor(oL.y, 32, 64);
  oL.z += __shfl_xor(oL.z, 32, 64); oL.w += __shfl_xor(oL.w, 32, 64);
  oH.x += __shfl_xor(oH.x, 32, 64); oH.y += __shfl_xor(oH.y, 32, 64);
  oH.z += __shfl_xor(oH.z, 32, 64); oH.w += __shfl_xor(oH.w, 32, 64);

  // ---- merge the 8 wave-states (per head); final normalize ----
  int hh = li >> 2;               // head of this lane's dims
  if (lane < 32 && (li & 3) == 0) wmS[wv][hh] = m;
  __syncthreads();
  float M = wmS[0][hh];
#pragma unroll
  for (int w = 1; w < 8; ++w) M = fmaxf(M, wmS[w][hh]);
  float f = __expf(m - M);
  if (lane < 32 && (li & 3) == 0) wsS[wv][hh] = s * f;
  if (lane < 32) {
    ooS[wv][2 * li]     = make_float4(oL.x * f, oL.y * f, oL.z * f, oL.w * f);
    ooS[wv][2 * li + 1] = make_float4(oH.x * f, oH.y * f, oH.z * f, oH.w * f);
  }
  __syncthreads();
  if (threadIdx.x < 64) {
    int l = threadIdx.x;
    int hg2 = l >> 3;
    float4 acc = make_float4(0.f, 0.f, 0.f, 0.f);
    float den = 0.f;
#pragma unroll
    for (int w = 0; w < 8; ++w) {
      float4 t = ooS[w][l];
      acc.x += t.x; acc.y += t.y; acc.z += t.z; acc.w += t.w;
      den += wsS[w][hg2];
    }
    float inv = 1.f / den;
    float4 res = make_float4(acc.x * inv, acc.y * inv, acc.z * inv, acc.w * inv);
    *(float4*)&out[(size_t)bid * 256 + l * 4] = res;
  }
}

// ---------------------------------------------------------------------------
// Cross-attention partial, 2-keys-per-pass layout (R16, best measured).
__global__ __launch_bounds__(256) void ca_attn_part(
    const float* __restrict__ qbuf, const __half* __restrict__ Kbuf,
    const __half* __restrict__ Vbuf, const int* __restrict__ lohi,
    float* __restrict__ pm, float* __restrict__ ps, float* __restrict__ po)
{
  __shared__ float wmS[4][8];
  __shared__ float wsS[4][8];
  __shared__ float4 ooS[4][64];

  // --- swizzle: 8640 blocks = 8 cls x 5 gsub x 27 iq x 8 part ---
  int idx  = blockIdx.x;
  int cls  = idx & 7;
  int rest = idx >> 3;          // 0..1079
  int gsub = rest / 216;        // 0..4
  int rem  = rest % 216;
  int iq   = rem >> 3;          // 0..26
  int part = rem & 7;           // NSPL == 8
  int g    = gsub * 8 + cls;    // organ-group 0..39
  int b    = g / 20;
  int q    = (g % 20) * QPO_ + iq;
  int bid  = b * NQQ + q;

  int wv = threadIdx.x >> 6;    // 0..3
  int lane = threadIdx.x & 63;
  int li   = lane & 31;         // dim-slot: dims 8*li .. 8*li+7
  int half = lane >> 5;         // even/odd key of each pass
  const float scale = 0.17677669529663687f;

  const int* lh = lohi + (size_t)bid * 6;
  int lo0 = lh[0], lo1 = lh[1], lo2 = lh[2];
  int nx = lh[3] - lo0, ny = lh[4] - lo1, nz = lh[5] - lo2;
  int nxy = nx * ny;
  float inv_ny = 1.0f / (float)ny;

  // q: 8 dims per lane, pre-scaled, as 4 h2v
  const float4* qp = (const float4*)(qbuf + (size_t)bid * 256 + 8 * li);
  float4 qa = qp[0], qb = qp[1];
  h2v qh0, qh1, qh2, qh3;
  qh0[0] = (_Float16)(qa.x * scale); qh0[1] = (_Float16)(qa.y * scale);
  qh1[0] = (_Float16)(qa.z * scale); qh1[1] = (_Float16)(qa.w * scale);
  qh2[0] = (_Float16)(qb.x * scale); qh2[1] = (_Float16)(qb.y * scale);
  qh3[0] = (_Float16)(qb.z * scale); qh3[1] = (_Float16)(qb.w * scale);

  const __half* Kb = Kbuf + (size_t)b * PP * 256;
  const __half* Vb = Vbuf + (size_t)b * PP * 256;

  float m = -INFINITY, sA = 0.f, sB = 0.f;
  float4 oA0 = make_float4(0.f, 0.f, 0.f, 0.f), oA1 = oA0;
  float4 oB0 = oA0, oB1 = oA0;

  for (int r = part + 8 * wv; r < nxy; r += 32) {
    int x = (int)((float)r * inv_ny);
    int y = r - x * ny;
    if (y < 0)        { x--; y += ny; }
    else if (y >= ny) { x++; y -= ny; }
    int base = (lo0 + x) * (PS1 * PS2) + (lo1 + y) * PS2 + lo2;

    for (int z0 = 0; z0 < nz; z0 += 8) {
      // lane's key for pass j: base + z0 + 2j + half; dims 8*li (16B)
      const uint4* kp = (const uint4*)(Kb + ((size_t)(base + z0 + half)) * 256 + 8 * li);
      const uint4* vp = (const uint4*)(Vb + ((size_t)(base + z0 + half)) * 256 + 8 * li);
      uint4 kw0 = kp[0],  kw1 = kp[64], kw2 = kp[128], kw3 = kp[192]; // 2-row step
      uint4 vw0 = vp[0],  vw1 = vp[64], vw2 = vp[128], vw3 = vp[192];

      float lg[4];
#pragma unroll
      for (int j = 0; j < 4; ++j) {
        uint4 kwj = (j == 0) ? kw0 : (j == 1) ? kw1 : (j == 2) ? kw2 : kw3;
        h2v a0 = *reinterpret_cast<h2v*>(&kwj.x);
        h2v a1 = *reinterpret_cast<h2v*>(&kwj.y);
        h2v a2 = *reinterpret_cast<h2v*>(&kwj.z);
        h2v a3 = *reinterpret_cast<h2v*>(&kwj.w);
        float d = __builtin_amdgcn_fdot2(a0, qh0, 0.f, false);
        d = __builtin_amdgcn_fdot2(a1, qh1, d, false);
        d = __builtin_amdgcn_fdot2(a2, qh2, d, false);
        d = __builtin_amdgcn_fdot2(a3, qh3, d, false);
        d += __shfl_xor(d, 1, 64);          // reduce over the 4 lanes of head
        d += __shfl_xor(d, 2, 64);
        lg[j] = (z0 + 2 * j + half < nz) ? d : -INFINITY;
      }

      float bm = fmaxf(fmaxf(lg[0], lg[1]), fmaxf(lg[2], lg[3]));
      bm = fmaxf(bm, __shfl_xor(bm, 32, 64));   // even|odd keys -> head max
      if (bm > m + 8.f) {                       // defer-max; first batch fires
        float f = __expf(m - bm);               // m=-inf -> 0
        sA *= f; sB *= f;
        oA0.x *= f; oA0.y *= f; oA0.z *= f; oA0.w *= f;
        oA1.x *= f; oA1.y *= f; oA1.z *= f; oA1.w *= f;
        oB0.x *= f; oB0.y *= f; oB0.z *= f; oB0.w *= f;
        oB1.x *= f; oB1.y *= f; oB1.z *= f; oB1.w *= f;
        m = bm;
      }
      {
        float pa = __expf(lg[0] - m);
        float pb = __expf(lg[1] - m);
        float4 alo = h4_to_f4(make_uint2(vw0.x, vw0.y));
        float4 ahi = h4_to_f4(make_uint2(vw0.z, vw0.w));
        float4 blo = h4_to_f4(make_uint2(vw1.x, vw1.y));
        float4 bhi = h4_to_f4(make_uint2(vw1.z, vw1.w));
        sA += pa; sB += pb;
        oA0.x = fmaf(pa, alo.x, oA0.x); oB0.x = fmaf(pb, blo.x, oB0.x);
        oA0.y = fmaf(pa, alo.y, oA0.y); oB0.y = fmaf(pb, blo.y, oB0.y);
        oA0.z = fmaf(pa, alo.z, oA0.z); oB0.z = fmaf(pb, blo.z, oB0.z);
        oA0.w = fmaf(pa, alo.w, oA0.w); oB0.w = fmaf(pb, blo.w, oB0.w);
        oA1.x = fmaf(pa, ahi.x, oA1.x); oB1.x = fmaf(pb, bhi.x, oB1.x);
        oA1.y = fmaf(pa, ahi.y, oA1.y); oB1.y = fmaf(pb, bhi.y, oB1.y);
        oA1.z = fmaf(pa, ahi.z, oA1.z); oB1.z = fmaf(pb, bhi.z, oB1.z);
        oA1.w = fmaf(pa, ahi.w, oA1.w); oB1.w = fmaf(pb, bhi.w, oB1.w);
      }
      {
        float pa = __expf(lg[2] - m);
        float pb = __expf(lg[3] - m);
        float4 alo = h4_to_f4(make_uint2(vw2.x, vw2.y));
        float4 ahi = h4_to_f4(make_uint2(vw2.z, vw2.w));
        float4 blo = h4_to_f4(make_uint2(vw3.x, vw3.y));
        float4 bhi = h4_to_f4(make_uint2(vw3.z, vw3.w));
        sA += pa; sB += pb;
        oA0.x = fmaf(pa, alo.x, oA0.x); oB0.x = fmaf(pb, blo.x, oB0.x);
        oA0.y = fmaf(pa, alo.y, oA0.y); oB0.y = fmaf(pb, blo.y, oB0.y);
        oA0.z = fmaf(pa, alo.z, oA0.z); oB0.z = fmaf(pb, blo.z, oB0.z);
        oA0.w = fmaf(pa, alo.w, oA0.w); oB0.w = fmaf(pb, blo.w, oB0.w);
        oA1.x = fmaf(pa, ahi.x, oA1.x); oB1.x = fmaf(pb, bhi.x, oB1.x);
        oA1.y = fmaf(pa, ahi.y, oA1.y); oB1.y = fmaf(pb, bhi.y, oB1.y);
        oA1.z = fmaf(pa, ahi.z, oA1.z); oB1.z = fmaf(pb, bhi.z, oB1.z);
        oA1.w = fmaf(pa, ahi.w, oA1.w); oB1.w = fmaf(pb, bhi.w, oB1.w);
      }
    }
  }

  // ---- merge even|odd key halves across lane^32 ----
  float s = sA + sB;
  s += __shfl_xor(s, 32, 64);
  float4 oL = make_float4(oA0.x + oB0.x, oA0.y + oB0.y, oA0.z + oB0.z, oA0.w + oB0.w);
  float4 oH = make_float4(oA1.x + oB1.x, oA1.y + oB1.y, oA1.z + oB1.z, oA1.w + oB1.w);
  oL.x += __shfl_xor(oL.x, 32, 64); oL.y += __shfl_xor(oL.y, 32, 64);
  oL.z += __shfl_xor(oL.z, 32, 64); oL.w += __shfl_xor(oL.w, 32, 64);
  oH.x += __shfl_xor(oH.x, 32, 64); oH.y += __shfl_xor(oH.y, 32, 64);
  oH.z += __shfl_xor(oH.z, 32, 64); oH.w += __shfl_xor(oH.w, 32, 64);

  // ---- merge this block's 4 wave-states; write partial (M, S, O) ----
  int hh = li >> 2;               // head of this lane's dims
  if (lane < 32 && (li & 3) == 0) wmS[wv][hh] = m;
  __syncthreads();
  float M = wmS[0][hh];
#pragma unroll
  for (int w = 1; w < 4; ++w) M = fmaxf(M, wmS[w][hh]);
  float f = (M == -INFINITY) ? 0.f : __expf(m - M);  // empty part -> zeros
  if (lane < 32 && (li & 3) == 0) wsS[wv][hh] = s * f;
  if (lane < 32) {
    ooS[wv][2 * li]     = make_float4(oL.x * f, oL.y * f, oL.z * f, oL.w * f);
    ooS[wv][2 * li + 1] = make_float4(oH.x * f, oH.y * f, oH.z * f, oH.w * f);
  }
  __syncthreads();
  if (threadIdx.x < 64) {
    int l = threadIdx.x;
    int hg2 = l >> 3;
    float4 acc = make_float4(0.f, 0.f, 0.f, 0.f);
    float den = 0.f;
#pragma unroll
    for (int w = 0; w < 4; ++w) {
      float4 t = ooS[w][l];
      acc.x += t.x; acc.y += t.y; acc.z += t.z; acc.w += t.w;
      den += wsS[w][hg2];
    }
    float M2 = wmS[0][hg2];
#pragma unroll
    for (int w = 1; w < 4; ++w) M2 = fmaxf(M2, wmS[w][hg2]);
    size_t pb = (size_t)bid * NSPL + part;
    if ((l & 7) == 0) { pm[pb * 8 + hg2] = M2; ps[pb * 8 + hg2] = den; }
    *(float4*)&po[pb * 256 + l * 4] = acc;
  }
}

// ---------------------------------------------------------------------------
// Merge NSPL cross-attn partials per query. One wave per (b,q).
__global__ __launch_bounds__(256) void ca_merge(
    const float* __restrict__ pm, const float* __restrict__ ps,
    const float* __restrict__ po, float* __restrict__ out)
{
  int wv = threadIdx.x >> 6;
  int lane = threadIdx.x & 63;
  int bid = blockIdx.x * 4 + wv;
  int hg = lane >> 3;
  size_t pb = (size_t)bid * NSPL;

  float mp[NSPL], sp[NSPL];
#pragma unroll
  for (int p = 0; p < NSPL; ++p) {
    mp[p] = pm[(pb + p) * 8 + hg];
    sp[p] = ps[(pb + p) * 8 + hg];
  }
  float M = mp[0];
#pragma unroll
  for (int p = 1; p < NSPL; ++p) M = fmaxf(M, mp[p]);
  float den = 0.f;
  float4 acc = make_float4(0.f, 0.f, 0.f, 0.f);
#pragma unroll
  for (int p = 0; p < NSPL; ++p) {
    float f = __expf(mp[p] - M);     // empty part m=-inf -> 0
    den = fmaf(f, sp[p], den);
    float4 t = *(const float4*)&po[(pb + p) * 256 + lane * 4];
    acc.x = fmaf(f, t.x, acc.x);
    acc.y = fmaf(f, t.y, acc.y);
    acc.z = fmaf(f, t.z, acc.z);
    acc.w = fmaf(f, t.w, acc.w);
  }
  float inv = 1.f / den;
  float4 res = make_float4(acc.x * inv, acc.y * inv, acc.z * inv, acc.w * inv);
  *(float4*)&out[(size_t)bid * 256 + lane * 4] = res;
}

// ---------------------------------------------------------------------------
// LayerNorm over D=256: one wave per row. x already contains residual sum.
__global__ __launch_bounds__(256) void ln_kernel(
    const float* __restrict__ x, const float* __restrict__ g,
    const float* __restrict__ bta, float* __restrict__ out)
{
  int wv = threadIdx.x >> 6;
  int lane = threadIdx.x & 63;
  int row = blockIdx.x * 4 + wv;
  const float* xr = x + (size_t)row * 256;
  float v[4];
#pragma unroll
  for (int j = 0; j < 4; ++j) v[j] = xr[lane + 64 * j];
  float s = v[0] + v[1] + v[2] + v[3];
  s = wred_sum(s);
  float mean = s * (1.f / 256.f);
  float vs = 0.f;
#pragma unroll
  for (int j = 0; j < 4; ++j) { float d = v[j] - mean; vs = fmaf(d, d, vs); }
  vs = wred_sum(vs);
  float inv = rsqrtf(vs * (1.f / 256.f) + 1e-5f);
  float* orow = out + (size_t)row * 256;
#pragma unroll
  for (int j = 0; j < 4; ++j) {
    int c = lane + 64 * j;
    orow[c] = (v[j] - mean) * inv * g[c] + bta[c];
  }
}

// ---------------------------------------------------------------------------
// Layer-0 mask boxes from attn_area.
__global__ __launch_bounds__(256) void mask0_kernel(
    const float* __restrict__ area, int* __restrict__ lohi,
    float px, float py, float pz)
{
  int row = blockIdx.x * 256 + threadIdx.x;
  if (row >= MR) return;
  int q = row % NQQ;
  int org = q / QPO_;
  const float* a = area + org * 6;
  int* o = lohi + (size_t)row * 6;
  o[0] = (int)fminf(fmaxf(floorf(a[0] * 20.f - px), 0.f), 20.f);
  o[1] = (int)fminf(fmaxf(floorf(a[1] * 20.f - py), 0.f), 20.f);
  o[2] = (int)fminf(fmaxf(floorf(a[2] * 32.f - pz), 0.f), 32.f);
  o[3] = (int)fminf(fmaxf(floorf(a[3] * 20.f + px), 0.f), 20.f);
  o[4] = (int)fminf(fmaxf(floorf(a[4] * 20.f + py), 0.f), 20.f);
  o[5] = (int)fminf(fmaxf(floorf(a[5] * 32.f + pz), 0.f), 32.f);
}

// ---------------------------------------------------------------------------
// Layers >=1: prop = h2 @ w3.T + b3 -> tanh*0.1 + anchors -> clip -> box ints.
__global__ __launch_bounds__(256) void mask_reg_kernel(
    const float* __restrict__ h2, const float* __restrict__ w3,
    const float* __restrict__ b3, const float* __restrict__ anchors,
    int* __restrict__ lohi, float px, float py, float pz)
{
  int wv = threadIdx.x >> 6;
  int lane = threadIdx.x & 63;
  int row = blockIdx.x * 4 + wv;
  int q = row % NQQ;
  const float* hr = h2 + (size_t)row * 256;
  float part[6] = {};
#pragma unroll
  for (int j = 0; j < 4; ++j) {
    float hv = hr[lane + 64 * j];
#pragma unroll
    for (int o = 0; o < 6; ++o)
      part[o] = fmaf(hv, w3[o * 256 + lane + 64 * j], part[o]);
  }
#pragma unroll
  for (int o = 0; o < 6; ++o) part[o] = wred_sum(part[o]);
  if (lane == 0) {
    float prop[6];
#pragma unroll
    for (int o = 0; o < 6; ++o) {
      float v = tanhf(part[o] + b3[o]) * 0.1f + anchors[q * 6 + o];
      prop[o] = fminf(fmaxf(v, 0.f), 1.f);
    }
    float vl0 = prop[0] - 0.5f * prop[3], vh0 = prop[0] + 0.5f * prop[3];
    float vl1 = prop[1] - 0.5f * prop[4], vh1 = prop[1] + 0.5f * prop[4];
    float vl2 = prop[2] - 0.5f * prop[5], vh2 = prop[2] + 0.5f * prop[5];
    int* o = lohi + (size_t)row * 6;
    o[0] = (int)fminf(fmaxf(floorf(vl0 * 20.f - px), 0.f), 20.f);
    o[1] = (int)fminf(fmaxf(floorf(vl1 * 20.f - py), 0.f), 20.f);
    o[2] = (int)fminf(fmaxf(floorf(vl2 * 32.f - pz), 0.f), 32.f);
    o[3] = (int)fminf(fmaxf(floorf(vh0 * 20.f + px), 0.f), 20.f);
    o[4] = (int)fminf(fmaxf(floorf(vh1 * 20.f + py), 0.f), 20.f);
    o[5] = (int)fminf(fmaxf(floorf(vh2 * 32.f + pz), 0.f), 32.f);
  }
}

// ---------------------------------------------------------------------------
extern "C" void kernel_launch(void* const* d_in, const int* in_sizes, int n_in,
                              void* d_out, int out_size, void* d_ws, size_t ws_size,
                              hipStream_t stream)
{
  const float* src       = (const float*)d_in[0];
  const float* pos       = (const float*)d_in[1];
  const float* qe        = (const float*)d_in[2];
  const float* sa_in_w   = (const float*)d_in[3];
  const float* sa_in_b   = (const float*)d_in[4];
  const float* sa_out_w  = (const float*)d_in[5];
  const float* sa_out_b  = (const float*)d_in[6];
  const float* ca_k_w    = (const float*)d_in[7];
  const float* ca_v_w    = (const float*)d_in[8];
  const float* ca_proj_w = (const float*)d_in[9];
  const float* ca_proj_b = (const float*)d_in[10];
  const float* ln1_g = (const float*)d_in[11];
  const float* ln1_b = (const float*)d_in[12];
  const float* ln2_g = (const float*)d_in[13];
  const float* ln2_b = (const float*)d_in[14];
  const float* ln3_g = (const float*)d_in[15];
  const float* ln3_b = (const float*)d_in[16];
  const float* ffn_w1 = (const float*)d_in[17];
  const float* ffn_b1 = (const float*)d_in[18];
  const float* ffn_w2 = (const float*)d_in[19];
  const float* ffn_b2 = (const float*)d_in[20];
  const float* reg_w1 = (const float*)d_in[21];
  const float* reg_b1 = (const float*)d_in[22];
  const float* reg_w2 = (const float*)d_in[23];
  const float* reg_b2 = (const float*)d_in[24];
  const float* reg_w3 = (const float*)d_in[25];
  const float* reg_b3 = (const float*)d_in[26];
  const float* anchors   = (const float*)d_in[27];
  const float* attn_area = (const float*)d_in[28];
  float* outp = (float*)d_out;

  float* ws = (float*)d_ws;
  size_t off = 0;
  auto alloc = [&](size_t n) { float* p = ws + off; off += n; return p; };
  __half* Kb = (__half*)alloc((size_t)BB * PP * 128);   // fp16 [b][p][256], 13.1 MB
  __half* Vb = (__half*)alloc((size_t)BB * PP * 128);   // fp16, 13.1 MB
  alloc(4096);                                          // over-read pad
  __half* s16  = (__half*)alloc((size_t)BB * PP * 128); // fp16(src) [b][p][d]
  __half* kv16 = (__half*)alloc((size_t)BB * PP * 128); // fp16(src+pos) [b][p][d]
  __half* kw16 = (__half*)alloc((size_t)LL * DD * DD / 2);
  __half* vw16 = (__half*)alloc((size_t)LL * DD * DD / 2);
  __half* saw16 = (__half*)alloc((size_t)LL * 768 * DD / 2);   // sa_in_w
  __half* sow16 = (__half*)alloc((size_t)LL * DD * DD / 2);    // sa_out_w
  __half* pw16  = (__half*)alloc((size_t)LL * DD * DD / 2);    // ca_proj_w
  __half* f1w16 = (__half*)alloc((size_t)LL * FFD * DD / 2);   // ffn_w1
  __half* f2w16 = (__half*)alloc((size_t)LL * DD * FFD / 2);   // ffn_w2
  __half* r1w16 = (__half*)alloc((size_t)DD * DD / 2);         // reg_w1
  __half* r2w16 = (__half*)alloc((size_t)DD * DD / 2);         // reg_w2
  __half* saqk16 = (__half*)alloc((size_t)MR * 512 / 2);       // SA q|k fp16
  __half* sav16  = (__half*)alloc((size_t)MR * 256 / 2);       // SA v fp16
  alloc(2048);                                          // SA over-read pad
  float* tgt  = alloc((size_t)MR * DD);
  float* qpos = alloc((size_t)MR * DD);
  float* tmp  = alloc((size_t)MR * DD);
  float* sao  = alloc((size_t)MR * DD);
  float* caq  = alloc((size_t)MR * DD);
  float* cao  = alloc((size_t)MR * DD);
  float* mh1  = alloc((size_t)MR * DD);
  float* mh2  = alloc((size_t)MR * DD);
  float* ffh  = alloc((size_t)MR * FFD);
  float* pmb  = alloc((size_t)MR * NSPL * 8);
  float* psb  = alloc((size_t)MR * NSPL * 8);
  float* pob  = alloc((size_t)MR * NSPL * 256);
  int*   lohi = (int*)alloc((size_t)MR * 6);
  alloc(4096);                                          // A over-read pad
  (void)in_sizes; (void)n_in; (void)out_size; (void)ws_size;

  const float FOCUS_H[6] = {0.1f, 0.075f, 0.05f, 0.05f, 0.025f, 0.025f};

  init_kernel<<<1080, 256, 0, stream>>>(qe, tgt, qpos);
  conv_kv_inputs<<<dim3(200, 4, 2), 256, 0, stream>>>(src, pos, s16, kv16);
  conv_w<<<768, 256, 0, stream>>>(ca_k_w, kw16, LL * DD * DD);
  conv_w<<<768, 256, 0, stream>>>(ca_v_w, vw16, LL * DD * DD);
  conv_w<<<768, 256, 0, stream>>>(sa_in_w, saw16, LL * 768 * DD);
  conv_w<<<768, 256, 0, stream>>>(sa_out_w, sow16, LL * DD * DD);
  conv_w<<<768, 256, 0, stream>>>(ca_proj_w, pw16, LL * DD * DD);
  conv_w<<<768, 256, 0, stream>>>(ffn_w1, f1w16, LL * FFD * DD);
  conv_w<<<768, 256, 0, stream>>>(ffn_w2, f2w16, LL * DD * FFD);
  conv_w<<<256, 256, 0, stream>>>(reg_w1, r1w16, DD * DD);
  conv_w<<<256, 256, 0, stream>>>(reg_w2, r2w16, DD * DD);

  for (int i = 0; i < LL; ++i) {
    const __half* wi16 = saw16 + (size_t)i * 768 * DD;
    const float*  bi   = sa_in_b + (size_t)i * 768;
    // SA: q,k from (tgt+qpos), v from tgt -> fp16 buffers
    gemm_rows_mfma_h<<<dim3(17, 8), 256, 0, stream>>>(tgt, qpos, wi16, bi, saqk16, MR, 512, DD);
    gemm_rows_mfma_h<<<dim3(17, 4), 256, 0, stream>>>(tgt, nullptr, wi16 + 512 * DD, bi + 512, sav16, MR, DD, DD);
    sa_attn<<<MR, 512, 0, stream>>>(saqk16, sav16, sao);
    gemm_rows_mfma<<<dim3(17, 4), 256, 0, stream>>>(sao, nullptr, sow16 + (size_t)i * DD * DD,
                                                    sa_out_b + (size_t)i * DD, tgt, tmp, MR, DD, DD, 0);
    ln_kernel<<<270, 256, 0, stream>>>(tmp, ln2_g + i * DD, ln2_b + i * DD, tgt);

    // mask boxes
    if (i == 0) {
      mask0_kernel<<<5, 256, 0, stream>>>(attn_area, lohi,
          FOCUS_H[0] * PS0, FOCUS_H[0] * PS1, FOCUS_H[0] * PS2);
    } else {
      gemm_rows_mfma<<<dim3(17, 4), 256, 0, stream>>>(tgt, nullptr, r1w16, reg_b1, nullptr, mh1, MR, DD, DD, 1);
      gemm_rows_mfma<<<dim3(17, 4), 256, 0, stream>>>(mh1, nullptr, r2w16, reg_b2, nullptr, mh2, MR, DD, DD, 1);
      mask_reg_kernel<<<270, 256, 0, stream>>>(mh2, reg_w3, reg_b3, anchors, lohi,
          FOCUS_H[i] * PS0, FOCUS_H[i] * PS1, FOCUS_H[i] * PS2);
    }

    // CA: q from (tgt+qpos)@ca_k_w; K from (src+pos)@ca_k_w; V from src@ca_v_w
    gemm_rows_mfma<<<dim3(17, 4), 256, 0, stream>>>(tgt, qpos, kw16 + (size_t)i * DD * DD,
                                                    nullptr, nullptr, caq, MR, DD, DD, 0);
    gemm_kv2_mfma<<<dim3(100, 2, 4), 256, 0, stream>>>(kv16, s16,
                                                       kw16 + (size_t)i * DD * DD,
                                                       vw16 + (size_t)i * DD * DD, Kb, Vb);
    ca_attn_part<<<MR * NSPL, 256, 0, stream>>>(caq, Kb, Vb, lohi, pmb, psb, pob);
    ca_merge<<<270, 256, 0, stream>>>(pmb, psb, pob, cao);
    gemm_rows_mfma<<<dim3(17, 4), 256, 0, stream>>>(cao, nullptr, pw16 + (size_t)i * DD * DD,
                                                    ca_proj_b + (size_t)i * DD, tgt, tmp, MR, DD, DD, 0);
    ln_kernel<<<270, 256, 0, stream>>>(tmp, ln1_g + i * DD, ln1_b + i * DD, tgt);

    // FFN
    gemm_rows_mfma<<<dim3(17, 16), 256, 0, stream>>>(tgt, nullptr, f1w16 + (size_t)i * FFD * DD,
                                                     ffn_b1 + (size_t)i * FFD, nullptr, ffh, MR, FFD, DD, 1);
    gemm_rows_mfma<<<dim3(17, 4), 256, 0, stream>>>(ffh, nullptr, f2w16 + (size_t)i * DD * FFD,
                                                    ffn_b2 + (size_t)i * DD, tgt, tmp, MR, DD, FFD, 0);
    float* lno = (i == LL - 1) ? outp : tgt;
    ln_kernel<<<270, 256, 0, stream>>>(tmp, ln3_g + i * DD, ln3_b + i * DD, lno);
  }
}

// Round 19
// 1394.729 us; speedup vs baseline: 1.4238x; 1.1164x over previous
//
#include <hip/hip_runtime.h>
#include <hip/hip_fp16.h>
#include <math.h>

#define BB 2
#define DD 256
#define HH 8
#define HDIM 32
#define FFD 1024
#define LL 6
#define NQQ 540
#define QPO_ 27
#define PS0 20
#define PS1 20
#define PS2 32
#define PP (PS0*PS1*PS2)   // 12800
#define MR (BB*NQQ)        // 1080
#define NSPL 8             // cross-attn row-partials per query (4-wave blocks)

typedef _Float16 half8 __attribute__((ext_vector_type(8)));
typedef _Float16 half4v __attribute__((ext_vector_type(4)));
typedef _Float16 h2v  __attribute__((ext_vector_type(2)));
typedef float f32x4 __attribute__((ext_vector_type(4)));

static __device__ __forceinline__ float wred_sum(float x) {
#pragma unroll
  for (int off = 32; off; off >>= 1) x += __shfl_xor(x, off, 64);
  return x;
}
static __device__ __forceinline__ float4 h4_to_f4(uint2 u) {
  __half2 h0 = *reinterpret_cast<__half2*>(&u.x);
  __half2 h1 = *reinterpret_cast<__half2*>(&u.y);
  float2 f0 = __half22float2(h0);
  float2 f1 = __half22float2(h1);
  return make_float4(f0.x, f0.y, f1.x, f1.y);
}

// ---------------------------------------------------------------------------
// init: tgt[b,q,d] = qe[q, 256+d]; qpos[b,q,d] = qe[q, d]
__global__ __launch_bounds__(256) void init_kernel(
    const float* __restrict__ qe, float* __restrict__ tgt, float* __restrict__ qpos)
{
  int idx = blockIdx.x * 256 + threadIdx.x;   // < B*NQ*D == 276480
  int d = idx % DD;
  int q = (idx / DD) % NQQ;
  qpos[idx] = qe[q * 512 + d];
  tgt[idx]  = qe[q * 512 + 256 + d];
}

// ---------------------------------------------------------------------------
// One-time: transpose+convert src/pos to fp16 [b][p][d] layouts.
__global__ __launch_bounds__(256) void conv_kv_inputs(
    const float* __restrict__ src, const float* __restrict__ pos,
    __half* __restrict__ s16, __half* __restrict__ kv16)
{
  __shared__ float ls[64][65];
  __shared__ float lk[64][65];
  int b  = blockIdx.z;
  int p0 = blockIdx.x * 64;
  int d0 = blockIdx.y * 64;
  int t = threadIdx.x;
  int pr = (t & 15) * 4;
  int dr = t >> 4;
#pragma unroll
  for (int dd = 0; dd < 64; dd += 16) {
    int d = d0 + dd + dr;
    float4 sv = *(const float4*)&src[((size_t)b * DD + d) * PP + p0 + pr];
    float4 pv = *(const float4*)&pos[((size_t)b * DD + d) * PP + p0 + pr];
    ls[pr + 0][dd + dr] = sv.x; ls[pr + 1][dd + dr] = sv.y;
    ls[pr + 2][dd + dr] = sv.z; ls[pr + 3][dd + dr] = sv.w;
    lk[pr + 0][dd + dr] = sv.x + pv.x; lk[pr + 1][dd + dr] = sv.y + pv.y;
    lk[pr + 2][dd + dr] = sv.z + pv.z; lk[pr + 3][dd + dr] = sv.w + pv.w;
  }
  __syncthreads();
  int wp = t >> 2;
  int wd = (t & 3) * 16;
  size_t base = ((size_t)b * PP + p0 + wp) * 256 + d0 + wd;
#pragma unroll
  for (int i = 0; i < 16; i += 2) {
    *(__half2*)&s16[base + i]  = __floats2half2_rn(ls[wp][wd + i], ls[wp][wd + i + 1]);
    *(__half2*)&kv16[base + i] = __floats2half2_rn(lk[wp][wd + i], lk[wp][wd + i + 1]);
  }
}

// One-time: fp32 -> fp16 weight conversion (grid-stride).
__global__ __launch_bounds__(256) void conv_w(
    const float* __restrict__ w, __half* __restrict__ w16, int n)
{
  for (int i = blockIdx.x * 256 + threadIdx.x; i < n; i += gridDim.x * 256)
    w16[i] = __float2half_rn(w[i]);
}

// ---------------------------------------------------------------------------
// Merged MFMA K&V projection: z>>1 selects (A,W,out) pair, z&1 = batch b.
__global__ __launch_bounds__(256) void gemm_kv2_mfma(
    const __half* __restrict__ Ak, const __half* __restrict__ Av,
    const __half* __restrict__ Wk, const __half* __restrict__ Wv,
    __half* __restrict__ Ko, __half* __restrict__ Vo)
{
  int z = blockIdx.z;
  int b = z & 1;
  const __half* A = (z >> 1) ? Av : Ak;
  const __half* W = (z >> 1) ? Wv : Wk;
  __half* out     = (z >> 1) ? Vo : Ko;
  int wid = threadIdx.x >> 6;
  int lane = threadIdx.x & 63;
  int p0 = blockIdx.x * 128 + (wid >> 1) * 64;
  int n0 = blockIdx.y * 128 + (wid & 1) * 64;
  const __half* Ab = A + (size_t)b * PP * 256;
  int row = lane & 15;
  int kg  = lane >> 4;
  f32x4 acc[4][4] = {};
  for (int k0 = 0; k0 < 256; k0 += 32) {
    half8 af[4], bf[4];
#pragma unroll
    for (int i = 0; i < 4; ++i)
      af[i] = *(const half8*)&Ab[((size_t)(p0 + 16 * i + row)) * 256 + k0 + kg * 8];
#pragma unroll
    for (int j = 0; j < 4; ++j)
      bf[j] = *(const half8*)&W[((size_t)(n0 + 16 * j + row)) * 256 + k0 + kg * 8];
#pragma unroll
    for (int i = 0; i < 4; ++i)
#pragma unroll
      for (int j = 0; j < 4; ++j)
        acc[i][j] = __builtin_amdgcn_mfma_f32_16x16x32_f16(af[i], bf[j], acc[i][j], 0, 0, 0);
  }
#pragma unroll
  for (int i = 0; i < 4; ++i)
#pragma unroll
    for (int j = 0; j < 4; ++j) {
      int nc = n0 + 16 * j + row;
#pragma unroll
      for (int r = 0; r < 4; ++r) {
        int pr = p0 + 16 * i + kg * 4 + r;
        out[((size_t)b * PP + pr) * 256 + nc] = __float2half_rn(acc[i][j][r]);
      }
    }
}

// ---------------------------------------------------------------------------
// MFMA row GEMM, BM=32 (136-block grids for skinny M=1080 shapes):
// C[r,n] = (A1[r,:](+A2[r,:])) @ W16[n,:] (+bias)(+res)(relu).
__global__ __launch_bounds__(256) void gemm_rows_mfma(
    const float* __restrict__ A1, const float* __restrict__ A2,
    const __half* __restrict__ W, const float* __restrict__ bias,
    const float* __restrict__ res, float* __restrict__ C,
    int M, int N, int K, int relu)
{
  __shared__ __half a_s[32][40];   // row stride 80B (16B-mult): aligned half8 ops
  int bm = blockIdx.x * 32;
  int bn = blockIdx.y * 64;
  int wv = threadIdx.x >> 6;
  int lane = threadIdx.x & 63;
  int row = lane & 15;
  int kg  = lane >> 4;
  int nw  = bn + wv * 16;
  int t = threadIdx.x;
  int srow = t >> 3, skq = (t & 7) * 4;
  f32x4 acc[2] = {};

  for (int k0 = 0; k0 < K; k0 += 32) {
    { // stage A tile (32 rows x 32 k) as fp16; over-read rows land in ws
      size_t off = (size_t)(bm + srow) * K + k0 + skq;
      float4 a0 = *(const float4*)&A1[off];
      if (A2) {
        float4 b0 = *(const float4*)&A2[off];
        a0.x += b0.x; a0.y += b0.y; a0.z += b0.z; a0.w += b0.w;
      }
      half4v h;
      h[0] = (_Float16)a0.x; h[1] = (_Float16)a0.y;
      h[2] = (_Float16)a0.z; h[3] = (_Float16)a0.w;
      *(half4v*)&a_s[srow][skq] = h;
    }
    __syncthreads();
    half8 bf = *(const half8*)&W[(size_t)(nw + row) * K + k0 + kg * 8];
#pragma unroll
    for (int i = 0; i < 2; ++i) {
      half8 af = *(const half8*)&a_s[16 * i + row][kg * 8];
      acc[i] = __builtin_amdgcn_mfma_f32_16x16x32_f16(af, bf, acc[i], 0, 0, 0);
    }
    __syncthreads();
  }

  int col = nw + row;
  float bval = bias ? bias[col] : 0.f;
#pragma unroll
  for (int i = 0; i < 2; ++i) {
#pragma unroll
    for (int r = 0; r < 4; ++r) {
      int rr = bm + 16 * i + kg * 4 + r;
      if (rr >= M) continue;
      float v = acc[i][r] + bval;
      if (relu) v = fmaxf(v, 0.f);
      if (res)  v += res[(size_t)rr * N + col];
      C[(size_t)rr * N + col] = v;
    }
  }
}

// ---------------------------------------------------------------------------
// MFMA row GEMM (BM=32) with fp16 output: C16 = A1(+A2) @ W16 + bias.
__global__ __launch_bounds__(256) void gemm_rows_mfma_h(
    const float* __restrict__ A1, const float* __restrict__ A2,
    const __half* __restrict__ W, const float* __restrict__ bias,
    __half* __restrict__ C, int M, int N, int K)
{
  __shared__ __half a_s[32][40];
  int bm = blockIdx.x * 32;
  int bn = blockIdx.y * 64;
  int wv = threadIdx.x >> 6;
  int lane = threadIdx.x & 63;
  int row = lane & 15;
  int kg  = lane >> 4;
  int nw  = bn + wv * 16;
  int t = threadIdx.x;
  int srow = t >> 3, skq = (t & 7) * 4;
  f32x4 acc[2] = {};

  for (int k0 = 0; k0 < K; k0 += 32) {
    {
      size_t off = (size_t)(bm + srow) * K + k0 + skq;
      float4 a0 = *(const float4*)&A1[off];
      if (A2) {
        float4 b0 = *(const float4*)&A2[off];
        a0.x += b0.x; a0.y += b0.y; a0.z += b0.z; a0.w += b0.w;
      }
      half4v h;
      h[0] = (_Float16)a0.x; h[1] = (_Float16)a0.y;
      h[2] = (_Float16)a0.z; h[3] = (_Float16)a0.w;
      *(half4v*)&a_s[srow][skq] = h;
    }
    __syncthreads();
    half8 bf = *(const half8*)&W[(size_t)(nw + row) * K + k0 + kg * 8];
#pragma unroll
    for (int i = 0; i < 2; ++i) {
      half8 af = *(const half8*)&a_s[16 * i + row][kg * 8];
      acc[i] = __builtin_amdgcn_mfma_f32_16x16x32_f16(af, bf, acc[i], 0, 0, 0);
    }
    __syncthreads();
  }

  int col = nw + row;
  float bval = bias ? bias[col] : 0.f;
#pragma unroll
  for (int i = 0; i < 2; ++i) {
#pragma unroll
    for (int r = 0; r < 4; ++r) {
      int rr = bm + 16 * i + kg * 4 + r;
      if (rr >= M) continue;
      C[(size_t)rr * N + col] = __float2half_rn(acc[i][r] + bval);
    }
  }
}

// ---------------------------------------------------------------------------
// Self-attention, fp16 K/V, 2-keys-per-pass layout (R16-proven).
__global__ __launch_bounds__(512) void sa_attn(
    const __half* __restrict__ qk16, const __half* __restrict__ v16,
    float* __restrict__ out)
{
  __shared__ float wmS[8][8];
  __shared__ float wsS[8][8];
  __shared__ float4 ooS[8][64];

  int bid = blockIdx.x;           // b*NQQ + q
  int b = bid / NQQ;
  int wv = threadIdx.x >> 6;
  int lane = threadIdx.x & 63;
  int li   = lane & 31;           // dim-slot: dims 8*li .. 8*li+7
  int half = lane >> 5;           // even/odd key of each pass
  const float scale = 0.17677669529663687f;  // 32^-0.5

  uint4 qraw = *(const uint4*)(qk16 + (size_t)bid * 512 + 8 * li);
  float4 qa = h4_to_f4(make_uint2(qraw.x, qraw.y));
  float4 qb = h4_to_f4(make_uint2(qraw.z, qraw.w));
  h2v qh0, qh1, qh2, qh3;
  qh0[0] = (_Float16)(qa.x * scale); qh0[1] = (_Float16)(qa.y * scale);
  qh1[0] = (_Float16)(qa.z * scale); qh1[1] = (_Float16)(qa.w * scale);
  qh2[0] = (_Float16)(qb.x * scale); qh2[1] = (_Float16)(qb.y * scale);
  qh3[0] = (_Float16)(qb.z * scale); qh3[1] = (_Float16)(qb.w * scale);

  const __half* Kb = qk16 + (size_t)b * NQQ * 512 + 256;  // k part of rows
  const __half* Vb = v16 + (size_t)b * NQQ * 256;

  float m = -INFINITY, sA = 0.f, sB = 0.f;
  float4 oA0 = make_float4(0.f, 0.f, 0.f, 0.f), oA1 = oA0;
  float4 oB0 = oA0, oB1 = oA0;

  for (int k0 = wv * 8; k0 < NQQ; k0 += 64) {
    const uint4* kp = (const uint4*)(Kb + (size_t)(k0 + half) * 512 + 8 * li);
    const uint4* vp = (const uint4*)(Vb + (size_t)(k0 + half) * 256 + 8 * li);
    uint4 kw0 = kp[0], kw1 = kp[128], kw2 = kp[256], kw3 = kp[384];
    uint4 vw0 = vp[0], vw1 = vp[64],  vw2 = vp[128], vw3 = vp[192];

    float lg[4];
#pragma unroll
    for (int j = 0; j < 4; ++j) {
      uint4 kwj = (j == 0) ? kw0 : (j == 1) ? kw1 : (j == 2) ? kw2 : kw3;
      h2v a0 = *reinterpret_cast<h2v*>(&kwj.x);
      h2v a1 = *reinterpret_cast<h2v*>(&kwj.y);
      h2v a2 = *reinterpret_cast<h2v*>(&kwj.z);
      h2v a3 = *reinterpret_cast<h2v*>(&kwj.w);
      float d = __builtin_amdgcn_fdot2(a0, qh0, 0.f, false);
      d = __builtin_amdgcn_fdot2(a1, qh1, d, false);
      d = __builtin_amdgcn_fdot2(a2, qh2, d, false);
      d = __builtin_amdgcn_fdot2(a3, qh3, d, false);
      d += __shfl_xor(d, 1, 64);
      d += __shfl_xor(d, 2, 64);
      lg[j] = (k0 + 2 * j + half < NQQ) ? d : -INFINITY;
    }

    float bm = fmaxf(fmaxf(lg[0], lg[1]), fmaxf(lg[2], lg[3]));
    bm = fmaxf(bm, __shfl_xor(bm, 32, 64));
    if (bm > m + 8.f) {
      float f = __expf(m - bm);
      sA *= f; sB *= f;
      oA0.x *= f; oA0.y *= f; oA0.z *= f; oA0.w *= f;
      oA1.x *= f; oA1.y *= f; oA1.z *= f; oA1.w *= f;
      oB0.x *= f; oB0.y *= f; oB0.z *= f; oB0.w *= f;
      oB1.x *= f; oB1.y *= f; oB1.z *= f; oB1.w *= f;
      m = bm;
    }
    {
      float pa = __expf(lg[0] - m);
      float pb = __expf(lg[1] - m);
      float4 alo = h4_to_f4(make_uint2(vw0.x, vw0.y));
      float4 ahi = h4_to_f4(make_uint2(vw0.z, vw0.w));
      float4 blo = h4_to_f4(make_uint2(vw1.x, vw1.y));
      float4 bhi = h4_to_f4(make_uint2(vw1.z, vw1.w));
      sA += pa; sB += pb;
      oA0.x = fmaf(pa, alo.x, oA0.x); oB0.x = fmaf(pb, blo.x, oB0.x);
      oA0.y = fmaf(pa, alo.y, oA0.y); oB0.y = fmaf(pb, blo.y, oB0.y);
      oA0.z = fmaf(pa, alo.z, oA0.z); oB0.z = fmaf(pb, blo.z, oB0.z);
      oA0.w = fmaf(pa, alo.w, oA0.w); oB0.w = fmaf(pb, blo.w, oB0.w);
      oA1.x = fmaf(pa, ahi.x, oA1.x); oB1.x = fmaf(pb, bhi.x, oB1.x);
      oA1.y = fmaf(pa, ahi.y, oA1.y); oB1.y = fmaf(pb, bhi.y, oB1.y);
      oA1.z = fmaf(pa, ahi.z, oA1.z); oB1.z = fmaf(pb, bhi.z, oB1.z);
      oA1.w = fmaf(pa, ahi.w, oA1.w); oB1.w = fmaf(pb, bhi.w, oB1.w);
    }
    {
      float pa = __expf(lg[2] - m);
      float pb = __expf(lg[3] - m);
      float4 alo = h4_to_f4(make_uint2(vw2.x, vw2.y));
      float4 ahi = h4_to_f4(make_uint2(vw2.z, vw2.w));
      float4 blo = h4_to_f4(make_uint2(vw3.x, vw3.y));
      float4 bhi = h4_to_f4(make_uint2(vw3.z, vw3.w));
      sA += pa; sB += pb;
      oA0.x = fmaf(pa, alo.x, oA0.x); oB0.x = fmaf(pb, blo.x, oB0.x);
      oA0.y = fmaf(pa, alo.y, oA0.y); oB0.y = fmaf(pb, blo.y, oB0.y);
      oA0.z = fmaf(pa, alo.z, oA0.z); oB0.z = fmaf(pb, blo.z, oB0.z);
      oA0.w = fmaf(pa, alo.w, oA0.w); oB0.w = fmaf(pb, blo.w, oB0.w);
      oA1.x = fmaf(pa, ahi.x, oA1.x); oB1.x = fmaf(pb, bhi.x, oB1.x);
      oA1.y = fmaf(pa, ahi.y, oA1.y); oB1.y = fmaf(pb, bhi.y, oB1.y);
      oA1.z = fmaf(pa, ahi.z, oA1.z); oB1.z = fmaf(pb, bhi.z, oB1.z);
      oA1.w = fmaf(pa, ahi.w, oA1.w); oB1.w = fmaf(pb, bhi.w, oB1.w);
    }
  }

  float s = sA + sB;
  s += __shfl_xor(s, 32, 64);
  float4 oL = make_float4(oA0.x + oB0.x, oA0.y + oB0.y, oA0.z + oB0.z, oA0.w + oB0.w);
  float4 oH = make_float4(oA1.x + oB1.x, oA1.y + oB1.y, oA1.z + oB1.z, oA1.w + oB1.w);
  oL.x += __shfl_xor(oL.x, 32, 64); oL.y += __shfl_xor(oL.y, 32, 64);
  oL.z += __shfl_xor(oL.z, 32, 64); oL.w += __shfl_xor(oL.w, 32, 64);
  oH.x += __shfl_xor(oH.x, 32, 64); oH.y += __shfl_xor(oH.y, 32, 64);
  oH.z += __shfl_xor(oH.z, 32, 64); oH.w += __shfl_xor(oH.w, 32, 64);

  int hh = li >> 2;
  if (lane < 32 && (li & 3) == 0) wmS[wv][hh] = m;
  __syncthreads();
  float M = wmS[0][hh];
#pragma unroll
  for (int w = 1; w < 8; ++w) M = fmaxf(M, wmS[w][hh]);
  float f = __expf(m - M);
  if (lane < 32 && (li & 3) == 0) wsS[wv][hh] = s * f;
  if (lane < 32) {
    ooS[wv][2 * li]     = make_float4(oL.x * f, oL.y * f, oL.z * f, oL.w * f);
    ooS[wv][2 * li + 1] = make_float4(oH.x * f, oH.y * f, oH.z * f, oH.w * f);
  }
  __syncthreads();
  if (threadIdx.x < 64) {
    int l = threadIdx.x;
    int hg2 = l >> 3;
    float4 acc = make_float4(0.f, 0.f, 0.f, 0.f);
    float den = 0.f;
#pragma unroll
    for (int w = 0; w < 8; ++w) {
      float4 t = ooS[w][l];
      acc.x += t.x; acc.y += t.y; acc.z += t.z; acc.w += t.w;
      den += wsS[w][hg2];
    }
    float inv = 1.f / den;
    float4 res = make_float4(acc.x * inv, acc.y * inv, acc.z * inv, acc.w * inv);
    *(float4*)&out[(size_t)bid * 256 + l * 4] = res;
  }
}

// ---------------------------------------------------------------------------
// Cross-attention partial, 2-keys-per-pass layout (R16, best measured).
__global__ __launch_bounds__(256) void ca_attn_part(
    const float* __restrict__ qbuf, const __half* __restrict__ Kbuf,
    const __half* __restrict__ Vbuf, const int* __restrict__ lohi,
    float* __restrict__ pm, float* __restrict__ ps, float* __restrict__ po)
{
  __shared__ float wmS[4][8];
  __shared__ float wsS[4][8];
  __shared__ float4 ooS[4][64];

  // --- swizzle: 8640 blocks = 8 cls x 5 gsub x 27 iq x 8 part ---
  int idx  = blockIdx.x;
  int cls  = idx & 7;
  int rest = idx >> 3;          // 0..1079
  int gsub = rest / 216;        // 0..4
  int rem  = rest % 216;
  int iq   = rem >> 3;          // 0..26
  int part = rem & 7;           // NSPL == 8
  int g    = gsub * 8 + cls;    // organ-group 0..39
  int b    = g / 20;
  int q    = (g % 20) * QPO_ + iq;
  int bid  = b * NQQ + q;

  int wv = threadIdx.x >> 6;    // 0..3
  int lane = threadIdx.x & 63;
  int li   = lane & 31;         // dim-slot: dims 8*li .. 8*li+7
  int half = lane >> 5;         // even/odd key of each pass
  const float scale = 0.17677669529663687f;

  const int* lh = lohi + (size_t)bid * 6;
  int lo0 = lh[0], lo1 = lh[1], lo2 = lh[2];
  int nx = lh[3] - lo0, ny = lh[4] - lo1, nz = lh[5] - lo2;
  int nxy = nx * ny;
  float inv_ny = 1.0f / (float)ny;

  const float4* qp = (const float4*)(qbuf + (size_t)bid * 256 + 8 * li);
  float4 qa = qp[0], qb = qp[1];
  h2v qh0, qh1, qh2, qh3;
  qh0[0] = (_Float16)(qa.x * scale); qh0[1] = (_Float16)(qa.y * scale);
  qh1[0] = (_Float16)(qa.z * scale); qh1[1] = (_Float16)(qa.w * scale);
  qh2[0] = (_Float16)(qb.x * scale); qh2[1] = (_Float16)(qb.y * scale);
  qh3[0] = (_Float16)(qb.z * scale); qh3[1] = (_Float16)(qb.w * scale);

  const __half* Kb = Kbuf + (size_t)b * PP * 256;
  const __half* Vb = Vbuf + (size_t)b * PP * 256;

  float m = -INFINITY, sA = 0.f, sB = 0.f;
  float4 oA0 = make_float4(0.f, 0.f, 0.f, 0.f), oA1 = oA0;
  float4 oB0 = oA0, oB1 = oA0;

  for (int r = part + 8 * wv; r < nxy; r += 32) {
    int x = (int)((float)r * inv_ny);
    int y = r - x * ny;
    if (y < 0)        { x--; y += ny; }
    else if (y >= ny) { x++; y -= ny; }
    int base = (lo0 + x) * (PS1 * PS2) + (lo1 + y) * PS2 + lo2;

    for (int z0 = 0; z0 < nz; z0 += 8) {
      const uint4* kp = (const uint4*)(Kb + ((size_t)(base + z0 + half)) * 256 + 8 * li);
      const uint4* vp = (const uint4*)(Vb + ((size_t)(base + z0 + half)) * 256 + 8 * li);
      uint4 kw0 = kp[0],  kw1 = kp[64], kw2 = kp[128], kw3 = kp[192];
      uint4 vw0 = vp[0],  vw1 = vp[64], vw2 = vp[128], vw3 = vp[192];

      float lg[4];
#pragma unroll
      for (int j = 0; j < 4; ++j) {
        uint4 kwj = (j == 0) ? kw0 : (j == 1) ? kw1 : (j == 2) ? kw2 : kw3;
        h2v a0 = *reinterpret_cast<h2v*>(&kwj.x);
        h2v a1 = *reinterpret_cast<h2v*>(&kwj.y);
        h2v a2 = *reinterpret_cast<h2v*>(&kwj.z);
        h2v a3 = *reinterpret_cast<h2v*>(&kwj.w);
        float d = __builtin_amdgcn_fdot2(a0, qh0, 0.f, false);
        d = __builtin_amdgcn_fdot2(a1, qh1, d, false);
        d = __builtin_amdgcn_fdot2(a2, qh2, d, false);
        d = __builtin_amdgcn_fdot2(a3, qh3, d, false);
        d += __shfl_xor(d, 1, 64);
        d += __shfl_xor(d, 2, 64);
        lg[j] = (z0 + 2 * j + half < nz) ? d : -INFINITY;
      }

      float bm = fmaxf(fmaxf(lg[0], lg[1]), fmaxf(lg[2], lg[3]));
      bm = fmaxf(bm, __shfl_xor(bm, 32, 64));
      if (bm > m + 8.f) {
        float f = __expf(m - bm);
        sA *= f; sB *= f;
        oA0.x *= f; oA0.y *= f; oA0.z *= f; oA0.w *= f;
        oA1.x *= f; oA1.y *= f; oA1.z *= f; oA1.w *= f;
        oB0.x *= f; oB0.y *= f; oB0.z *= f; oB0.w *= f;
        oB1.x *= f; oB1.y *= f; oB1.z *= f; oB1.w *= f;
        m = bm;
      }
      {
        float pa = __expf(lg[0] - m);
        float pb = __expf(lg[1] - m);
        float4 alo = h4_to_f4(make_uint2(vw0.x, vw0.y));
        float4 ahi = h4_to_f4(make_uint2(vw0.z, vw0.w));
        float4 blo = h4_to_f4(make_uint2(vw1.x, vw1.y));
        float4 bhi = h4_to_f4(make_uint2(vw1.z, vw1.w));
        sA += pa; sB += pb;
        oA0.x = fmaf(pa, alo.x, oA0.x); oB0.x = fmaf(pb, blo.x, oB0.x);
        oA0.y = fmaf(pa, alo.y, oA0.y); oB0.y = fmaf(pb, blo.y, oB0.y);
        oA0.z = fmaf(pa, alo.z, oA0.z); oB0.z = fmaf(pb, blo.z, oB0.z);
        oA0.w = fmaf(pa, alo.w, oA0.w); oB0.w = fmaf(pb, blo.w, oB0.w);
        oA1.x = fmaf(pa, ahi.x, oA1.x); oB1.x = fmaf(pb, bhi.x, oB1.x);
        oA1.y = fmaf(pa, ahi.y, oA1.y); oB1.y = fmaf(pb, bhi.y, oB1.y);
        oA1.z = fmaf(pa, ahi.z, oA1.z); oB1.z = fmaf(pb, bhi.z, oB1.z);
        oA1.w = fmaf(pa, ahi.w, oA1.w); oB1.w = fmaf(pb, bhi.w, oB1.w);
      }
      {
        float pa = __expf(lg[2] - m);
        float pb = __expf(lg[3] - m);
        float4 alo = h4_to_f4(make_uint2(vw2.x, vw2.y));
        float4 ahi = h4_to_f4(make_uint2(vw2.z, vw2.w));
        float4 blo = h4_to_f4(make_uint2(vw3.x, vw3.y));
        float4 bhi = h4_to_f4(make_uint2(vw3.z, vw3.w));
        sA += pa; sB += pb;
        oA0.x = fmaf(pa, alo.x, oA0.x); oB0.x = fmaf(pb, blo.x, oB0.x);
        oA0.y = fmaf(pa, alo.y, oA0.y); oB0.y = fmaf(pb, blo.y, oB0.y);
        oA0.z = fmaf(pa, alo.z, oA0.z); oB0.z = fmaf(pb, blo.z, oB0.z);
        oA0.w = fmaf(pa, alo.w, oA0.w); oB0.w = fmaf(pb, blo.w, oB0.w);
        oA1.x = fmaf(pa, ahi.x, oA1.x); oB1.x = fmaf(pb, bhi.x, oB1.x);
        oA1.y = fmaf(pa, ahi.y, oA1.y); oB1.y = fmaf(pb, bhi.y, oB1.y);
        oA1.z = fmaf(pa, ahi.z, oA1.z); oB1.z = fmaf(pb, bhi.z, oB1.z);
        oA1.w = fmaf(pa, ahi.w, oA1.w); oB1.w = fmaf(pb, bhi.w, oB1.w);
      }
    }
  }

  float s = sA + sB;
  s += __shfl_xor(s, 32, 64);
  float4 oL = make_float4(oA0.x + oB0.x, oA0.y + oB0.y, oA0.z + oB0.z, oA0.w + oB0.w);
  float4 oH = make_float4(oA1.x + oB1.x, oA1.y + oB1.y, oA1.z + oB1.z, oA1.w + oB1.w);
  oL.x += __shfl_xor(oL.x, 32, 64); oL.y += __shfl_xor(oL.y, 32, 64);
  oL.z += __shfl_xor(oL.z, 32, 64); oL.w += __shfl_xor(oL.w, 32, 64);
  oH.x += __shfl_xor(oH.x, 32, 64); oH.y += __shfl_xor(oH.y, 32, 64);
  oH.z += __shfl_xor(oH.z, 32, 64); oH.w += __shfl_xor(oH.w, 32, 64);

  int hh = li >> 2;
  if (lane < 32 && (li & 3) == 0) wmS[wv][hh] = m;
  __syncthreads();
  float M = wmS[0][hh];
#pragma unroll
  for (int w = 1; w < 4; ++w) M = fmaxf(M, wmS[w][hh]);
  float f = (M == -INFINITY) ? 0.f : __expf(m - M);
  if (lane < 32 && (li & 3) == 0) wsS[wv][hh] = s * f;
  if (lane < 32) {
    ooS[wv][2 * li]     = make_float4(oL.x * f, oL.y * f, oL.z * f, oL.w * f);
    ooS[wv][2 * li + 1] = make_float4(oH.x * f, oH.y * f, oH.z * f, oH.w * f);
  }
  __syncthreads();
  if (threadIdx.x < 64) {
    int l = threadIdx.x;
    int hg2 = l >> 3;
    float4 acc = make_float4(0.f, 0.f, 0.f, 0.f);
    float den = 0.f;
#pragma unroll
    for (int w = 0; w < 4; ++w) {
      float4 t = ooS[w][l];
      acc.x += t.x; acc.y += t.y; acc.z += t.z; acc.w += t.w;
      den += wsS[w][hg2];
    }
    float M2 = wmS[0][hg2];
#pragma unroll
    for (int w = 1; w < 4; ++w) M2 = fmaxf(M2, wmS[w][hg2]);
    size_t pb = (size_t)bid * NSPL + part;
    if ((l & 7) == 0) { pm[pb * 8 + hg2] = M2; ps[pb * 8 + hg2] = den; }
    *(float4*)&po[pb * 256 + l * 4] = acc;
  }
}

// ---------------------------------------------------------------------------
// Merge NSPL cross-attn partials per query. One wave per (b,q).
__global__ __launch_bounds__(256) void ca_merge(
    const float* __restrict__ pm, const float* __restrict__ ps,
    const float* __restrict__ po, float* __restrict__ out)
{
  int wv = threadIdx.x >> 6;
  int lane = threadIdx.x & 63;
  int bid = blockIdx.x * 4 + wv;
  int hg = lane >> 3;
  size_t pb = (size_t)bid * NSPL;

  float mp[NSPL], sp[NSPL];
#pragma unroll
  for (int p = 0; p < NSPL; ++p) {
    mp[p] = pm[(pb + p) * 8 + hg];
    sp[p] = ps[(pb + p) * 8 + hg];
  }
  float M = mp[0];
#pragma unroll
  for (int p = 1; p < NSPL; ++p) M = fmaxf(M, mp[p]);
  float den = 0.f;
  float4 acc = make_float4(0.f, 0.f, 0.f, 0.f);
#pragma unroll
  for (int p = 0; p < NSPL; ++p) {
    float f = __expf(mp[p] - M);     // empty part m=-inf -> 0
    den = fmaf(f, sp[p], den);
    float4 t = *(const float4*)&po[(pb + p) * 256 + lane * 4];
    acc.x = fmaf(f, t.x, acc.x);
    acc.y = fmaf(f, t.y, acc.y);
    acc.z = fmaf(f, t.z, acc.z);
    acc.w = fmaf(f, t.w, acc.w);
  }
  float inv = 1.f / den;
  float4 res = make_float4(acc.x * inv, acc.y * inv, acc.z * inv, acc.w * inv);
  *(float4*)&out[(size_t)bid * 256 + lane * 4] = res;
}

// ---------------------------------------------------------------------------
// LayerNorm over D=256: one wave per row. x already contains residual sum.
__global__ __launch_bounds__(256) void ln_kernel(
    const float* __restrict__ x, const float* __restrict__ g,
    const float* __restrict__ bta, float* __restrict__ out)
{
  int wv = threadIdx.x >> 6;
  int lane = threadIdx.x & 63;
  int row = blockIdx.x * 4 + wv;
  const float* xr = x + (size_t)row * 256;
  float v[4];
#pragma unroll
  for (int j = 0; j < 4; ++j) v[j] = xr[lane + 64 * j];
  float s = v[0] + v[1] + v[2] + v[3];
  s = wred_sum(s);
  float mean = s * (1.f / 256.f);
  float vs = 0.f;
#pragma unroll
  for (int j = 0; j < 4; ++j) { float d = v[j] - mean; vs = fmaf(d, d, vs); }
  vs = wred_sum(vs);
  float inv = rsqrtf(vs * (1.f / 256.f) + 1e-5f);
  float* orow = out + (size_t)row * 256;
#pragma unroll
  for (int j = 0; j < 4; ++j) {
    int c = lane + 64 * j;
    orow[c] = (v[j] - mean) * inv * g[c] + bta[c];
  }
}

// ---------------------------------------------------------------------------
// Layer-0 mask boxes from attn_area.
__global__ __launch_bounds__(256) void mask0_kernel(
    const float* __restrict__ area, int* __restrict__ lohi,
    float px, float py, float pz)
{
  int row = blockIdx.x * 256 + threadIdx.x;
  if (row >= MR) return;
  int q = row % NQQ;
  int org = q / QPO_;
  const float* a = area + org * 6;
  int* o = lohi + (size_t)row * 6;
  o[0] = (int)fminf(fmaxf(floorf(a[0] * 20.f - px), 0.f), 20.f);
  o[1] = (int)fminf(fmaxf(floorf(a[1] * 20.f - py), 0.f), 20.f);
  o[2] = (int)fminf(fmaxf(floorf(a[2] * 32.f - pz), 0.f), 32.f);
  o[3] = (int)fminf(fmaxf(floorf(a[3] * 20.f + px), 0.f), 20.f);
  o[4] = (int)fminf(fmaxf(floorf(a[4] * 20.f + py), 0.f), 20.f);
  o[5] = (int)fminf(fmaxf(floorf(a[5] * 32.f + pz), 0.f), 32.f);
}

// ---------------------------------------------------------------------------
// Layers >=1: prop = h2 @ w3.T + b3 -> tanh*0.1 + anchors -> clip -> box ints.
__global__ __launch_bounds__(256) void mask_reg_kernel(
    const float* __restrict__ h2, const float* __restrict__ w3,
    const float* __restrict__ b3, const float* __restrict__ anchors,
    int* __restrict__ lohi, float px, float py, float pz)
{
  int wv = threadIdx.x >> 6;
  int lane = threadIdx.x & 63;
  int row = blockIdx.x * 4 + wv;
  int q = row % NQQ;
  const float* hr = h2 + (size_t)row * 256;
  float part[6] = {};
#pragma unroll
  for (int j = 0; j < 4; ++j) {
    float hv = hr[lane + 64 * j];
#pragma unroll
    for (int o = 0; o < 6; ++o)
      part[o] = fmaf(hv, w3[o * 256 + lane + 64 * j], part[o]);
  }
#pragma unroll
  for (int o = 0; o < 6; ++o) part[o] = wred_sum(part[o]);
  if (lane == 0) {
    float prop[6];
#pragma unroll
    for (int o = 0; o < 6; ++o) {
      float v = tanhf(part[o] + b3[o]) * 0.1f + anchors[q * 6 + o];
      prop[o] = fminf(fmaxf(v, 0.f), 1.f);
    }
    float vl0 = prop[0] - 0.5f * prop[3], vh0 = prop[0] + 0.5f * prop[3];
    float vl1 = prop[1] - 0.5f * prop[4], vh1 = prop[1] + 0.5f * prop[4];
    float vl2 = prop[2] - 0.5f * prop[5], vh2 = prop[2] + 0.5f * prop[5];
    int* o = lohi + (size_t)row * 6;
    o[0] = (int)fminf(fmaxf(floorf(vl0 * 20.f - px), 0.f), 20.f);
    o[1] = (int)fminf(fmaxf(floorf(vl1 * 20.f - py), 0.f), 20.f);
    o[2] = (int)fminf(fmaxf(floorf(vl2 * 32.f - pz), 0.f), 32.f);
    o[3] = (int)fminf(fmaxf(floorf(vh0 * 20.f + px), 0.f), 20.f);
    o[4] = (int)fminf(fmaxf(floorf(vh1 * 20.f + py), 0.f), 20.f);
    o[5] = (int)fminf(fmaxf(floorf(vh2 * 32.f + pz), 0.f), 32.f);
  }
}

// ---------------------------------------------------------------------------
extern "C" void kernel_launch(void* const* d_in, const int* in_sizes, int n_in,
                              void* d_out, int out_size, void* d_ws, size_t ws_size,
                              hipStream_t stream)
{
  const float* src       = (const float*)d_in[0];
  const float* pos       = (const float*)d_in[1];
  const float* qe        = (const float*)d_in[2];
  const float* sa_in_w   = (const float*)d_in[3];
  const float* sa_in_b   = (const float*)d_in[4];
  const float* sa_out_w  = (const float*)d_in[5];
  const float* sa_out_b  = (const float*)d_in[6];
  const float* ca_k_w    = (const float*)d_in[7];
  const float* ca_v_w    = (const float*)d_in[8];
  const float* ca_proj_w = (const float*)d_in[9];
  const float* ca_proj_b = (const float*)d_in[10];
  const float* ln1_g = (const float*)d_in[11];
  const float* ln1_b = (const float*)d_in[12];
  const float* ln2_g = (const float*)d_in[13];
  const float* ln2_b = (const float*)d_in[14];
  const float* ln3_g = (const float*)d_in[15];
  const float* ln3_b = (const float*)d_in[16];
  const float* ffn_w1 = (const float*)d_in[17];
  const float* ffn_b1 = (const float*)d_in[18];
  const float* ffn_w2 = (const float*)d_in[19];
  const float* ffn_b2 = (const float*)d_in[20];
  const float* reg_w1 = (const float*)d_in[21];
  const float* reg_b1 = (const float*)d_in[22];
  const float* reg_w2 = (const float*)d_in[23];
  const float* reg_b2 = (const float*)d_in[24];
  const float* reg_w3 = (const float*)d_in[25];
  const float* reg_b3 = (const float*)d_in[26];
  const float* anchors   = (const float*)d_in[27];
  const float* attn_area = (const float*)d_in[28];
  float* outp = (float*)d_out;

  float* ws = (float*)d_ws;
  size_t off = 0;
  auto alloc = [&](size_t n) { float* p = ws + off; off += n; return p; };
  __half* Kb = (__half*)alloc((size_t)BB * PP * 128);   // fp16 [b][p][256], 13.1 MB
  __half* Vb = (__half*)alloc((size_t)BB * PP * 128);   // fp16, 13.1 MB
  alloc(4096);                                          // over-read pad
  __half* s16  = (__half*)alloc((size_t)BB * PP * 128); // fp16(src) [b][p][d]
  __half* kv16 = (__half*)alloc((size_t)BB * PP * 128); // fp16(src+pos) [b][p][d]
  __half* kw16 = (__half*)alloc((size_t)LL * DD * DD / 2);
  __half* vw16 = (__half*)alloc((size_t)LL * DD * DD / 2);
  __half* saw16 = (__half*)alloc((size_t)LL * 768 * DD / 2);   // sa_in_w
  __half* sow16 = (__half*)alloc((size_t)LL * DD * DD / 2);    // sa_out_w
  __half* pw16  = (__half*)alloc((size_t)LL * DD * DD / 2);    // ca_proj_w
  __half* f1w16 = (__half*)alloc((size_t)LL * FFD * DD / 2);   // ffn_w1
  __half* f2w16 = (__half*)alloc((size_t)LL * DD * FFD / 2);   // ffn_w2
  __half* r1w16 = (__half*)alloc((size_t)DD * DD / 2);         // reg_w1
  __half* r2w16 = (__half*)alloc((size_t)DD * DD / 2);         // reg_w2
  __half* saqk16 = (__half*)alloc((size_t)MR * 512 / 2);       // SA q|k fp16
  __half* sav16  = (__half*)alloc((size_t)MR * 256 / 2);       // SA v fp16
  alloc(2048);                                          // SA over-read pad
  float* tgt  = alloc((size_t)MR * DD);
  float* qpos = alloc((size_t)MR * DD);
  float* tmp  = alloc((size_t)MR * DD);
  float* sao  = alloc((size_t)MR * DD);
  float* caq  = alloc((size_t)MR * DD);
  float* cao  = alloc((size_t)MR * DD);
  float* mh1  = alloc((size_t)MR * DD);
  float* mh2  = alloc((size_t)MR * DD);
  float* ffh  = alloc((size_t)MR * FFD);
  float* pmb  = alloc((size_t)MR * NSPL * 8);
  float* psb  = alloc((size_t)MR * NSPL * 8);
  float* pob  = alloc((size_t)MR * NSPL * 256);
  int*   lohi = (int*)alloc((size_t)MR * 6);
  alloc(8192);                                          // A over-read pad
  (void)in_sizes; (void)n_in; (void)out_size; (void)ws_size;

  const float FOCUS_H[6] = {0.1f, 0.075f, 0.05f, 0.05f, 0.025f, 0.025f};

  init_kernel<<<1080, 256, 0, stream>>>(qe, tgt, qpos);
  conv_kv_inputs<<<dim3(200, 4, 2), 256, 0, stream>>>(src, pos, s16, kv16);
  conv_w<<<768, 256, 0, stream>>>(ca_k_w, kw16, LL * DD * DD);
  conv_w<<<768, 256, 0, stream>>>(ca_v_w, vw16, LL * DD * DD);
  conv_w<<<768, 256, 0, stream>>>(sa_in_w, saw16, LL * 768 * DD);
  conv_w<<<768, 256, 0, stream>>>(sa_out_w, sow16, LL * DD * DD);
  conv_w<<<768, 256, 0, stream>>>(ca_proj_w, pw16, LL * DD * DD);
  conv_w<<<768, 256, 0, stream>>>(ffn_w1, f1w16, LL * FFD * DD);
  conv_w<<<768, 256, 0, stream>>>(ffn_w2, f2w16, LL * DD * FFD);
  conv_w<<<256, 256, 0, stream>>>(reg_w1, r1w16, DD * DD);
  conv_w<<<256, 256, 0, stream>>>(reg_w2, r2w16, DD * DD);

  for (int i = 0; i < LL; ++i) {
    const __half* wi16 = saw16 + (size_t)i * 768 * DD;
    const float*  bi   = sa_in_b + (size_t)i * 768;
    // SA: q,k from (tgt+qpos), v from tgt -> fp16 buffers
    gemm_rows_mfma_h<<<dim3(34, 8), 256, 0, stream>>>(tgt, qpos, wi16, bi, saqk16, MR, 512, DD);
    gemm_rows_mfma_h<<<dim3(34, 4), 256, 0, stream>>>(tgt, nullptr, wi16 + 512 * DD, bi + 512, sav16, MR, DD, DD);
    sa_attn<<<MR, 512, 0, stream>>>(saqk16, sav16, sao);
    gemm_rows_mfma<<<dim3(34, 4), 256, 0, stream>>>(sao, nullptr, sow16 + (size_t)i * DD * DD,
                                                    sa_out_b + (size_t)i * DD, tgt, tmp, MR, DD, DD, 0);
    ln_kernel<<<270, 256, 0, stream>>>(tmp, ln2_g + i * DD, ln2_b + i * DD, tgt);

    // mask boxes
    if (i == 0) {
      mask0_kernel<<<5, 256, 0, stream>>>(attn_area, lohi,
          FOCUS_H[0] * PS0, FOCUS_H[0] * PS1, FOCUS_H[0] * PS2);
    } else {
      gemm_rows_mfma<<<dim3(34, 4), 256, 0, stream>>>(tgt, nullptr, r1w16, reg_b1, nullptr, mh1, MR, DD, DD, 1);
      gemm_rows_mfma<<<dim3(34, 4), 256, 0, stream>>>(mh1, nullptr, r2w16, reg_b2, nullptr, mh2, MR, DD, DD, 1);
      mask_reg_kernel<<<270, 256, 0, stream>>>(mh2, reg_w3, reg_b3, anchors, lohi,
          FOCUS_H[i] * PS0, FOCUS_H[i] * PS1, FOCUS_H[i] * PS2);
    }

    // CA: q from (tgt+qpos)@ca_k_w; K from (src+pos)@ca_k_w; V from src@ca_v_w
    gemm_rows_mfma<<<dim3(34, 4), 256, 0, stream>>>(tgt, qpos, kw16 + (size_t)i * DD * DD,
                                                    nullptr, nullptr, caq, MR, DD, DD, 0);
    gemm_kv2_mfma<<<dim3(100, 2, 4), 256, 0, stream>>>(kv16, s16,
                                                       kw16 + (size_t)i * DD * DD,
                                                       vw16 + (size_t)i * DD * DD, Kb, Vb);
    ca_attn_part<<<MR * NSPL, 256, 0, stream>>>(caq, Kb, Vb, lohi, pmb, psb, pob);
    ca_merge<<<270, 256, 0, stream>>>(pmb, psb, pob, cao);
    gemm_rows_mfma<<<dim3(34, 4), 256, 0, stream>>>(cao, nullptr, pw16 + (size_t)i * DD * DD,
                                                    ca_proj_b + (size_t)i * DD, tgt, tmp, MR, DD, DD, 0);
    ln_kernel<<<270, 256, 0, stream>>>(tmp, ln1_g + i * DD, ln1_b + i * DD, tgt);

    // FFN
    gemm_rows_mfma<<<dim3(34, 16), 256, 0, stream>>>(tgt, nullptr, f1w16 + (size_t)i * FFD * DD,
                                                     ffn_b1 + (size_t)i * FFD, nullptr, ffh, MR, FFD, DD, 1);
    gemm_rows_mfma<<<dim3(34, 4), 256, 0, stream>>>(ffh, nullptr, f2w16 + (size_t)i * DD * FFD,
                                                    ffn_b2 + (size_t)i * DD, tgt, tmp, MR, DD, FFD, 0);
    float* lno = (i == LL - 1) ? outp : tgt;
    ln_kernel<<<270, 256, 0, stream>>>(tmp, ln3_g + i * DD, ln3_b + i * DD, lno);
  }
}

// Round 20
// 1344.400 us; speedup vs baseline: 1.4771x; 1.0374x over previous
//
#include <hip/hip_runtime.h>
#include <hip/hip_fp16.h>
#include <math.h>

#define BB 2
#define DD 256
#define HH 8
#define HDIM 32
#define FFD 1024
#define LL 6
#define NQQ 540
#define QPO_ 27
#define PS0 20
#define PS1 20
#define PS2 32
#define PP (PS0*PS1*PS2)   // 12800
#define MR (BB*NQQ)        // 1080
#define NSPL 8             // cross-attn row-partials per query (4-wave blocks)

typedef _Float16 half8 __attribute__((ext_vector_type(8)));
typedef _Float16 half4v __attribute__((ext_vector_type(4)));
typedef _Float16 h2v  __attribute__((ext_vector_type(2)));
typedef float f32x4 __attribute__((ext_vector_type(4)));

static __device__ __forceinline__ float wred_sum(float x) {
#pragma unroll
  for (int off = 32; off; off >>= 1) x += __shfl_xor(x, off, 64);
  return x;
}
static __device__ __forceinline__ float4 h4_to_f4(uint2 u) {
  __half2 h0 = *reinterpret_cast<__half2*>(&u.x);
  __half2 h1 = *reinterpret_cast<__half2*>(&u.y);
  float2 f0 = __half22float2(h0);
  float2 f1 = __half22float2(h1);
  return make_float4(f0.x, f0.y, f1.x, f1.y);
}

// ---------------------------------------------------------------------------
// init: tgt[b,q,d] = qe[q, 256+d]; qpos[b,q,d] = qe[q, d]
__global__ __launch_bounds__(256) void init_kernel(
    const float* __restrict__ qe, float* __restrict__ tgt, float* __restrict__ qpos)
{
  int idx = blockIdx.x * 256 + threadIdx.x;   // < B*NQ*D == 276480
  int d = idx % DD;
  int q = (idx / DD) % NQQ;
  qpos[idx] = qe[q * 512 + d];
  tgt[idx]  = qe[q * 512 + 256 + d];
}

// ---------------------------------------------------------------------------
// One-time: transpose+convert src/pos to fp16 [b][p][d] layouts.
__global__ __launch_bounds__(256) void conv_kv_inputs(
    const float* __restrict__ src, const float* __restrict__ pos,
    __half* __restrict__ s16, __half* __restrict__ kv16)
{
  __shared__ float ls[64][65];
  __shared__ float lk[64][65];
  int b  = blockIdx.z;
  int p0 = blockIdx.x * 64;
  int d0 = blockIdx.y * 64;
  int t = threadIdx.x;
  int pr = (t & 15) * 4;
  int dr = t >> 4;
#pragma unroll
  for (int dd = 0; dd < 64; dd += 16) {
    int d = d0 + dd + dr;
    float4 sv = *(const float4*)&src[((size_t)b * DD + d) * PP + p0 + pr];
    float4 pv = *(const float4*)&pos[((size_t)b * DD + d) * PP + p0 + pr];
    ls[pr + 0][dd + dr] = sv.x; ls[pr + 1][dd + dr] = sv.y;
    ls[pr + 2][dd + dr] = sv.z; ls[pr + 3][dd + dr] = sv.w;
    lk[pr + 0][dd + dr] = sv.x + pv.x; lk[pr + 1][dd + dr] = sv.y + pv.y;
    lk[pr + 2][dd + dr] = sv.z + pv.z; lk[pr + 3][dd + dr] = sv.w + pv.w;
  }
  __syncthreads();
  int wp = t >> 2;
  int wd = (t & 3) * 16;
  size_t base = ((size_t)b * PP + p0 + wp) * 256 + d0 + wd;
#pragma unroll
  for (int i = 0; i < 16; i += 2) {
    *(__half2*)&s16[base + i]  = __floats2half2_rn(ls[wp][wd + i], ls[wp][wd + i + 1]);
    *(__half2*)&kv16[base + i] = __floats2half2_rn(lk[wp][wd + i], lk[wp][wd + i + 1]);
  }
}

// One-time: fp32 -> fp16 weight conversion (grid-stride).
__global__ __launch_bounds__(256) void conv_w(
    const float* __restrict__ w, __half* __restrict__ w16, int n)
{
  for (int i = blockIdx.x * 256 + threadIdx.x; i < n; i += gridDim.x * 256)
    w16[i] = __float2half_rn(w[i]);
}

// ---------------------------------------------------------------------------
// Merged MFMA K&V projection: z>>1 selects (A,W,out) pair, z&1 = batch b.
__global__ __launch_bounds__(256) void gemm_kv2_mfma(
    const __half* __restrict__ Ak, const __half* __restrict__ Av,
    const __half* __restrict__ Wk, const __half* __restrict__ Wv,
    __half* __restrict__ Ko, __half* __restrict__ Vo)
{
  int z = blockIdx.z;
  int b = z & 1;
  const __half* A = (z >> 1) ? Av : Ak;
  const __half* W = (z >> 1) ? Wv : Wk;
  __half* out     = (z >> 1) ? Vo : Ko;
  int wid = threadIdx.x >> 6;
  int lane = threadIdx.x & 63;
  int p0 = blockIdx.x * 128 + (wid >> 1) * 64;
  int n0 = blockIdx.y * 128 + (wid & 1) * 64;
  const __half* Ab = A + (size_t)b * PP * 256;
  int row = lane & 15;
  int kg  = lane >> 4;
  f32x4 acc[4][4] = {};
  for (int k0 = 0; k0 < 256; k0 += 32) {
    half8 af[4], bf[4];
#pragma unroll
    for (int i = 0; i < 4; ++i)
      af[i] = *(const half8*)&Ab[((size_t)(p0 + 16 * i + row)) * 256 + k0 + kg * 8];
#pragma unroll
    for (int j = 0; j < 4; ++j)
      bf[j] = *(const half8*)&W[((size_t)(n0 + 16 * j + row)) * 256 + k0 + kg * 8];
#pragma unroll
    for (int i = 0; i < 4; ++i)
#pragma unroll
      for (int j = 0; j < 4; ++j)
        acc[i][j] = __builtin_amdgcn_mfma_f32_16x16x32_f16(af[i], bf[j], acc[i][j], 0, 0, 0);
  }
#pragma unroll
  for (int i = 0; i < 4; ++i)
#pragma unroll
    for (int j = 0; j < 4; ++j) {
      int nc = n0 + 16 * j + row;
#pragma unroll
      for (int r = 0; r < 4; ++r) {
        int pr = p0 + 16 * i + kg * 4 + r;
        out[((size_t)b * PP + pr) * 256 + nc] = __float2half_rn(acc[i][j][r]);
      }
    }
}

// ---------------------------------------------------------------------------
// MFMA row GEMM, BM=32 (for N=512/1024 shapes with >=272-block grids).
__global__ __launch_bounds__(256) void gemm_rows_mfma(
    const float* __restrict__ A1, const float* __restrict__ A2,
    const __half* __restrict__ W, const float* __restrict__ bias,
    const float* __restrict__ res, float* __restrict__ C,
    int M, int N, int K, int relu)
{
  __shared__ __half a_s[32][40];
  int bm = blockIdx.x * 32;
  int bn = blockIdx.y * 64;
  int wv = threadIdx.x >> 6;
  int lane = threadIdx.x & 63;
  int row = lane & 15;
  int kg  = lane >> 4;
  int nw  = bn + wv * 16;
  int t = threadIdx.x;
  int srow = t >> 3, skq = (t & 7) * 4;
  f32x4 acc[2] = {};

  for (int k0 = 0; k0 < K; k0 += 32) {
    {
      size_t off = (size_t)(bm + srow) * K + k0 + skq;
      float4 a0 = *(const float4*)&A1[off];
      if (A2) {
        float4 b0 = *(const float4*)&A2[off];
        a0.x += b0.x; a0.y += b0.y; a0.z += b0.z; a0.w += b0.w;
      }
      half4v h;
      h[0] = (_Float16)a0.x; h[1] = (_Float16)a0.y;
      h[2] = (_Float16)a0.z; h[3] = (_Float16)a0.w;
      *(half4v*)&a_s[srow][skq] = h;
    }
    __syncthreads();
    half8 bf = *(const half8*)&W[(size_t)(nw + row) * K + k0 + kg * 8];
#pragma unroll
    for (int i = 0; i < 2; ++i) {
      half8 af = *(const half8*)&a_s[16 * i + row][kg * 8];
      acc[i] = __builtin_amdgcn_mfma_f32_16x16x32_f16(af, bf, acc[i], 0, 0, 0);
    }
    __syncthreads();
  }

  int col = nw + row;
  float bval = bias ? bias[col] : 0.f;
#pragma unroll
  for (int i = 0; i < 2; ++i) {
#pragma unroll
    for (int r = 0; r < 4; ++r) {
      int rr = bm + 16 * i + kg * 4 + r;
      if (rr >= M) continue;
      float v = acc[i][r] + bval;
      if (relu) v = fmaxf(v, 0.f);
      if (res)  v += res[(size_t)rr * N + col];
      C[(size_t)rr * N + col] = v;
    }
  }
}

// ---------------------------------------------------------------------------
// MFMA row GEMM, BM=16 (272-block grids for N=256 skinny shapes).
__global__ __launch_bounds__(256) void gemm_rows_mfma16(
    const float* __restrict__ A1, const float* __restrict__ A2,
    const __half* __restrict__ W, const float* __restrict__ bias,
    const float* __restrict__ res, float* __restrict__ C,
    int M, int N, int K, int relu)
{
  __shared__ __half a_s[16][40];
  int bm = blockIdx.x * 16;
  int bn = blockIdx.y * 64;
  int wv = threadIdx.x >> 6;
  int lane = threadIdx.x & 63;
  int row = lane & 15;
  int kg  = lane >> 4;
  int nw  = bn + wv * 16;
  int t = threadIdx.x;
  int srow = t >> 4, skq = (t & 15) * 2;
  f32x4 acc = {};

  for (int k0 = 0; k0 < K; k0 += 32) {
    {
      size_t off = (size_t)(bm + srow) * K + k0 + skq;
      float2 a0 = *(const float2*)&A1[off];
      if (A2) {
        float2 b0 = *(const float2*)&A2[off];
        a0.x += b0.x; a0.y += b0.y;
      }
      *(__half2*)&a_s[srow][skq] = __floats2half2_rn(a0.x, a0.y);
    }
    __syncthreads();
    half8 bf = *(const half8*)&W[(size_t)(nw + row) * K + k0 + kg * 8];
    half8 af = *(const half8*)&a_s[row][kg * 8];
    acc = __builtin_amdgcn_mfma_f32_16x16x32_f16(af, bf, acc, 0, 0, 0);
    __syncthreads();
  }

  int col = nw + row;
  float bval = bias ? bias[col] : 0.f;
#pragma unroll
  for (int r = 0; r < 4; ++r) {
    int rr = bm + kg * 4 + r;
    if (rr >= M) continue;
    float v = acc[r] + bval;
    if (relu) v = fmaxf(v, 0.f);
    if (res)  v += res[(size_t)rr * N + col];
    C[(size_t)rr * N + col] = v;
  }
}

// ---------------------------------------------------------------------------
// MFMA row GEMM (BM=32) with fp16 output (saqk, N=512: grid 34x8=272).
__global__ __launch_bounds__(256) void gemm_rows_mfma_h(
    const float* __restrict__ A1, const float* __restrict__ A2,
    const __half* __restrict__ W, const float* __restrict__ bias,
    __half* __restrict__ C, int M, int N, int K)
{
  __shared__ __half a_s[32][40];
  int bm = blockIdx.x * 32;
  int bn = blockIdx.y * 64;
  int wv = threadIdx.x >> 6;
  int lane = threadIdx.x & 63;
  int row = lane & 15;
  int kg  = lane >> 4;
  int nw  = bn + wv * 16;
  int t = threadIdx.x;
  int srow = t >> 3, skq = (t & 7) * 4;
  f32x4 acc[2] = {};

  for (int k0 = 0; k0 < K; k0 += 32) {
    {
      size_t off = (size_t)(bm + srow) * K + k0 + skq;
      float4 a0 = *(const float4*)&A1[off];
      if (A2) {
        float4 b0 = *(const float4*)&A2[off];
        a0.x += b0.x; a0.y += b0.y; a0.z += b0.z; a0.w += b0.w;
      }
      half4v h;
      h[0] = (_Float16)a0.x; h[1] = (_Float16)a0.y;
      h[2] = (_Float16)a0.z; h[3] = (_Float16)a0.w;
      *(half4v*)&a_s[srow][skq] = h;
    }
    __syncthreads();
    half8 bf = *(const half8*)&W[(size_t)(nw + row) * K + k0 + kg * 8];
#pragma unroll
    for (int i = 0; i < 2; ++i) {
      half8 af = *(const half8*)&a_s[16 * i + row][kg * 8];
      acc[i] = __builtin_amdgcn_mfma_f32_16x16x32_f16(af, bf, acc[i], 0, 0, 0);
    }
    __syncthreads();
  }

  int col = nw + row;
  float bval = bias ? bias[col] : 0.f;
#pragma unroll
  for (int i = 0; i < 2; ++i) {
#pragma unroll
    for (int r = 0; r < 4; ++r) {
      int rr = bm + 16 * i + kg * 4 + r;
      if (rr >= M) continue;
      C[(size_t)rr * N + col] = __float2half_rn(acc[i][r] + bval);
    }
  }
}

// ---------------------------------------------------------------------------
// MFMA row GEMM, BM=16, fp16 output (sav, N=256: grid 68x4=272).
__global__ __launch_bounds__(256) void gemm_rows_mfma_h16(
    const float* __restrict__ A1, const float* __restrict__ A2,
    const __half* __restrict__ W, const float* __restrict__ bias,
    __half* __restrict__ C, int M, int N, int K)
{
  __shared__ __half a_s[16][40];
  int bm = blockIdx.x * 16;
  int bn = blockIdx.y * 64;
  int wv = threadIdx.x >> 6;
  int lane = threadIdx.x & 63;
  int row = lane & 15;
  int kg  = lane >> 4;
  int nw  = bn + wv * 16;
  int t = threadIdx.x;
  int srow = t >> 4, skq = (t & 15) * 2;
  f32x4 acc = {};

  for (int k0 = 0; k0 < K; k0 += 32) {
    {
      size_t off = (size_t)(bm + srow) * K + k0 + skq;
      float2 a0 = *(const float2*)&A1[off];
      if (A2) {
        float2 b0 = *(const float2*)&A2[off];
        a0.x += b0.x; a0.y += b0.y;
      }
      *(__half2*)&a_s[srow][skq] = __floats2half2_rn(a0.x, a0.y);
    }
    __syncthreads();
    half8 bf = *(const half8*)&W[(size_t)(nw + row) * K + k0 + kg * 8];
    half8 af = *(const half8*)&a_s[row][kg * 8];
    acc = __builtin_amdgcn_mfma_f32_16x16x32_f16(af, bf, acc, 0, 0, 0);
    __syncthreads();
  }

  int col = nw + row;
  float bval = bias ? bias[col] : 0.f;
#pragma unroll
  for (int r = 0; r < 4; ++r) {
    int rr = bm + kg * 4 + r;
    if (rr >= M) continue;
    C[(size_t)rr * N + col] = __float2half_rn(acc[r] + bval);
  }
}

// ---------------------------------------------------------------------------
// Self-attention, fp16 K/V, 2-keys-per-pass layout (R16-proven).
__global__ __launch_bounds__(512) void sa_attn(
    const __half* __restrict__ qk16, const __half* __restrict__ v16,
    float* __restrict__ out)
{
  __shared__ float wmS[8][8];
  __shared__ float wsS[8][8];
  __shared__ float4 ooS[8][64];

  int bid = blockIdx.x;           // b*NQQ + q
  int b = bid / NQQ;
  int wv = threadIdx.x >> 6;
  int lane = threadIdx.x & 63;
  int li   = lane & 31;           // dim-slot: dims 8*li .. 8*li+7
  int half = lane >> 5;           // even/odd key of each pass
  const float scale = 0.17677669529663687f;  // 32^-0.5

  uint4 qraw = *(const uint4*)(qk16 + (size_t)bid * 512 + 8 * li);
  float4 qa = h4_to_f4(make_uint2(qraw.x, qraw.y));
  float4 qb = h4_to_f4(make_uint2(qraw.z, qraw.w));
  h2v qh0, qh1, qh2, qh3;
  qh0[0] = (_Float16)(qa.x * scale); qh0[1] = (_Float16)(qa.y * scale);
  qh1[0] = (_Float16)(qa.z * scale); qh1[1] = (_Float16)(qa.w * scale);
  qh2[0] = (_Float16)(qb.x * scale); qh2[1] = (_Float16)(qb.y * scale);
  qh3[0] = (_Float16)(qb.z * scale); qh3[1] = (_Float16)(qb.w * scale);

  const __half* Kb = qk16 + (size_t)b * NQQ * 512 + 256;  // k part of rows
  const __half* Vb = v16 + (size_t)b * NQQ * 256;

  float m = -INFINITY, sA = 0.f, sB = 0.f;
  float4 oA0 = make_float4(0.f, 0.f, 0.f, 0.f), oA1 = oA0;
  float4 oB0 = oA0, oB1 = oA0;

  for (int k0 = wv * 8; k0 < NQQ; k0 += 64) {
    const uint4* kp = (const uint4*)(Kb + (size_t)(k0 + half) * 512 + 8 * li);
    const uint4* vp = (const uint4*)(Vb + (size_t)(k0 + half) * 256 + 8 * li);
    uint4 kw0 = kp[0], kw1 = kp[128], kw2 = kp[256], kw3 = kp[384];
    uint4 vw0 = vp[0], vw1 = vp[64],  vw2 = vp[128], vw3 = vp[192];

    float lg[4];
#pragma unroll
    for (int j = 0; j < 4; ++j) {
      uint4 kwj = (j == 0) ? kw0 : (j == 1) ? kw1 : (j == 2) ? kw2 : kw3;
      h2v a0 = *reinterpret_cast<h2v*>(&kwj.x);
      h2v a1 = *reinterpret_cast<h2v*>(&kwj.y);
      h2v a2 = *reinterpret_cast<h2v*>(&kwj.z);
      h2v a3 = *reinterpret_cast<h2v*>(&kwj.w);
      float d = __builtin_amdgcn_fdot2(a0, qh0, 0.f, false);
      d = __builtin_amdgcn_fdot2(a1, qh1, d, false);
      d = __builtin_amdgcn_fdot2(a2, qh2, d, false);
      d = __builtin_amdgcn_fdot2(a3, qh3, d, false);
      d += __shfl_xor(d, 1, 64);
      d += __shfl_xor(d, 2, 64);
      lg[j] = (k0 + 2 * j + half < NQQ) ? d : -INFINITY;
    }

    float bm = fmaxf(fmaxf(lg[0], lg[1]), fmaxf(lg[2], lg[3]));
    bm = fmaxf(bm, __shfl_xor(bm, 32, 64));
    if (bm > m + 8.f) {
      float f = __expf(m - bm);
      sA *= f; sB *= f;
      oA0.x *= f; oA0.y *= f; oA0.z *= f; oA0.w *= f;
      oA1.x *= f; oA1.y *= f; oA1.z *= f; oA1.w *= f;
      oB0.x *= f; oB0.y *= f; oB0.z *= f; oB0.w *= f;
      oB1.x *= f; oB1.y *= f; oB1.z *= f; oB1.w *= f;
      m = bm;
    }
    {
      float pa = __expf(lg[0] - m);
      float pb = __expf(lg[1] - m);
      float4 alo = h4_to_f4(make_uint2(vw0.x, vw0.y));
      float4 ahi = h4_to_f4(make_uint2(vw0.z, vw0.w));
      float4 blo = h4_to_f4(make_uint2(vw1.x, vw1.y));
      float4 bhi = h4_to_f4(make_uint2(vw1.z, vw1.w));
      sA += pa; sB += pb;
      oA0.x = fmaf(pa, alo.x, oA0.x); oB0.x = fmaf(pb, blo.x, oB0.x);
      oA0.y = fmaf(pa, alo.y, oA0.y); oB0.y = fmaf(pb, blo.y, oB0.y);
      oA0.z = fmaf(pa, alo.z, oA0.z); oB0.z = fmaf(pb, blo.z, oB0.z);
      oA0.w = fmaf(pa, alo.w, oA0.w); oB0.w = fmaf(pb, blo.w, oB0.w);
      oA1.x = fmaf(pa, ahi.x, oA1.x); oB1.x = fmaf(pb, bhi.x, oB1.x);
      oA1.y = fmaf(pa, ahi.y, oA1.y); oB1.y = fmaf(pb, bhi.y, oB1.y);
      oA1.z = fmaf(pa, ahi.z, oA1.z); oB1.z = fmaf(pb, bhi.z, oB1.z);
      oA1.w = fmaf(pa, ahi.w, oA1.w); oB1.w = fmaf(pb, bhi.w, oB1.w);
    }
    {
      float pa = __expf(lg[2] - m);
      float pb = __expf(lg[3] - m);
      float4 alo = h4_to_f4(make_uint2(vw2.x, vw2.y));
      float4 ahi = h4_to_f4(make_uint2(vw2.z, vw2.w));
      float4 blo = h4_to_f4(make_uint2(vw3.x, vw3.y));
      float4 bhi = h4_to_f4(make_uint2(vw3.z, vw3.w));
      sA += pa; sB += pb;
      oA0.x = fmaf(pa, alo.x, oA0.x); oB0.x = fmaf(pb, blo.x, oB0.x);
      oA0.y = fmaf(pa, alo.y, oA0.y); oB0.y = fmaf(pb, blo.y, oB0.y);
      oA0.z = fmaf(pa, alo.z, oA0.z); oB0.z = fmaf(pb, blo.z, oB0.z);
      oA0.w = fmaf(pa, alo.w, oA0.w); oB0.w = fmaf(pb, blo.w, oB0.w);
      oA1.x = fmaf(pa, ahi.x, oA1.x); oB1.x = fmaf(pb, bhi.x, oB1.x);
      oA1.y = fmaf(pa, ahi.y, oA1.y); oB1.y = fmaf(pb, bhi.y, oB1.y);
      oA1.z = fmaf(pa, ahi.z, oA1.z); oB1.z = fmaf(pb, bhi.z, oB1.z);
      oA1.w = fmaf(pa, ahi.w, oA1.w); oB1.w = fmaf(pb, bhi.w, oB1.w);
    }
  }

  float s = sA + sB;
  s += __shfl_xor(s, 32, 64);
  float4 oL = make_float4(oA0.x + oB0.x, oA0.y + oB0.y, oA0.z + oB0.z, oA0.w + oB0.w);
  float4 oH = make_float4(oA1.x + oB1.x, oA1.y + oB1.y, oA1.z + oB1.z, oA1.w + oB1.w);
  oL.x += __shfl_xor(oL.x, 32, 64); oL.y += __shfl_xor(oL.y, 32, 64);
  oL.z += __shfl_xor(oL.z, 32, 64); oL.w += __shfl_xor(oL.w, 32, 64);
  oH.x += __shfl_xor(oH.x, 32, 64); oH.y += __shfl_xor(oH.y, 32, 64);
  oH.z += __shfl_xor(oH.z, 32, 64); oH.w += __shfl_xor(oH.w, 32, 64);

  int hh = li >> 2;
  if (lane < 32 && (li & 3) == 0) wmS[wv][hh] = m;
  __syncthreads();
  float M = wmS[0][hh];
#pragma unroll
  for (int w = 1; w < 8; ++w) M = fmaxf(M, wmS[w][hh]);
  float f = __expf(m - M);
  if (lane < 32 && (li & 3) == 0) wsS[wv][hh] = s * f;
  if (lane < 32) {
    ooS[wv][2 * li]     = make_float4(oL.x * f, oL.y * f, oL.z * f, oL.w * f);
    ooS[wv][2 * li + 1] = make_float4(oH.x * f, oH.y * f, oH.z * f, oH.w * f);
  }
  __syncthreads();
  if (threadIdx.x < 64) {
    int l = threadIdx.x;
    int hg2 = l >> 3;
    float4 acc = make_float4(0.f, 0.f, 0.f, 0.f);
    float den = 0.f;
#pragma unroll
    for (int w = 0; w < 8; ++w) {
      float4 t = ooS[w][l];
      acc.x += t.x; acc.y += t.y; acc.z += t.z; acc.w += t.w;
      den += wsS[w][hg2];
    }
    float inv = 1.f / den;
    float4 res = make_float4(acc.x * inv, acc.y * inv, acc.z * inv, acc.w * inv);
    *(float4*)&out[(size_t)bid * 256 + l * 4] = res;
  }
}

// ---------------------------------------------------------------------------
// Cross-attention partial, 2-keys-per-pass layout (R16, best measured).
__global__ __launch_bounds__(256) void ca_attn_part(
    const float* __restrict__ qbuf, const __half* __restrict__ Kbuf,
    const __half* __restrict__ Vbuf, const int* __restrict__ lohi,
    float* __restrict__ pm, float* __restrict__ ps, float* __restrict__ po)
{
  __shared__ float wmS[4][8];
  __shared__ float wsS[4][8];
  __shared__ float4 ooS[4][64];

  // --- swizzle: 8640 blocks = 8 cls x 5 gsub x 27 iq x 8 part ---
  int idx  = blockIdx.x;
  int cls  = idx & 7;
  int rest = idx >> 3;          // 0..1079
  int gsub = rest / 216;        // 0..4
  int rem  = rest % 216;
  int iq   = rem >> 3;          // 0..26
  int part = rem & 7;           // NSPL == 8
  int g    = gsub * 8 + cls;    // organ-group 0..39
  int b    = g / 20;
  int q    = (g % 20) * QPO_ + iq;
  int bid  = b * NQQ + q;

  int wv = threadIdx.x >> 6;    // 0..3
  int lane = threadIdx.x & 63;
  int li   = lane & 31;         // dim-slot: dims 8*li .. 8*li+7
  int half = lane >> 5;         // even/odd key of each pass
  const float scale = 0.17677669529663687f;

  const int* lh = lohi + (size_t)bid * 6;
  int lo0 = lh[0], lo1 = lh[1], lo2 = lh[2];
  int nx = lh[3] - lo0, ny = lh[4] - lo1, nz = lh[5] - lo2;
  int nxy = nx * ny;
  float inv_ny = 1.0f / (float)ny;

  const float4* qp = (const float4*)(qbuf + (size_t)bid * 256 + 8 * li);
  float4 qa = qp[0], qb = qp[1];
  h2v qh0, qh1, qh2, qh3;
  qh0[0] = (_Float16)(qa.x * scale); qh0[1] = (_Float16)(qa.y * scale);
  qh1[0] = (_Float16)(qa.z * scale); qh1[1] = (_Float16)(qa.w * scale);
  qh2[0] = (_Float16)(qb.x * scale); qh2[1] = (_Float16)(qb.y * scale);
  qh3[0] = (_Float16)(qb.z * scale); qh3[1] = (_Float16)(qb.w * scale);

  const __half* Kb = Kbuf + (size_t)b * PP * 256;
  const __half* Vb = Vbuf + (size_t)b * PP * 256;

  float m = -INFINITY, sA = 0.f, sB = 0.f;
  float4 oA0 = make_float4(0.f, 0.f, 0.f, 0.f), oA1 = oA0;
  float4 oB0 = oA0, oB1 = oA0;

  for (int r = part + 8 * wv; r < nxy; r += 32) {
    int x = (int)((float)r * inv_ny);
    int y = r - x * ny;
    if (y < 0)        { x--; y += ny; }
    else if (y >= ny) { x++; y -= ny; }
    int base = (lo0 + x) * (PS1 * PS2) + (lo1 + y) * PS2 + lo2;

    for (int z0 = 0; z0 < nz; z0 += 8) {
      const uint4* kp = (const uint4*)(Kb + ((size_t)(base + z0 + half)) * 256 + 8 * li);
      const uint4* vp = (const uint4*)(Vb + ((size_t)(base + z0 + half)) * 256 + 8 * li);
      uint4 kw0 = kp[0],  kw1 = kp[64], kw2 = kp[128], kw3 = kp[192];
      uint4 vw0 = vp[0],  vw1 = vp[64], vw2 = vp[128], vw3 = vp[192];

      float lg[4];
#pragma unroll
      for (int j = 0; j < 4; ++j) {
        uint4 kwj = (j == 0) ? kw0 : (j == 1) ? kw1 : (j == 2) ? kw2 : kw3;
        h2v a0 = *reinterpret_cast<h2v*>(&kwj.x);
        h2v a1 = *reinterpret_cast<h2v*>(&kwj.y);
        h2v a2 = *reinterpret_cast<h2v*>(&kwj.z);
        h2v a3 = *reinterpret_cast<h2v*>(&kwj.w);
        float d = __builtin_amdgcn_fdot2(a0, qh0, 0.f, false);
        d = __builtin_amdgcn_fdot2(a1, qh1, d, false);
        d = __builtin_amdgcn_fdot2(a2, qh2, d, false);
        d = __builtin_amdgcn_fdot2(a3, qh3, d, false);
        d += __shfl_xor(d, 1, 64);
        d += __shfl_xor(d, 2, 64);
        lg[j] = (z0 + 2 * j + half < nz) ? d : -INFINITY;
      }

      float bm = fmaxf(fmaxf(lg[0], lg[1]), fmaxf(lg[2], lg[3]));
      bm = fmaxf(bm, __shfl_xor(bm, 32, 64));
      if (bm > m + 8.f) {
        float f = __expf(m - bm);
        sA *= f; sB *= f;
        oA0.x *= f; oA0.y *= f; oA0.z *= f; oA0.w *= f;
        oA1.x *= f; oA1.y *= f; oA1.z *= f; oA1.w *= f;
        oB0.x *= f; oB0.y *= f; oB0.z *= f; oB0.w *= f;
        oB1.x *= f; oB1.y *= f; oB1.z *= f; oB1.w *= f;
        m = bm;
      }
      {
        float pa = __expf(lg[0] - m);
        float pb = __expf(lg[1] - m);
        float4 alo = h4_to_f4(make_uint2(vw0.x, vw0.y));
        float4 ahi = h4_to_f4(make_uint2(vw0.z, vw0.w));
        float4 blo = h4_to_f4(make_uint2(vw1.x, vw1.y));
        float4 bhi = h4_to_f4(make_uint2(vw1.z, vw1.w));
        sA += pa; sB += pb;
        oA0.x = fmaf(pa, alo.x, oA0.x); oB0.x = fmaf(pb, blo.x, oB0.x);
        oA0.y = fmaf(pa, alo.y, oA0.y); oB0.y = fmaf(pb, blo.y, oB0.y);
        oA0.z = fmaf(pa, alo.z, oA0.z); oB0.z = fmaf(pb, blo.z, oB0.z);
        oA0.w = fmaf(pa, alo.w, oA0.w); oB0.w = fmaf(pb, blo.w, oB0.w);
        oA1.x = fmaf(pa, ahi.x, oA1.x); oB1.x = fmaf(pb, bhi.x, oB1.x);
        oA1.y = fmaf(pa, ahi.y, oA1.y); oB1.y = fmaf(pb, bhi.y, oB1.y);
        oA1.z = fmaf(pa, ahi.z, oA1.z); oB1.z = fmaf(pb, bhi.z, oB1.z);
        oA1.w = fmaf(pa, ahi.w, oA1.w); oB1.w = fmaf(pb, bhi.w, oB1.w);
      }
      {
        float pa = __expf(lg[2] - m);
        float pb = __expf(lg[3] - m);
        float4 alo = h4_to_f4(make_uint2(vw2.x, vw2.y));
        float4 ahi = h4_to_f4(make_uint2(vw2.z, vw2.w));
        float4 blo = h4_to_f4(make_uint2(vw3.x, vw3.y));
        float4 bhi = h4_to_f4(make_uint2(vw3.z, vw3.w));
        sA += pa; sB += pb;
        oA0.x = fmaf(pa, alo.x, oA0.x); oB0.x = fmaf(pb, blo.x, oB0.x);
        oA0.y = fmaf(pa, alo.y, oA0.y); oB0.y = fmaf(pb, blo.y, oB0.y);
        oA0.z = fmaf(pa, alo.z, oA0.z); oB0.z = fmaf(pb, blo.z, oB0.z);
        oA0.w = fmaf(pa, alo.w, oA0.w); oB0.w = fmaf(pb, blo.w, oB0.w);
        oA1.x = fmaf(pa, ahi.x, oA1.x); oB1.x = fmaf(pb, bhi.x, oB1.x);
        oA1.y = fmaf(pa, ahi.y, oA1.y); oB1.y = fmaf(pb, bhi.y, oB1.y);
        oA1.z = fmaf(pa, ahi.z, oA1.z); oB1.z = fmaf(pb, bhi.z, oB1.z);
        oA1.w = fmaf(pa, ahi.w, oA1.w); oB1.w = fmaf(pb, bhi.w, oB1.w);
      }
    }
  }

  float s = sA + sB;
  s += __shfl_xor(s, 32, 64);
  float4 oL = make_float4(oA0.x + oB0.x, oA0.y + oB0.y, oA0.z + oB0.z, oA0.w + oB0.w);
  float4 oH = make_float4(oA1.x + oB1.x, oA1.y + oB1.y, oA1.z + oB1.z, oA1.w + oB1.w);
  oL.x += __shfl_xor(oL.x, 32, 64); oL.y += __shfl_xor(oL.y, 32, 64);
  oL.z += __shfl_xor(oL.z, 32, 64); oL.w += __shfl_xor(oL.w, 32, 64);
  oH.x += __shfl_xor(oH.x, 32, 64); oH.y += __shfl_xor(oH.y, 32, 64);
  oH.z += __shfl_xor(oH.z, 32, 64); oH.w += __shfl_xor(oH.w, 32, 64);

  int hh = li >> 2;
  if (lane < 32 && (li & 3) == 0) wmS[wv][hh] = m;
  __syncthreads();
  float M = wmS[0][hh];
#pragma unroll
  for (int w = 1; w < 4; ++w) M = fmaxf(M, wmS[w][hh]);
  float f = (M == -INFINITY) ? 0.f : __expf(m - M);
  if (lane < 32 && (li & 3) == 0) wsS[wv][hh] = s * f;
  if (lane < 32) {
    ooS[wv][2 * li]     = make_float4(oL.x * f, oL.y * f, oL.z * f, oL.w * f);
    ooS[wv][2 * li + 1] = make_float4(oH.x * f, oH.y * f, oH.z * f, oH.w * f);
  }
  __syncthreads();
  if (threadIdx.x < 64) {
    int l = threadIdx.x;
    int hg2 = l >> 3;
    float4 acc = make_float4(0.f, 0.f, 0.f, 0.f);
    float den = 0.f;
#pragma unroll
    for (int w = 0; w < 4; ++w) {
      float4 t = ooS[w][l];
      acc.x += t.x; acc.y += t.y; acc.z += t.z; acc.w += t.w;
      den += wsS[w][hg2];
    }
    float M2 = wmS[0][hg2];
#pragma unroll
    for (int w = 1; w < 4; ++w) M2 = fmaxf(M2, wmS[w][hg2]);
    size_t pb = (size_t)bid * NSPL + part;
    if ((l & 7) == 0) { pm[pb * 8 + hg2] = M2; ps[pb * 8 + hg2] = den; }
    *(float4*)&po[pb * 256 + l * 4] = acc;
  }
}

// ---------------------------------------------------------------------------
// Merge NSPL cross-attn partials per query. One wave per (b,q).
__global__ __launch_bounds__(256) void ca_merge(
    const float* __restrict__ pm, const float* __restrict__ ps,
    const float* __restrict__ po, float* __restrict__ out)
{
  int wv = threadIdx.x >> 6;
  int lane = threadIdx.x & 63;
  int bid = blockIdx.x * 4 + wv;
  int hg = lane >> 3;
  size_t pb = (size_t)bid * NSPL;

  float mp[NSPL], sp[NSPL];
#pragma unroll
  for (int p = 0; p < NSPL; ++p) {
    mp[p] = pm[(pb + p) * 8 + hg];
    sp[p] = ps[(pb + p) * 8 + hg];
  }
  float M = mp[0];
#pragma unroll
  for (int p = 1; p < NSPL; ++p) M = fmaxf(M, mp[p]);
  float den = 0.f;
  float4 acc = make_float4(0.f, 0.f, 0.f, 0.f);
#pragma unroll
  for (int p = 0; p < NSPL; ++p) {
    float f = __expf(mp[p] - M);     // empty part m=-inf -> 0
    den = fmaf(f, sp[p], den);
    float4 t = *(const float4*)&po[(pb + p) * 256 + lane * 4];
    acc.x = fmaf(f, t.x, acc.x);
    acc.y = fmaf(f, t.y, acc.y);
    acc.z = fmaf(f, t.z, acc.z);
    acc.w = fmaf(f, t.w, acc.w);
  }
  float inv = 1.f / den;
  float4 res = make_float4(acc.x * inv, acc.y * inv, acc.z * inv, acc.w * inv);
  *(float4*)&out[(size_t)bid * 256 + lane * 4] = res;
}

// ---------------------------------------------------------------------------
// LayerNorm over D=256: one wave per row. x already contains residual sum.
__global__ __launch_bounds__(256) void ln_kernel(
    const float* __restrict__ x, const float* __restrict__ g,
    const float* __restrict__ bta, float* __restrict__ out)
{
  int wv = threadIdx.x >> 6;
  int lane = threadIdx.x & 63;
  int row = blockIdx.x * 4 + wv;
  const float* xr = x + (size_t)row * 256;
  float v[4];
#pragma unroll
  for (int j = 0; j < 4; ++j) v[j] = xr[lane + 64 * j];
  float s = v[0] + v[1] + v[2] + v[3];
  s = wred_sum(s);
  float mean = s * (1.f / 256.f);
  float vs = 0.f;
#pragma unroll
  for (int j = 0; j < 4; ++j) { float d = v[j] - mean; vs = fmaf(d, d, vs); }
  vs = wred_sum(vs);
  float inv = rsqrtf(vs * (1.f / 256.f) + 1e-5f);
  float* orow = out + (size_t)row * 256;
#pragma unroll
  for (int j = 0; j < 4; ++j) {
    int c = lane + 64 * j;
    orow[c] = (v[j] - mean) * inv * g[c] + bta[c];
  }
}

// ---------------------------------------------------------------------------
// Layer-0 mask boxes from attn_area.
__global__ __launch_bounds__(256) void mask0_kernel(
    const float* __restrict__ area, int* __restrict__ lohi,
    float px, float py, float pz)
{
  int row = blockIdx.x * 256 + threadIdx.x;
  if (row >= MR) return;
  int q = row % NQQ;
  int org = q / QPO_;
  const float* a = area + org * 6;
  int* o = lohi + (size_t)row * 6;
  o[0] = (int)fminf(fmaxf(floorf(a[0] * 20.f - px), 0.f), 20.f);
  o[1] = (int)fminf(fmaxf(floorf(a[1] * 20.f - py), 0.f), 20.f);
  o[2] = (int)fminf(fmaxf(floorf(a[2] * 32.f - pz), 0.f), 32.f);
  o[3] = (int)fminf(fmaxf(floorf(a[3] * 20.f + px), 0.f), 20.f);
  o[4] = (int)fminf(fmaxf(floorf(a[4] * 20.f + py), 0.f), 20.f);
  o[5] = (int)fminf(fmaxf(floorf(a[5] * 32.f + pz), 0.f), 32.f);
}

// ---------------------------------------------------------------------------
// Layers >=1: prop = h2 @ w3.T + b3 -> tanh*0.1 + anchors -> clip -> box ints.
__global__ __launch_bounds__(256) void mask_reg_kernel(
    const float* __restrict__ h2, const float* __restrict__ w3,
    const float* __restrict__ b3, const float* __restrict__ anchors,
    int* __restrict__ lohi, float px, float py, float pz)
{
  int wv = threadIdx.x >> 6;
  int lane = threadIdx.x & 63;
  int row = blockIdx.x * 4 + wv;
  int q = row % NQQ;
  const float* hr = h2 + (size_t)row * 256;
  float part[6] = {};
#pragma unroll
  for (int j = 0; j < 4; ++j) {
    float hv = hr[lane + 64 * j];
#pragma unroll
    for (int o = 0; o < 6; ++o)
      part[o] = fmaf(hv, w3[o * 256 + lane + 64 * j], part[o]);
  }
#pragma unroll
  for (int o = 0; o < 6; ++o) part[o] = wred_sum(part[o]);
  if (lane == 0) {
    float prop[6];
#pragma unroll
    for (int o = 0; o < 6; ++o) {
      float v = tanhf(part[o] + b3[o]) * 0.1f + anchors[q * 6 + o];
      prop[o] = fminf(fmaxf(v, 0.f), 1.f);
    }
    float vl0 = prop[0] - 0.5f * prop[3], vh0 = prop[0] + 0.5f * prop[3];
    float vl1 = prop[1] - 0.5f * prop[4], vh1 = prop[1] + 0.5f * prop[4];
    float vl2 = prop[2] - 0.5f * prop[5], vh2 = prop[2] + 0.5f * prop[5];
    int* o = lohi + (size_t)row * 6;
    o[0] = (int)fminf(fmaxf(floorf(vl0 * 20.f - px), 0.f), 20.f);
    o[1] = (int)fminf(fmaxf(floorf(vl1 * 20.f - py), 0.f), 20.f);
    o[2] = (int)fminf(fmaxf(floorf(vl2 * 32.f - pz), 0.f), 32.f);
    o[3] = (int)fminf(fmaxf(floorf(vh0 * 20.f + px), 0.f), 20.f);
    o[4] = (int)fminf(fmaxf(floorf(vh1 * 20.f + py), 0.f), 20.f);
    o[5] = (int)fminf(fmaxf(floorf(vh2 * 32.f + pz), 0.f), 32.f);
  }
}

// ---------------------------------------------------------------------------
extern "C" void kernel_launch(void* const* d_in, const int* in_sizes, int n_in,
                              void* d_out, int out_size, void* d_ws, size_t ws_size,
                              hipStream_t stream)
{
  const float* src       = (const float*)d_in[0];
  const float* pos       = (const float*)d_in[1];
  const float* qe        = (const float*)d_in[2];
  const float* sa_in_w   = (const float*)d_in[3];
  const float* sa_in_b   = (const float*)d_in[4];
  const float* sa_out_w  = (const float*)d_in[5];
  const float* sa_out_b  = (const float*)d_in[6];
  const float* ca_k_w    = (const float*)d_in[7];
  const float* ca_v_w    = (const float*)d_in[8];
  const float* ca_proj_w = (const float*)d_in[9];
  const float* ca_proj_b = (const float*)d_in[10];
  const float* ln1_g = (const float*)d_in[11];
  const float* ln1_b = (const float*)d_in[12];
  const float* ln2_g = (const float*)d_in[13];
  const float* ln2_b = (const float*)d_in[14];
  const float* ln3_g = (const float*)d_in[15];
  const float* ln3_b = (const float*)d_in[16];
  const float* ffn_w1 = (const float*)d_in[17];
  const float* ffn_b1 = (const float*)d_in[18];
  const float* ffn_w2 = (const float*)d_in[19];
  const float* ffn_b2 = (const float*)d_in[20];
  const float* reg_w1 = (const float*)d_in[21];
  const float* reg_b1 = (const float*)d_in[22];
  const float* reg_w2 = (const float*)d_in[23];
  const float* reg_b2 = (const float*)d_in[24];
  const float* reg_w3 = (const float*)d_in[25];
  const float* reg_b3 = (const float*)d_in[26];
  const float* anchors   = (const float*)d_in[27];
  const float* attn_area = (const float*)d_in[28];
  float* outp = (float*)d_out;

  float* ws = (float*)d_ws;
  size_t off = 0;
  auto alloc = [&](size_t n) { float* p = ws + off; off += n; return p; };
  __half* Kb = (__half*)alloc((size_t)BB * PP * 128);   // fp16 [b][p][256], 13.1 MB
  __half* Vb = (__half*)alloc((size_t)BB * PP * 128);   // fp16, 13.1 MB
  alloc(4096);                                          // over-read pad
  __half* s16  = (__half*)alloc((size_t)BB * PP * 128); // fp16(src) [b][p][d]
  __half* kv16 = (__half*)alloc((size_t)BB * PP * 128); // fp16(src+pos) [b][p][d]
  __half* kw16 = (__half*)alloc((size_t)LL * DD * DD / 2);
  __half* vw16 = (__half*)alloc((size_t)LL * DD * DD / 2);
  __half* saw16 = (__half*)alloc((size_t)LL * 768 * DD / 2);   // sa_in_w
  __half* sow16 = (__half*)alloc((size_t)LL * DD * DD / 2);    // sa_out_w
  __half* pw16  = (__half*)alloc((size_t)LL * DD * DD / 2);    // ca_proj_w
  __half* f1w16 = (__half*)alloc((size_t)LL * FFD * DD / 2);   // ffn_w1
  __half* f2w16 = (__half*)alloc((size_t)LL * DD * FFD / 2);   // ffn_w2
  __half* r1w16 = (__half*)alloc((size_t)DD * DD / 2);         // reg_w1
  __half* r2w16 = (__half*)alloc((size_t)DD * DD / 2);         // reg_w2
  __half* saqk16 = (__half*)alloc((size_t)MR * 512 / 2);       // SA q|k fp16
  __half* sav16  = (__half*)alloc((size_t)MR * 256 / 2);       // SA v fp16
  alloc(2048);                                          // SA over-read pad
  float* tgt  = alloc((size_t)MR * DD);
  float* qpos = alloc((size_t)MR * DD);
  float* tmp  = alloc((size_t)MR * DD);
  float* sao  = alloc((size_t)MR * DD);
  float* caq  = alloc((size_t)MR * DD);
  float* cao  = alloc((size_t)MR * DD);
  float* mh1  = alloc((size_t)MR * DD);
  float* mh2  = alloc((size_t)MR * DD);
  float* ffh  = alloc((size_t)MR * FFD);
  float* pmb  = alloc((size_t)MR * NSPL * 8);
  float* psb  = alloc((size_t)MR * NSPL * 8);
  float* pob  = alloc((size_t)MR * NSPL * 256);
  int*   lohi = (int*)alloc((size_t)MR * 6);
  alloc(16384);                                         // A over-read pad
  (void)in_sizes; (void)n_in; (void)out_size; (void)ws_size;

  const float FOCUS_H[6] = {0.1f, 0.075f, 0.05f, 0.05f, 0.025f, 0.025f};

  init_kernel<<<1080, 256, 0, stream>>>(qe, tgt, qpos);
  conv_kv_inputs<<<dim3(200, 4, 2), 256, 0, stream>>>(src, pos, s16, kv16);
  conv_w<<<768, 256, 0, stream>>>(ca_k_w, kw16, LL * DD * DD);
  conv_w<<<768, 256, 0, stream>>>(ca_v_w, vw16, LL * DD * DD);
  conv_w<<<768, 256, 0, stream>>>(sa_in_w, saw16, LL * 768 * DD);
  conv_w<<<768, 256, 0, stream>>>(sa_out_w, sow16, LL * DD * DD);
  conv_w<<<768, 256, 0, stream>>>(ca_proj_w, pw16, LL * DD * DD);
  conv_w<<<768, 256, 0, stream>>>(ffn_w1, f1w16, LL * FFD * DD);
  conv_w<<<768, 256, 0, stream>>>(ffn_w2, f2w16, LL * DD * FFD);
  conv_w<<<256, 256, 0, stream>>>(reg_w1, r1w16, DD * DD);
  conv_w<<<256, 256, 0, stream>>>(reg_w2, r2w16, DD * DD);

  for (int i = 0; i < LL; ++i) {
    const __half* wi16 = saw16 + (size_t)i * 768 * DD;
    const float*  bi   = sa_in_b + (size_t)i * 768;
    // SA: q,k from (tgt+qpos), v from tgt -> fp16 buffers
    gemm_rows_mfma_h<<<dim3(34, 8), 256, 0, stream>>>(tgt, qpos, wi16, bi, saqk16, MR, 512, DD);
    gemm_rows_mfma_h16<<<dim3(68, 4), 256, 0, stream>>>(tgt, nullptr, wi16 + 512 * DD, bi + 512, sav16, MR, DD, DD);
    sa_attn<<<MR, 512, 0, stream>>>(saqk16, sav16, sao);
    gemm_rows_mfma16<<<dim3(68, 4), 256, 0, stream>>>(sao, nullptr, sow16 + (size_t)i * DD * DD,
                                                      sa_out_b + (size_t)i * DD, tgt, tmp, MR, DD, DD, 0);
    ln_kernel<<<270, 256, 0, stream>>>(tmp, ln2_g + i * DD, ln2_b + i * DD, tgt);

    // mask boxes
    if (i == 0) {
      mask0_kernel<<<5, 256, 0, stream>>>(attn_area, lohi,
          FOCUS_H[0] * PS0, FOCUS_H[0] * PS1, FOCUS_H[0] * PS2);
    } else {
      gemm_rows_mfma16<<<dim3(68, 4), 256, 0, stream>>>(tgt, nullptr, r1w16, reg_b1, nullptr, mh1, MR, DD, DD, 1);
      gemm_rows_mfma16<<<dim3(68, 4), 256, 0, stream>>>(mh1, nullptr, r2w16, reg_b2, nullptr, mh2, MR, DD, DD, 1);
      mask_reg_kernel<<<270, 256, 0, stream>>>(mh2, reg_w3, reg_b3, anchors, lohi,
          FOCUS_H[i] * PS0, FOCUS_H[i] * PS1, FOCUS_H[i] * PS2);
    }

    // CA: q from (tgt+qpos)@ca_k_w; K from (src+pos)@ca_k_w; V from src@ca_v_w
    gemm_rows_mfma16<<<dim3(68, 4), 256, 0, stream>>>(tgt, qpos, kw16 + (size_t)i * DD * DD,
                                                      nullptr, nullptr, caq, MR, DD, DD, 0);
    gemm_kv2_mfma<<<dim3(100, 2, 4), 256, 0, stream>>>(kv16, s16,
                                                       kw16 + (size_t)i * DD * DD,
                                                       vw16 + (size_t)i * DD * DD, Kb, Vb);
    ca_attn_part<<<MR * NSPL, 256, 0, stream>>>(caq, Kb, Vb, lohi, pmb, psb, pob);
    ca_merge<<<270, 256, 0, stream>>>(pmb, psb, pob, cao);
    gemm_rows_mfma16<<<dim3(68, 4), 256, 0, stream>>>(cao, nullptr, pw16 + (size_t)i * DD * DD,
                                                      ca_proj_b + (size_t)i * DD, tgt, tmp, MR, DD, DD, 0);
    ln_kernel<<<270, 256, 0, stream>>>(tmp, ln1_g + i * DD, ln1_b + i * DD, tgt);

    // FFN
    gemm_rows_mfma<<<dim3(34, 16), 256, 0, stream>>>(tgt, nullptr, f1w16 + (size_t)i * FFD * DD,
                                                     ffn_b1 + (size_t)i * FFD, nullptr, ffh, MR, FFD, DD, 1);
    gemm_rows_mfma16<<<dim3(68, 4), 256, 0, stream>>>(ffh, nullptr, f2w16 + (size_t)i * DD * FFD,
                                                      ffn_b2 + (size_t)i * DD, tgt, tmp, MR, DD, FFD, 0);
    float* lno = (i == LL - 1) ? outp : tgt;
    ln_kernel<<<270, 256, 0, stream>>>(tmp, ln3_g + i * DD, ln3_b + i * DD, lno);
  }
}